// Round 2
// baseline (3755.819 us; speedup 1.0000x reference)
//
#include <hip/hip_runtime.h>
#include <math.h>

// ---------------- problem constants ----------------
constexpr int Bz  = 32;
constexpr int Nn  = 196;
constexpr int Cc  = 768;
constexpr int Hh  = 12;
constexpr int Dd  = 64;
constexpr int HID = 36;           // Hh * 3
constexpr int NN2 = Nn * Nn;      // 38416
constexpr int QSZ = Bz * Nn * Cc;          // 4,816,896
constexpr int ATT = Bz * Hh * NN2;         // 14,751,744
constexpr int SAMP = Bz * NN2;    // 1,229,312 samples per BN channel
constexpr float RS = 0.35355339059327373f; // 64^-0.25

// ws layout (floats), peak 20,020,480 floats = 80.1 MB:
//  [0, QSZ)            v [B,H,N,D]
//  [QSZ, QSZ+ATT)      "big" slot: q(+0), k(+QSZ) during qkv/qk; then attn
//                      (softmax output); then out_pre [B,N,C] (first QSZ)
//  [QSZ+ATT, +256)     stats: a1[36] b1[36] a2[36] b2[36] Af[12] Bf[12]
//  [+256, +6272*72)    partials

// ---------------- K1: qkv GEMM (f32, 64x64 tile) ----------------
__global__ __launch_bounds__(256) void k_gemm_qkv(const float* __restrict__ X,
                                                  const float* __restrict__ Wq,
                                                  float* __restrict__ qp,
                                                  float* __restrict__ kp,
                                                  float* __restrict__ vp) {
  __shared__ float As[16][68];
  __shared__ float Bs[16][68];
  const int t = threadIdx.x;
  const int tx = t & 15, ty = t >> 4;
  const int m0 = blockIdx.y * 64, n0 = blockIdx.x * 64;
  const int lrow = t >> 2, lkv = t & 3;
  float acc[4][4] = {};
  const float* ap = X + (size_t)(m0 + lrow) * Cc + lkv * 4;
  const float* bp = Wq + (size_t)(n0 + lrow) * Cc + lkv * 4;
  for (int k0 = 0; k0 < Cc; k0 += 16) {
    float4 av = *(const float4*)(ap + k0);
    float4 bv = *(const float4*)(bp + k0);
    __syncthreads();
    As[lkv*4+0][lrow] = av.x; As[lkv*4+1][lrow] = av.y;
    As[lkv*4+2][lrow] = av.z; As[lkv*4+3][lrow] = av.w;
    Bs[lkv*4+0][lrow] = bv.x; Bs[lkv*4+1][lrow] = bv.y;
    Bs[lkv*4+2][lrow] = bv.z; Bs[lkv*4+3][lrow] = bv.w;
    __syncthreads();
#pragma unroll
    for (int kk = 0; kk < 16; kk++) {
      float a[4], b[4];
      *(float4*)a = *(const float4*)&As[kk][ty*4];
      *(float4*)b = *(const float4*)&Bs[kk][tx*4];
#pragma unroll
      for (int i = 0; i < 4; i++)
#pragma unroll
        for (int j = 0; j < 4; j++) acc[i][j] = fmaf(a[i], b[j], acc[i][j]);
    }
  }
#pragma unroll
  for (int i = 0; i < 4; i++) {
    int mi = m0 + ty*4 + i;
    int b = mi / Nn, n = mi - b*Nn;
#pragma unroll
    for (int j = 0; j < 4; j++) {
      int nj = n0 + tx*4 + j;
      int three = nj / Cc;
      int rem = nj - three*Cc;
      int h = rem >> 6, dd = rem & 63;
      float v = acc[i][j] * (three < 2 ? RS : 1.0f);
      float* base = (three == 0) ? qp : (three == 1) ? kp : vp;
      base[((size_t)(b*Hh + h)*Nn + n)*Dd + dd] = v;
    }
  }
}

// ---------------- K7: proj GEMM (f32, 64x64 tile, +bias) ----------------
__global__ __launch_bounds__(256) void k_gemm_proj(const float* __restrict__ A_,
                                                   const float* __restrict__ Wp,
                                                   const float* __restrict__ bias,
                                                   float* __restrict__ out) {
  __shared__ float As[16][68];
  __shared__ float Bs[16][68];
  const int t = threadIdx.x;
  const int tx = t & 15, ty = t >> 4;
  const int m0 = blockIdx.y * 64, n0 = blockIdx.x * 64;
  const int lrow = t >> 2, lkv = t & 3;
  float acc[4][4] = {};
  const float* ap = A_ + (size_t)(m0 + lrow) * Cc + lkv * 4;
  const float* bp = Wp + (size_t)(n0 + lrow) * Cc + lkv * 4;
  for (int k0 = 0; k0 < Cc; k0 += 16) {
    float4 av = *(const float4*)(ap + k0);
    float4 bv = *(const float4*)(bp + k0);
    __syncthreads();
    As[lkv*4+0][lrow] = av.x; As[lkv*4+1][lrow] = av.y;
    As[lkv*4+2][lrow] = av.z; As[lkv*4+3][lrow] = av.w;
    Bs[lkv*4+0][lrow] = bv.x; Bs[lkv*4+1][lrow] = bv.y;
    Bs[lkv*4+2][lrow] = bv.z; Bs[lkv*4+3][lrow] = bv.w;
    __syncthreads();
#pragma unroll
    for (int kk = 0; kk < 16; kk++) {
      float a[4], b[4];
      *(float4*)a = *(const float4*)&As[kk][ty*4];
      *(float4*)b = *(const float4*)&Bs[kk][tx*4];
#pragma unroll
      for (int i = 0; i < 4; i++)
#pragma unroll
        for (int j = 0; j < 4; j++) acc[i][j] = fmaf(a[i], b[j], acc[i][j]);
    }
  }
#pragma unroll
  for (int i = 0; i < 4; i++) {
    int mi = m0 + ty*4 + i;
#pragma unroll
    for (int j = 0; j < 4; j++) {
      int nj = n0 + tx*4 + j;
      out[(size_t)mi*Cc + nj] = acc[i][j] + bias[nj];
    }
  }
}

// ---------------- K2a: S = Q K^T (batched, 32x32 tiles) ----------------
__global__ __launch_bounds__(256) void k_qk(const float* __restrict__ qbuf,
                                            const float* __restrict__ kbuf,
                                            float* __restrict__ S) {
  __shared__ float Qs[32][68];
  __shared__ float Ks[32][68];
  const int t = threadIdx.x;
  const int bh = blockIdx.x;
  const int r0 = blockIdx.y * 32, c0 = blockIdx.z * 32;
  const float* qp = qbuf + (size_t)bh * Nn * Dd;
  const float* kp = kbuf + (size_t)bh * Nn * Dd;
#pragma unroll
  for (int i = 0; i < 2; i++) {
    int idx = t + i*256;            // float4 index
    int row = idx >> 4, kv = idx & 15;
    float4 qv = make_float4(0,0,0,0), kk4 = make_float4(0,0,0,0);
    int gr = r0 + row;
    if (gr < Nn) qv = *(const float4*)(qp + (size_t)gr*Dd + kv*4);
    int gc = c0 + row;
    if (gc < Nn) kk4 = *(const float4*)(kp + (size_t)gc*Dd + kv*4);
    *(float4*)&Qs[row][kv*4] = qv;
    *(float4*)&Ks[row][kv*4] = kk4;
  }
  __syncthreads();
  const int tx = t & 15, ty = t >> 4;
  float acc[2][2] = {};
#pragma unroll
  for (int kk = 0; kk < 64; kk++) {
    float a0 = Qs[ty*2+0][kk], a1 = Qs[ty*2+1][kk];
    float b0 = Ks[tx*2+0][kk], b1 = Ks[tx*2+1][kk];
    acc[0][0] = fmaf(a0,b0,acc[0][0]); acc[0][1] = fmaf(a0,b1,acc[0][1]);
    acc[1][0] = fmaf(a1,b0,acc[1][0]); acc[1][1] = fmaf(a1,b1,acc[1][1]);
  }
#pragma unroll
  for (int i = 0; i < 2; i++) {
    int rr = r0 + ty*2 + i;
    if (rr >= Nn) continue;
#pragma unroll
    for (int j = 0; j < 2; j++) {
      int cc2 = c0 + tx*2 + j;
      if (cc2 < Nn) S[((size_t)bh*Nn + rr)*Nn + cc2] = acc[i][j];
    }
  }
}

// ---------------- K2b: row softmax, src -> dst ----------------
__global__ __launch_bounds__(256) void k_softmax(const float* __restrict__ src,
                                                 float* __restrict__ dst) {
  const int row = blockIdx.x*4 + (threadIdx.x >> 6);
  const int lane = threadIdx.x & 63;
  const float* p = src + (size_t)row * Nn;
  float* o = dst + (size_t)row * Nn;
  float v[4];
  float mx = -1e30f;
#pragma unroll
  for (int i = 0; i < 4; i++) {
    int m = lane + i*64;
    v[i] = (m < Nn) ? p[m] : -1e30f;
    mx = fmaxf(mx, v[i]);
  }
#pragma unroll
  for (int off = 32; off; off >>= 1) mx = fmaxf(mx, __shfl_xor(mx, off, 64));
  float sum = 0.0f;
#pragma unroll
  for (int i = 0; i < 4; i++) {
    int m = lane + i*64;
    v[i] = (m < Nn) ? __expf(v[i]-mx) : 0.0f;
    sum += v[i];
  }
#pragma unroll
  for (int off = 32; off; off >>= 1) sum += __shfl_xor(sum, off, 64);
  float inv = 1.0f / sum;
#pragma unroll
  for (int i = 0; i < 4; i++) {
    int m = lane + i*64;
    if (m < Nn) o[m] = v[i]*inv;
  }
}

// ---------------- K3: y1 = conv_exp(attn) stats (recompute, no store) ----------------
__global__ __launch_bounds__(256) void k_y1stats(const float* __restrict__ attn,
                                                 const float* __restrict__ w_exp,
                                                 float* __restrict__ part) {
  __shared__ float wse[HID*Hh];
  __shared__ float red2[4*72];
  const int t = threadIdx.x;
  for (int i = t; i < HID*Hh; i += 256) wse[i] = w_exp[i];
  __syncthreads();
  float s1[36] = {}, s2[36] = {};
  const int stride = gridDim.x * 256;
  for (int s = blockIdx.x*256 + t; s < SAMP; s += stride) {
    int b = s / NN2, p = s - b*NN2;
    float a[12];
#pragma unroll
    for (int h = 0; h < 12; h++) a[h] = attn[((size_t)(b*12+h))*NN2 + p];
#pragma unroll
    for (int c = 0; c < 36; c++) {
      float y = 0.0f;
#pragma unroll
      for (int h = 0; h < 12; h++) y = fmaf(wse[c*12+h], a[h], y);
      s1[c] += y; s2[c] += y*y;
    }
  }
#pragma unroll
  for (int c = 0; c < 36; c++) {
#pragma unroll
    for (int off = 32; off; off >>= 1) {
      s1[c] += __shfl_xor(s1[c], off, 64);
      s2[c] += __shfl_xor(s2[c], off, 64);
    }
  }
  const int w = t >> 6;
  if ((t & 63) == 0) {
#pragma unroll
    for (int c = 0; c < 36; c++) { red2[w*72 + c] = s1[c]; red2[w*72 + 36 + c] = s2[c]; }
  }
  __syncthreads();
  if (t < 72)
    part[(size_t)blockIdx.x*72 + t] = red2[t] + red2[72+t] + red2[144+t] + red2[216+t];
}

// ---------------- reduce partials -> BN affine (36 ch) ----------------
__global__ void k_bnaffine36(const float* __restrict__ part, int nb,
                             const float* __restrict__ g, const float* __restrict__ beta,
                             float* __restrict__ stats, int off) {
  int c = threadIdx.x;
  if (c >= 36) return;
  double s0=0, s1=0, q0=0, q1=0;
  int i = 0;
  for (; i+1 < nb; i += 2) {
    s0 += part[(size_t)i*72 + c];        s1 += part[(size_t)(i+1)*72 + c];
    q0 += part[(size_t)i*72 + 36 + c];   q1 += part[(size_t)(i+1)*72 + 36 + c];
  }
  if (i < nb) { s0 += part[(size_t)i*72 + c]; q0 += part[(size_t)i*72 + 36 + c]; }
  double m = (s0+s1) / (double)SAMP;
  double v = (q0+q1) / (double)SAMP - m*m;
  float a = g[c] * rsqrtf((float)v + 1e-5f);
  stats[off + c] = a;
  stats[off + 36 + c] = beta[c] - (float)m * a;
}

// ---- tiled DLA recompute. MODE 0: y2 stats. MODE 1: z stats. MODE 2: attn_r write ----
template<int MODE>
__global__ __launch_bounds__(256) void k_dla(const float* __restrict__ attn,
                                             const float* __restrict__ w_exp,
                                             const float* __restrict__ w_dw,
                                             const float* __restrict__ w_pro,
                                             const float* __restrict__ stats,
                                             float* __restrict__ attn_r,
                                             float* __restrict__ part) {
  __shared__ float a_s[12*256];
  __shared__ float y_s[36*256];
  __shared__ float wse[432];
  __shared__ float wdw[324];
  __shared__ float wpr[432];
  __shared__ float aff[168];
  __shared__ float red2[4*72];
  const int t = threadIdx.x;
  const int blk = blockIdx.x;
  const int b = blk / 196, tile = blk - b*196;
  const int tyq = tile / 14;
  const int ty0 = tyq * 14, tx0 = (tile - tyq*14) * 14;
  for (int i = t; i < 432; i += 256) wse[i] = w_exp[i];
  for (int i = t; i < 324; i += 256) wdw[i] = w_dw[i];
  if (MODE >= 1) for (int i = t; i < 432; i += 256) wpr[i] = w_pro[i];
  if (t < 168) aff[t] = stats[t];
  __syncthreads();
  // halo load: attn [12][16][16] (zero outside image)
#pragma unroll
  for (int i = 0; i < 12; i++) {
    int idx = t + i*256;
    int ch = idx >> 8, pos = idx & 255;
    int hy = ty0 + (pos >> 4) - 1, hx = tx0 + (pos & 15) - 1;
    float vv = 0.0f;
    if (hy >= 0 && hy < 196 && hx >= 0 && hx < 196)
      vv = attn[((size_t)(b*12+ch))*NN2 + (size_t)hy*196 + hx];
    a_s[ch*256 + pos] = vv;
  }
  __syncthreads();
  // y1c = clip(bn1(conv_exp)) on halo; ZERO outside image (dw conv pads with 0)
#pragma unroll
  for (int i = 0; i < 36; i++) {
    int idx = t + i*256;
    int c = idx >> 8, pos = idx & 255;
    int hy = ty0 + (pos >> 4) - 1, hx = tx0 + (pos & 15) - 1;
    float y = 0.0f;
#pragma unroll
    for (int h = 0; h < 12; h++) y = fmaf(wse[c*12+h], a_s[h*256+pos], y);
    y = y*aff[c] + aff[36+c];
    y = fminf(fmaxf(y, 0.0f), 6.0f);
    bool inb = (hy >= 0) && (hy < 196) && (hx >= 0) && (hx < 196);
    y_s[c*256 + pos] = inb ? y : 0.0f;
  }
  __syncthreads();
  float s1[36] = {}, s2[36] = {};
  float z[12] = {};
  const bool act = (t < 196);
  const int py = t / 14, px = t - py*14;
  const int base = (py+1)*16 + (px+1);
  if (act) {
#pragma unroll
    for (int c = 0; c < 36; c++) {
      const float* ys = &y_s[c*256];
      const float* wd = &wdw[c*9];
      float y2 = 0.0f;
#pragma unroll
      for (int di = 0; di < 3; di++)
#pragma unroll
        for (int dj = 0; dj < 3; dj++)
          y2 = fmaf(wd[di*3+dj], ys[base + (di-1)*16 + (dj-1)], y2);
      if (MODE == 0) { s1[c] = y2; s2[c] = y2*y2; }
      else {
        float y2c = y2*aff[72+c] + aff[108+c];
        y2c = fminf(fmaxf(y2c, 0.0f), 6.0f);
#pragma unroll
        for (int cc = 0; cc < 12; cc++) z[cc] = fmaf(wpr[cc*36+c], y2c, z[cc]);
      }
    }
    if (MODE == 1) {
#pragma unroll
      for (int cc = 0; cc < 12; cc++) { s1[cc] = z[cc]; s2[cc] = z[cc]*z[cc]; }
    }
    if (MODE == 2) {
      int oy = ty0 + py, ox = tx0 + px;
#pragma unroll
      for (int cc = 0; cc < 12; cc++)
        attn_r[((size_t)(b*12+cc))*NN2 + (size_t)oy*196 + ox] =
            z[cc]*aff[144+cc] + aff[156+cc];
    }
  }
  if (MODE < 2) {
    const int NRED = (MODE == 0) ? 36 : 12;
#pragma unroll
    for (int c = 0; c < 36; c++) {
      if (c >= NRED) break;
#pragma unroll
      for (int off = 32; off; off >>= 1) {
        s1[c] += __shfl_xor(s1[c], off, 64);
        s2[c] += __shfl_xor(s2[c], off, 64);
      }
    }
    const int w = t >> 6;
    if ((t & 63) == 0) {
#pragma unroll
      for (int c = 0; c < 36; c++) {
        if (c >= NRED) break;
        red2[w*2*NRED + c] = s1[c];
        red2[w*2*NRED + NRED + c] = s2[c];
      }
    }
    __syncthreads();
    if (t < 2*NRED)
      part[(size_t)blk*2*NRED + t] =
        red2[t] + red2[2*NRED+t] + red2[4*NRED+t] + red2[6*NRED+t];
  }
}

// ---------------- combined bn3 + adapt_bn affine ----------------
__global__ void k_bnfinal(const float* __restrict__ part, int nb,
                          const float* __restrict__ g3, const float* __restrict__ b3,
                          const float* __restrict__ ag, const float* __restrict__ ab,
                          float* __restrict__ stats) {
  int c = threadIdx.x;
  if (c >= 12) return;
  (void)b3; // bn3 beta cancels exactly in the composed affine
  double s=0, q=0;
  for (int i = 0; i < nb; i++) { s += part[(size_t)i*24 + c]; q += part[(size_t)i*24 + 12 + c]; }
  double m = s / (double)SAMP;
  double v = q / (double)SAMP - m*m;
  float r1 = rsqrtf((float)v + 1e-5f);
  float vt = g3[c]*g3[c]*(float)v*r1*r1;
  float r2 = rsqrtf(vt + 1e-5f);
  float A = g3[c]*ag[c]*r1*r2;
  stats[144 + c] = A;
  stats[156 + c] = ab[c] - (float)m*A;
}

// ---------------- PV: O = attn_r @ V -> out_pre [B,N,C] ----------------
__global__ __launch_bounds__(256) void k_pv(const float* __restrict__ attn_r,
                                            const float* __restrict__ vbuf,
                                            float* __restrict__ out_pre) {
  __shared__ float Vs[196*65];
  __shared__ float ar_s[16*200];
  const int t = threadIdx.x;
  const int bh = blockIdx.x;
  const int b = bh / 12, h = bh - b*12;
  const float* vp = vbuf + (size_t)bh * Nn * Dd;
#pragma unroll
  for (int i = 0; i < 49; i++) {
    int idx = t + i*256;
    Vs[(idx >> 6)*65 + (idx & 63)] = vp[idx];
  }
  const float* arp = attn_r + (size_t)bh * NN2;
  const int dd = t & 63, wy = t >> 6;
  for (int ch = 0; ch < 13; ch++) {
    const int r0 = ch*16;
    const int nrows = (r0 + 16 <= 196) ? 16 : (196 - r0);
    __syncthreads();
    for (int idx = t; idx < nrows*196; idx += 256) {
      int rr = idx / 196, m = idx - rr*196;
      ar_s[rr*200 + m] = arp[(size_t)(r0+rr)*196 + m];
    }
    __syncthreads();
    float acc[4] = {0,0,0,0};
#pragma unroll 2
    for (int m = 0; m < 196; m++) {
      float vv = Vs[m*65 + dd];
#pragma unroll
      for (int r = 0; r < 4; r++) acc[r] = fmaf(ar_s[(wy*4+r)*200 + m], vv, acc[r]);
    }
#pragma unroll
    for (int r = 0; r < 4; r++) {
      int rr = wy*4 + r;
      if (rr < nrows)
        out_pre[((size_t)(b*196 + r0 + rr))*Cc + h*64 + dd] = acc[r];
    }
  }
}

// ---------------- launch ----------------
extern "C" void kernel_launch(void* const* d_in, const int* in_sizes, int n_in,
                              void* d_out, int out_size, void* d_ws, size_t ws_size,
                              hipStream_t stream) {
  (void)in_sizes; (void)n_in; (void)out_size; (void)ws_size;
  const float* x      = (const float*)d_in[0];
  const float* w_qkv  = (const float*)d_in[1];
  const float* w_exp  = (const float*)d_in[2];
  const float* bn1_g  = (const float*)d_in[3];
  const float* bn1_b  = (const float*)d_in[4];
  const float* w_dw   = (const float*)d_in[5];
  const float* bn2_g  = (const float*)d_in[6];
  const float* bn2_b  = (const float*)d_in[7];
  const float* w_pro  = (const float*)d_in[8];
  const float* bn3_g  = (const float*)d_in[9];
  const float* bn3_b  = (const float*)d_in[10];
  const float* abn_g  = (const float*)d_in[11];
  const float* abn_b  = (const float*)d_in[12];
  const float* w_proj = (const float*)d_in[13];
  const float* b_proj = (const float*)d_in[14];

  float* out      = (float*)d_out;
  float* attn_out = out + (size_t)QSZ;     // d_out's attn_r region (also S scratch)
  float* ws    = (float*)d_ws;
  float* vbuf  = ws;                        // [QSZ]
  float* big   = ws + (size_t)QSZ;          // [ATT]: q,k -> attn -> out_pre
  float* qbuf  = big;
  float* kbuf  = big + (size_t)QSZ;
  float* stats = ws + (size_t)QSZ + ATT;    // [256]
  float* part  = stats + 256;               // [6272*72]

  k_gemm_qkv <<<dim3(36, 98), 256, 0, stream>>>(x, w_qkv, qbuf, kbuf, vbuf);
  k_qk       <<<dim3(384, 7, 7), 256, 0, stream>>>(qbuf, kbuf, attn_out);   // S -> d_out scratch
  k_softmax  <<<18816, 256, 0, stream>>>(attn_out, big);                    // attn -> ws (q,k dead)
  k_y1stats  <<<1024, 256, 0, stream>>>(big, w_exp, part);
  k_bnaffine36<<<1, 64, 0, stream>>>(part, 1024, bn1_g, bn1_b, stats, 0);
  k_dla<0>   <<<6272, 256, 0, stream>>>(big, w_exp, w_dw, nullptr, stats, nullptr, part);
  k_bnaffine36<<<1, 64, 0, stream>>>(part, 6272, bn2_g, bn2_b, stats, 72);
  k_dla<1>   <<<6272, 256, 0, stream>>>(big, w_exp, w_dw, w_pro, stats, nullptr, part);
  k_bnfinal  <<<1, 64, 0, stream>>>(part, 6272, bn3_g, bn3_b, abn_g, abn_b, stats);
  k_dla<2>   <<<6272, 256, 0, stream>>>(big, w_exp, w_dw, w_pro, stats, attn_out, nullptr);
  k_pv       <<<384, 256, 0, stream>>>(attn_out, vbuf, big);                // out_pre -> big[0..QSZ)
  k_gemm_proj<<<dim3(12, 98), 256, 0, stream>>>(big, w_proj, b_proj, out);
}

// Round 3
// 1602.781 us; speedup vs baseline: 2.3433x; 2.3433x over previous
//
#include <hip/hip_runtime.h>
#include <math.h>

// ---------------- problem constants ----------------
constexpr int Bz  = 32;
constexpr int Nn  = 196;
constexpr int Cc  = 768;
constexpr int Hh  = 12;
constexpr int Dd  = 64;
constexpr int HID = 36;           // Hh * 3
constexpr int NN2 = Nn * Nn;      // 38416
constexpr int QSZ = Bz * Nn * Cc;          // 4,816,896
constexpr int ATT = Bz * Hh * NN2;         // 14,751,744
constexpr int SAMP = Bz * NN2;    // 1,229,312 samples per BN channel
constexpr float RS = 0.35355339059327373f; // 64^-0.25

// ws layout (floats), peak ~80.3 MB:
//  [0, QSZ)            v [B,H,N,D]
//  [QSZ, QSZ+ATT)      "big" slot: q(+0), k(+QSZ) during qkv/qk; then attn
//                      (softmax output); then out_pre [B,N,C] (first QSZ)
//  [QSZ+ATT, +256)     stats: a1[36] b1[36] a2[36] b2[36] Af[12] Bf[12]
//  [+256, +6272*72)    partials
//  [then]              dsum[96] doubles (192 floats)

// ---------------- K1: qkv GEMM (f32, 64x64 tile) ----------------
__global__ __launch_bounds__(256) void k_gemm_qkv(const float* __restrict__ X,
                                                  const float* __restrict__ Wq,
                                                  float* __restrict__ qp,
                                                  float* __restrict__ kp,
                                                  float* __restrict__ vp) {
  __shared__ float As[16][68];
  __shared__ float Bs[16][68];
  const int t = threadIdx.x;
  const int tx = t & 15, ty = t >> 4;
  const int m0 = blockIdx.y * 64, n0 = blockIdx.x * 64;
  const int lrow = t >> 2, lkv = t & 3;
  float acc[4][4] = {};
  const float* ap = X + (size_t)(m0 + lrow) * Cc + lkv * 4;
  const float* bp = Wq + (size_t)(n0 + lrow) * Cc + lkv * 4;
  for (int k0 = 0; k0 < Cc; k0 += 16) {
    float4 av = *(const float4*)(ap + k0);
    float4 bv = *(const float4*)(bp + k0);
    __syncthreads();
    As[lkv*4+0][lrow] = av.x; As[lkv*4+1][lrow] = av.y;
    As[lkv*4+2][lrow] = av.z; As[lkv*4+3][lrow] = av.w;
    Bs[lkv*4+0][lrow] = bv.x; Bs[lkv*4+1][lrow] = bv.y;
    Bs[lkv*4+2][lrow] = bv.z; Bs[lkv*4+3][lrow] = bv.w;
    __syncthreads();
#pragma unroll
    for (int kk = 0; kk < 16; kk++) {
      float a[4], b[4];
      *(float4*)a = *(const float4*)&As[kk][ty*4];
      *(float4*)b = *(const float4*)&Bs[kk][tx*4];
#pragma unroll
      for (int i = 0; i < 4; i++)
#pragma unroll
        for (int j = 0; j < 4; j++) acc[i][j] = fmaf(a[i], b[j], acc[i][j]);
    }
  }
#pragma unroll
  for (int i = 0; i < 4; i++) {
    int mi = m0 + ty*4 + i;
    int b = mi / Nn, n = mi - b*Nn;
#pragma unroll
    for (int j = 0; j < 4; j++) {
      int nj = n0 + tx*4 + j;
      int three = nj / Cc;
      int rem = nj - three*Cc;
      int h = rem >> 6, dd = rem & 63;
      float v = acc[i][j] * (three < 2 ? RS : 1.0f);
      float* base = (three == 0) ? qp : (three == 1) ? kp : vp;
      base[((size_t)(b*Hh + h)*Nn + n)*Dd + dd] = v;
    }
  }
}

// ---------------- K7: proj GEMM (f32, 64x64 tile, +bias) ----------------
__global__ __launch_bounds__(256) void k_gemm_proj(const float* __restrict__ A_,
                                                   const float* __restrict__ Wp,
                                                   const float* __restrict__ bias,
                                                   float* __restrict__ out) {
  __shared__ float As[16][68];
  __shared__ float Bs[16][68];
  const int t = threadIdx.x;
  const int tx = t & 15, ty = t >> 4;
  const int m0 = blockIdx.y * 64, n0 = blockIdx.x * 64;
  const int lrow = t >> 2, lkv = t & 3;
  float acc[4][4] = {};
  const float* ap = A_ + (size_t)(m0 + lrow) * Cc + lkv * 4;
  const float* bp = Wp + (size_t)(n0 + lrow) * Cc + lkv * 4;
  for (int k0 = 0; k0 < Cc; k0 += 16) {
    float4 av = *(const float4*)(ap + k0);
    float4 bv = *(const float4*)(bp + k0);
    __syncthreads();
    As[lkv*4+0][lrow] = av.x; As[lkv*4+1][lrow] = av.y;
    As[lkv*4+2][lrow] = av.z; As[lkv*4+3][lrow] = av.w;
    Bs[lkv*4+0][lrow] = bv.x; Bs[lkv*4+1][lrow] = bv.y;
    Bs[lkv*4+2][lrow] = bv.z; Bs[lkv*4+3][lrow] = bv.w;
    __syncthreads();
#pragma unroll
    for (int kk = 0; kk < 16; kk++) {
      float a[4], b[4];
      *(float4*)a = *(const float4*)&As[kk][ty*4];
      *(float4*)b = *(const float4*)&Bs[kk][tx*4];
#pragma unroll
      for (int i = 0; i < 4; i++)
#pragma unroll
        for (int j = 0; j < 4; j++) acc[i][j] = fmaf(a[i], b[j], acc[i][j]);
    }
  }
#pragma unroll
  for (int i = 0; i < 4; i++) {
    int mi = m0 + ty*4 + i;
#pragma unroll
    for (int j = 0; j < 4; j++) {
      int nj = n0 + tx*4 + j;
      out[(size_t)mi*Cc + nj] = acc[i][j] + bias[nj];
    }
  }
}

// ---------------- K2a: S = Q K^T (batched, 32x32 tiles) ----------------
__global__ __launch_bounds__(256) void k_qk(const float* __restrict__ qbuf,
                                            const float* __restrict__ kbuf,
                                            float* __restrict__ S) {
  __shared__ float Qs[32][68];
  __shared__ float Ks[32][68];
  const int t = threadIdx.x;
  const int bh = blockIdx.x;
  const int r0 = blockIdx.y * 32, c0 = blockIdx.z * 32;
  const float* qp = qbuf + (size_t)bh * Nn * Dd;
  const float* kp = kbuf + (size_t)bh * Nn * Dd;
#pragma unroll
  for (int i = 0; i < 2; i++) {
    int idx = t + i*256;            // float4 index
    int row = idx >> 4, kv = idx & 15;
    float4 qv = make_float4(0,0,0,0), kk4 = make_float4(0,0,0,0);
    int gr = r0 + row;
    if (gr < Nn) qv = *(const float4*)(qp + (size_t)gr*Dd + kv*4);
    int gc = c0 + row;
    if (gc < Nn) kk4 = *(const float4*)(kp + (size_t)gc*Dd + kv*4);
    *(float4*)&Qs[row][kv*4] = qv;
    *(float4*)&Ks[row][kv*4] = kk4;
  }
  __syncthreads();
  const int tx = t & 15, ty = t >> 4;
  float acc[2][2] = {};
#pragma unroll
  for (int kk = 0; kk < 64; kk++) {
    float a0 = Qs[ty*2+0][kk], a1 = Qs[ty*2+1][kk];
    float b0 = Ks[tx*2+0][kk], b1 = Ks[tx*2+1][kk];
    acc[0][0] = fmaf(a0,b0,acc[0][0]); acc[0][1] = fmaf(a0,b1,acc[0][1]);
    acc[1][0] = fmaf(a1,b0,acc[1][0]); acc[1][1] = fmaf(a1,b1,acc[1][1]);
  }
#pragma unroll
  for (int i = 0; i < 2; i++) {
    int rr = r0 + ty*2 + i;
    if (rr >= Nn) continue;
#pragma unroll
    for (int j = 0; j < 2; j++) {
      int cc2 = c0 + tx*2 + j;
      if (cc2 < Nn) S[((size_t)bh*Nn + rr)*Nn + cc2] = acc[i][j];
    }
  }
}

// ---------------- K2b: row softmax, src -> dst ----------------
__global__ __launch_bounds__(256) void k_softmax(const float* __restrict__ src,
                                                 float* __restrict__ dst) {
  const int row = blockIdx.x*4 + (threadIdx.x >> 6);
  const int lane = threadIdx.x & 63;
  const float* p = src + (size_t)row * Nn;
  float* o = dst + (size_t)row * Nn;
  float v[4];
  float mx = -1e30f;
#pragma unroll
  for (int i = 0; i < 4; i++) {
    int m = lane + i*64;
    v[i] = (m < Nn) ? p[m] : -1e30f;
    mx = fmaxf(mx, v[i]);
  }
#pragma unroll
  for (int off = 32; off; off >>= 1) mx = fmaxf(mx, __shfl_xor(mx, off, 64));
  float sum = 0.0f;
#pragma unroll
  for (int i = 0; i < 4; i++) {
    int m = lane + i*64;
    v[i] = (m < Nn) ? __expf(v[i]-mx) : 0.0f;
    sum += v[i];
  }
#pragma unroll
  for (int off = 32; off; off >>= 1) sum += __shfl_xor(sum, off, 64);
  float inv = 1.0f / sum;
#pragma unroll
  for (int i = 0; i < 4; i++) {
    int m = lane + i*64;
    if (m < Nn) o[m] = v[i]*inv;
  }
}

// ---------------- K3: y1 = conv_exp(attn) stats (recompute, no store) ----------------
__global__ __launch_bounds__(256) void k_y1stats(const float* __restrict__ attn,
                                                 const float* __restrict__ w_exp,
                                                 float* __restrict__ part) {
  __shared__ float wse[HID*Hh];
  __shared__ float red2[4*72];
  const int t = threadIdx.x;
  for (int i = t; i < HID*Hh; i += 256) wse[i] = w_exp[i];
  __syncthreads();
  float s1[36] = {}, s2[36] = {};
  const int stride = gridDim.x * 256;
  for (int s = blockIdx.x*256 + t; s < SAMP; s += stride) {
    int b = s / NN2, p = s - b*NN2;
    float a[12];
#pragma unroll
    for (int h = 0; h < 12; h++) a[h] = attn[((size_t)(b*12+h))*NN2 + p];
#pragma unroll
    for (int c = 0; c < 36; c++) {
      float y = 0.0f;
#pragma unroll
      for (int h = 0; h < 12; h++) y = fmaf(wse[c*12+h], a[h], y);
      s1[c] += y; s2[c] += y*y;
    }
  }
#pragma unroll
  for (int c = 0; c < 36; c++) {
#pragma unroll
    for (int off = 32; off; off >>= 1) {
      s1[c] += __shfl_xor(s1[c], off, 64);
      s2[c] += __shfl_xor(s2[c], off, 64);
    }
  }
  const int w = t >> 6;
  if ((t & 63) == 0) {
#pragma unroll
    for (int c = 0; c < 36; c++) { red2[w*72 + c] = s1[c]; red2[w*72 + 36 + c] = s2[c]; }
  }
  __syncthreads();
  if (t < 72)
    part[(size_t)blockIdx.x*72 + t] = red2[t] + red2[72+t] + red2[144+t] + red2[216+t];
}

// ---------------- hierarchical deterministic reduce: part[nb][stride] -> dsum[stride] ----------------
__global__ __launch_bounds__(256) void k_reduce(const float* __restrict__ part, int nb,
                                               int stride, double* __restrict__ dsum) {
  __shared__ double sh[256];
  const int c = blockIdx.x;       // one block per channel-stat
  const int t = threadIdx.x;
  double s = 0.0;
  for (int i = t; i < nb; i += 256) s += (double)part[(size_t)i*stride + c];
  sh[t] = s;
  __syncthreads();
  for (int o = 128; o; o >>= 1) {
    if (t < o) sh[t] += sh[t + o];
    __syncthreads();
  }
  if (t == 0) dsum[c] = sh[0];
}

// ---------------- dsum -> BN affine (36 ch) ----------------
__global__ void k_bnaffine36(const double* __restrict__ dsum,
                             const float* __restrict__ g, const float* __restrict__ beta,
                             float* __restrict__ stats, int off) {
  int c = threadIdx.x;
  if (c >= 36) return;
  double m = dsum[c] / (double)SAMP;
  double v = dsum[36 + c] / (double)SAMP - m*m;
  float a = g[c] * rsqrtf((float)v + 1e-5f);
  stats[off + c] = a;
  stats[off + 36 + c] = beta[c] - (float)m * a;
}

// ---- tiled DLA recompute. MODE 0: y2 stats. MODE 1: z stats. MODE 2: attn_r write ----
template<int MODE>
__global__ __launch_bounds__(256) void k_dla(const float* __restrict__ attn,
                                             const float* __restrict__ w_exp,
                                             const float* __restrict__ w_dw,
                                             const float* __restrict__ w_pro,
                                             const float* __restrict__ stats,
                                             float* __restrict__ attn_r,
                                             float* __restrict__ part) {
  __shared__ float a_s[12*256];
  __shared__ float y_s[36*256];
  __shared__ float wse[432];
  __shared__ float wdw[324];
  __shared__ float wpr[432];
  __shared__ float aff[168];
  __shared__ float red2[4*72];
  const int t = threadIdx.x;
  const int blk = blockIdx.x;
  const int b = blk / 196, tile = blk - b*196;
  const int tyq = tile / 14;
  const int ty0 = tyq * 14, tx0 = (tile - tyq*14) * 14;
  for (int i = t; i < 432; i += 256) wse[i] = w_exp[i];
  for (int i = t; i < 324; i += 256) wdw[i] = w_dw[i];
  if (MODE >= 1) for (int i = t; i < 432; i += 256) wpr[i] = w_pro[i];
  if (t < 168) aff[t] = stats[t];
  __syncthreads();
  // halo load: attn [12][16][16] (zero outside image)
#pragma unroll
  for (int i = 0; i < 12; i++) {
    int idx = t + i*256;
    int ch = idx >> 8, pos = idx & 255;
    int hy = ty0 + (pos >> 4) - 1, hx = tx0 + (pos & 15) - 1;
    float vv = 0.0f;
    if (hy >= 0 && hy < 196 && hx >= 0 && hx < 196)
      vv = attn[((size_t)(b*12+ch))*NN2 + (size_t)hy*196 + hx];
    a_s[ch*256 + pos] = vv;
  }
  __syncthreads();
  // y1c = clip(bn1(conv_exp)) on halo; ZERO outside image (dw conv pads with 0)
#pragma unroll
  for (int i = 0; i < 36; i++) {
    int idx = t + i*256;
    int c = idx >> 8, pos = idx & 255;
    int hy = ty0 + (pos >> 4) - 1, hx = tx0 + (pos & 15) - 1;
    float y = 0.0f;
#pragma unroll
    for (int h = 0; h < 12; h++) y = fmaf(wse[c*12+h], a_s[h*256+pos], y);
    y = y*aff[c] + aff[36+c];
    y = fminf(fmaxf(y, 0.0f), 6.0f);
    bool inb = (hy >= 0) && (hy < 196) && (hx >= 0) && (hx < 196);
    y_s[c*256 + pos] = inb ? y : 0.0f;
  }
  __syncthreads();
  float s1[36] = {}, s2[36] = {};
  float z[12] = {};
  const bool act = (t < 196);
  const int py = t / 14, px = t - py*14;
  const int base = (py+1)*16 + (px+1);
  if (act) {
#pragma unroll
    for (int c = 0; c < 36; c++) {
      const float* ys = &y_s[c*256];
      const float* wd = &wdw[c*9];
      float y2 = 0.0f;
#pragma unroll
      for (int di = 0; di < 3; di++)
#pragma unroll
        for (int dj = 0; dj < 3; dj++)
          y2 = fmaf(wd[di*3+dj], ys[base + (di-1)*16 + (dj-1)], y2);
      if (MODE == 0) { s1[c] = y2; s2[c] = y2*y2; }
      else {
        float y2c = y2*aff[72+c] + aff[108+c];
        y2c = fminf(fmaxf(y2c, 0.0f), 6.0f);
#pragma unroll
        for (int cc = 0; cc < 12; cc++) z[cc] = fmaf(wpr[cc*36+c], y2c, z[cc]);
      }
    }
    if (MODE == 1) {
#pragma unroll
      for (int cc = 0; cc < 12; cc++) { s1[cc] = z[cc]; s2[cc] = z[cc]*z[cc]; }
    }
    if (MODE == 2) {
      int oy = ty0 + py, ox = tx0 + px;
#pragma unroll
      for (int cc = 0; cc < 12; cc++)
        attn_r[((size_t)(b*12+cc))*NN2 + (size_t)oy*196 + ox] =
            z[cc]*aff[144+cc] + aff[156+cc];
    }
  }
  if (MODE < 2) {
    const int NRED = (MODE == 0) ? 36 : 12;
#pragma unroll
    for (int c = 0; c < 36; c++) {
      if (c >= NRED) break;
#pragma unroll
      for (int off = 32; off; off >>= 1) {
        s1[c] += __shfl_xor(s1[c], off, 64);
        s2[c] += __shfl_xor(s2[c], off, 64);
      }
    }
    const int w = t >> 6;
    if ((t & 63) == 0) {
#pragma unroll
      for (int c = 0; c < 36; c++) {
        if (c >= NRED) break;
        red2[w*2*NRED + c] = s1[c];
        red2[w*2*NRED + NRED + c] = s2[c];
      }
    }
    __syncthreads();
    if (t < 2*NRED)
      part[(size_t)blk*2*NRED + t] =
        red2[t] + red2[2*NRED+t] + red2[4*NRED+t] + red2[6*NRED+t];
  }
}

// ---------------- combined bn3 + adapt_bn affine (from dsum[24]) ----------------
__global__ void k_bnfinal(const double* __restrict__ dsum,
                          const float* __restrict__ g3, const float* __restrict__ b3,
                          const float* __restrict__ ag, const float* __restrict__ ab,
                          float* __restrict__ stats) {
  int c = threadIdx.x;
  if (c >= 12) return;
  (void)b3; // bn3 beta cancels exactly in the composed affine
  double m = dsum[c] / (double)SAMP;
  double v = dsum[12 + c] / (double)SAMP - m*m;
  float r1 = rsqrtf((float)v + 1e-5f);
  float vt = g3[c]*g3[c]*(float)v*r1*r1;
  float r2 = rsqrtf(vt + 1e-5f);
  float A = g3[c]*ag[c]*r1*r2;
  stats[144 + c] = A;
  stats[156 + c] = ab[c] - (float)m*A;
}

// ---------------- PV: O = attn_r @ V -> out_pre [B,N,C] ----------------
__global__ __launch_bounds__(256) void k_pv(const float* __restrict__ attn_r,
                                            const float* __restrict__ vbuf,
                                            float* __restrict__ out_pre) {
  __shared__ float Vs[196*65];
  __shared__ float ar_s[16*200];
  const int t = threadIdx.x;
  const int bh = blockIdx.x;
  const int b = bh / 12, h = bh - b*12;
  const float* vp = vbuf + (size_t)bh * Nn * Dd;
#pragma unroll
  for (int i = 0; i < 49; i++) {
    int idx = t + i*256;
    Vs[(idx >> 6)*65 + (idx & 63)] = vp[idx];
  }
  const float* arp = attn_r + (size_t)bh * NN2;
  const int dd = t & 63, wy = t >> 6;
  for (int ch = 0; ch < 13; ch++) {
    const int r0 = ch*16;
    const int nrows = (r0 + 16 <= 196) ? 16 : (196 - r0);
    __syncthreads();
    for (int idx = t; idx < nrows*196; idx += 256) {
      int rr = idx / 196, m = idx - rr*196;
      ar_s[rr*200 + m] = arp[(size_t)(r0+rr)*196 + m];
    }
    __syncthreads();
    float acc[4] = {0,0,0,0};
#pragma unroll 2
    for (int m = 0; m < 196; m++) {
      float vv = Vs[m*65 + dd];
#pragma unroll
      for (int r = 0; r < 4; r++) acc[r] = fmaf(ar_s[(wy*4+r)*200 + m], vv, acc[r]);
    }
#pragma unroll
    for (int r = 0; r < 4; r++) {
      int rr = wy*4 + r;
      if (rr < nrows)
        out_pre[((size_t)(b*196 + r0 + rr))*Cc + h*64 + dd] = acc[r];
    }
  }
}

// ---------------- launch ----------------
extern "C" void kernel_launch(void* const* d_in, const int* in_sizes, int n_in,
                              void* d_out, int out_size, void* d_ws, size_t ws_size,
                              hipStream_t stream) {
  (void)in_sizes; (void)n_in; (void)out_size; (void)ws_size;
  const float* x      = (const float*)d_in[0];
  const float* w_qkv  = (const float*)d_in[1];
  const float* w_exp  = (const float*)d_in[2];
  const float* bn1_g  = (const float*)d_in[3];
  const float* bn1_b  = (const float*)d_in[4];
  const float* w_dw   = (const float*)d_in[5];
  const float* bn2_g  = (const float*)d_in[6];
  const float* bn2_b  = (const float*)d_in[7];
  const float* w_pro  = (const float*)d_in[8];
  const float* bn3_g  = (const float*)d_in[9];
  const float* bn3_b  = (const float*)d_in[10];
  const float* abn_g  = (const float*)d_in[11];
  const float* abn_b  = (const float*)d_in[12];
  const float* w_proj = (const float*)d_in[13];
  const float* b_proj = (const float*)d_in[14];

  float* out      = (float*)d_out;
  float* attn_out = out + (size_t)QSZ;     // d_out's attn_r region (also S scratch)
  float* ws    = (float*)d_ws;
  float* vbuf  = ws;                        // [QSZ]
  float* big   = ws + (size_t)QSZ;          // [ATT]: q,k -> attn -> out_pre
  float* qbuf  = big;
  float* kbuf  = big + (size_t)QSZ;
  float* stats = ws + (size_t)QSZ + ATT;    // [256]
  float* part  = stats + 256;               // [6272*72]
  double* dsum = (double*)(part + (size_t)6272*72); // [96] doubles (8B-aligned)

  k_gemm_qkv <<<dim3(36, 98), 256, 0, stream>>>(x, w_qkv, qbuf, kbuf, vbuf);
  k_qk       <<<dim3(384, 7, 7), 256, 0, stream>>>(qbuf, kbuf, attn_out);   // S -> d_out scratch
  k_softmax  <<<18816, 256, 0, stream>>>(attn_out, big);                    // attn -> ws (q,k dead)
  k_y1stats  <<<1024, 256, 0, stream>>>(big, w_exp, part);
  k_reduce   <<<72, 256, 0, stream>>>(part, 1024, 72, dsum);
  k_bnaffine36<<<1, 64, 0, stream>>>(dsum, bn1_g, bn1_b, stats, 0);
  k_dla<0>   <<<6272, 256, 0, stream>>>(big, w_exp, w_dw, nullptr, stats, nullptr, part);
  k_reduce   <<<72, 256, 0, stream>>>(part, 6272, 72, dsum);
  k_bnaffine36<<<1, 64, 0, stream>>>(dsum, bn2_g, bn2_b, stats, 72);
  k_dla<1>   <<<6272, 256, 0, stream>>>(big, w_exp, w_dw, w_pro, stats, nullptr, part);
  k_reduce   <<<24, 256, 0, stream>>>(part, 6272, 24, dsum);
  k_bnfinal  <<<1, 64, 0, stream>>>(dsum, bn3_g, bn3_b, abn_g, abn_b, stats);
  k_dla<2>   <<<6272, 256, 0, stream>>>(big, w_exp, w_dw, w_pro, stats, attn_out, nullptr);
  k_pv       <<<384, 256, 0, stream>>>(attn_out, vbuf, big);                // out_pre -> big[0..QSZ)
  k_gemm_proj<<<dim3(12, 98), 256, 0, stream>>>(big, w_proj, b_proj, out);
}

// Round 4
// 1360.638 us; speedup vs baseline: 2.7603x; 1.1780x over previous
//
#include <hip/hip_runtime.h>
#include <math.h>

// ---------------- problem constants ----------------
constexpr int Bz  = 32;
constexpr int Nn  = 196;
constexpr int Cc  = 768;
constexpr int Hh  = 12;
constexpr int Dd  = 64;
constexpr int HID = 36;           // Hh * 3
constexpr int NN2 = Nn * Nn;      // 38416
constexpr int QSZ = Bz * Nn * Cc;          // 4,816,896
constexpr int ATT = Bz * Hh * NN2;         // 14,751,744
constexpr int SAMP = Bz * NN2;    // 1,229,312 samples per BN channel
constexpr float RS = 0.35355339059327373f; // 64^-0.25

// ws layout (floats), peak ~80.3 MB:
//  [0, QSZ)            v [B,H,N,D]
//  [QSZ, QSZ+ATT)      "big" slot: q(+0), k(+QSZ) during qkv/qk; then attn
//                      (softmax output); then out_pre [B,N,C] (first QSZ)
//  [QSZ+ATT, +256)     stats: a1[36] b1[36] a2[36] b2[36] Af[12] Bf[12]
//  [+256, +6272*72)    partials
//  [then]              dsum[96] doubles

// ---------------- K1: qkv GEMM (f32, 64x64 tile) ----------------
__global__ __launch_bounds__(256) void k_gemm_qkv(const float* __restrict__ X,
                                                  const float* __restrict__ Wq,
                                                  float* __restrict__ qp,
                                                  float* __restrict__ kp,
                                                  float* __restrict__ vp) {
  __shared__ float As[16][68];
  __shared__ float Bs[16][68];
  const int t = threadIdx.x;
  const int tx = t & 15, ty = t >> 4;
  const int m0 = blockIdx.y * 64, n0 = blockIdx.x * 64;
  const int lrow = t >> 2, lkv = t & 3;
  float acc[4][4] = {};
  const float* ap = X + (size_t)(m0 + lrow) * Cc + lkv * 4;
  const float* bp = Wq + (size_t)(n0 + lrow) * Cc + lkv * 4;
  for (int k0 = 0; k0 < Cc; k0 += 16) {
    float4 av = *(const float4*)(ap + k0);
    float4 bv = *(const float4*)(bp + k0);
    __syncthreads();
    As[lkv*4+0][lrow] = av.x; As[lkv*4+1][lrow] = av.y;
    As[lkv*4+2][lrow] = av.z; As[lkv*4+3][lrow] = av.w;
    Bs[lkv*4+0][lrow] = bv.x; Bs[lkv*4+1][lrow] = bv.y;
    Bs[lkv*4+2][lrow] = bv.z; Bs[lkv*4+3][lrow] = bv.w;
    __syncthreads();
#pragma unroll
    for (int kk = 0; kk < 16; kk++) {
      float a[4], b[4];
      *(float4*)a = *(const float4*)&As[kk][ty*4];
      *(float4*)b = *(const float4*)&Bs[kk][tx*4];
#pragma unroll
      for (int i = 0; i < 4; i++)
#pragma unroll
        for (int j = 0; j < 4; j++) acc[i][j] = fmaf(a[i], b[j], acc[i][j]);
    }
  }
#pragma unroll
  for (int i = 0; i < 4; i++) {
    int mi = m0 + ty*4 + i;
    int b = mi / Nn, n = mi - b*Nn;
#pragma unroll
    for (int j = 0; j < 4; j++) {
      int nj = n0 + tx*4 + j;
      int three = nj / Cc;
      int rem = nj - three*Cc;
      int h = rem >> 6, dd = rem & 63;
      float v = acc[i][j] * (three < 2 ? RS : 1.0f);
      float* base = (three == 0) ? qp : (three == 1) ? kp : vp;
      base[((size_t)(b*Hh + h)*Nn + n)*Dd + dd] = v;
    }
  }
}

// ---------------- K7: proj GEMM (f32, 64x64 tile, +bias) ----------------
__global__ __launch_bounds__(256) void k_gemm_proj(const float* __restrict__ A_,
                                                   const float* __restrict__ Wp,
                                                   const float* __restrict__ bias,
                                                   float* __restrict__ out) {
  __shared__ float As[16][68];
  __shared__ float Bs[16][68];
  const int t = threadIdx.x;
  const int tx = t & 15, ty = t >> 4;
  const int m0 = blockIdx.y * 64, n0 = blockIdx.x * 64;
  const int lrow = t >> 2, lkv = t & 3;
  float acc[4][4] = {};
  const float* ap = A_ + (size_t)(m0 + lrow) * Cc + lkv * 4;
  const float* bp = Wp + (size_t)(n0 + lrow) * Cc + lkv * 4;
  for (int k0 = 0; k0 < Cc; k0 += 16) {
    float4 av = *(const float4*)(ap + k0);
    float4 bv = *(const float4*)(bp + k0);
    __syncthreads();
    As[lkv*4+0][lrow] = av.x; As[lkv*4+1][lrow] = av.y;
    As[lkv*4+2][lrow] = av.z; As[lkv*4+3][lrow] = av.w;
    Bs[lkv*4+0][lrow] = bv.x; Bs[lkv*4+1][lrow] = bv.y;
    Bs[lkv*4+2][lrow] = bv.z; Bs[lkv*4+3][lrow] = bv.w;
    __syncthreads();
#pragma unroll
    for (int kk = 0; kk < 16; kk++) {
      float a[4], b[4];
      *(float4*)a = *(const float4*)&As[kk][ty*4];
      *(float4*)b = *(const float4*)&Bs[kk][tx*4];
#pragma unroll
      for (int i = 0; i < 4; i++)
#pragma unroll
        for (int j = 0; j < 4; j++) acc[i][j] = fmaf(a[i], b[j], acc[i][j]);
    }
  }
#pragma unroll
  for (int i = 0; i < 4; i++) {
    int mi = m0 + ty*4 + i;
#pragma unroll
    for (int j = 0; j < 4; j++) {
      int nj = n0 + tx*4 + j;
      out[(size_t)mi*Cc + nj] = acc[i][j] + bias[nj];
    }
  }
}

// ---------------- K2a: S = Q K^T (batched, 32x32 tiles) ----------------
__global__ __launch_bounds__(256) void k_qk(const float* __restrict__ qbuf,
                                            const float* __restrict__ kbuf,
                                            float* __restrict__ S) {
  __shared__ float Qs[32][68];
  __shared__ float Ks[32][68];
  const int t = threadIdx.x;
  const int bh = blockIdx.x;
  const int r0 = blockIdx.y * 32, c0 = blockIdx.z * 32;
  const float* qp = qbuf + (size_t)bh * Nn * Dd;
  const float* kp = kbuf + (size_t)bh * Nn * Dd;
#pragma unroll
  for (int i = 0; i < 2; i++) {
    int idx = t + i*256;            // float4 index
    int row = idx >> 4, kv = idx & 15;
    float4 qv = make_float4(0,0,0,0), kk4 = make_float4(0,0,0,0);
    int gr = r0 + row;
    if (gr < Nn) qv = *(const float4*)(qp + (size_t)gr*Dd + kv*4);
    int gc = c0 + row;
    if (gc < Nn) kk4 = *(const float4*)(kp + (size_t)gc*Dd + kv*4);
    *(float4*)&Qs[row][kv*4] = qv;
    *(float4*)&Ks[row][kv*4] = kk4;
  }
  __syncthreads();
  const int tx = t & 15, ty = t >> 4;
  float acc[2][2] = {};
#pragma unroll
  for (int kk = 0; kk < 64; kk++) {
    float a0 = Qs[ty*2+0][kk], a1 = Qs[ty*2+1][kk];
    float b0 = Ks[tx*2+0][kk], b1 = Ks[tx*2+1][kk];
    acc[0][0] = fmaf(a0,b0,acc[0][0]); acc[0][1] = fmaf(a0,b1,acc[0][1]);
    acc[1][0] = fmaf(a1,b0,acc[1][0]); acc[1][1] = fmaf(a1,b1,acc[1][1]);
  }
#pragma unroll
  for (int i = 0; i < 2; i++) {
    int rr = r0 + ty*2 + i;
    if (rr >= Nn) continue;
#pragma unroll
    for (int j = 0; j < 2; j++) {
      int cc2 = c0 + tx*2 + j;
      if (cc2 < Nn) S[((size_t)bh*Nn + rr)*Nn + cc2] = acc[i][j];
    }
  }
}

// ---------------- K2b: row softmax, src -> dst ----------------
__global__ __launch_bounds__(256) void k_softmax(const float* __restrict__ src,
                                                 float* __restrict__ dst) {
  const int row = blockIdx.x*4 + (threadIdx.x >> 6);
  const int lane = threadIdx.x & 63;
  const float* p = src + (size_t)row * Nn;
  float* o = dst + (size_t)row * Nn;
  float v[4];
  float mx = -1e30f;
#pragma unroll
  for (int i = 0; i < 4; i++) {
    int m = lane + i*64;
    v[i] = (m < Nn) ? p[m] : -1e30f;
    mx = fmaxf(mx, v[i]);
  }
#pragma unroll
  for (int off = 32; off; off >>= 1) mx = fmaxf(mx, __shfl_xor(mx, off, 64));
  float sum = 0.0f;
#pragma unroll
  for (int i = 0; i < 4; i++) {
    int m = lane + i*64;
    v[i] = (m < Nn) ? __expf(v[i]-mx) : 0.0f;
    sum += v[i];
  }
#pragma unroll
  for (int off = 32; off; off >>= 1) sum += __shfl_xor(sum, off, 64);
  float inv = 1.0f / sum;
#pragma unroll
  for (int i = 0; i < 4; i++) {
    int m = lane + i*64;
    if (m < Nn) o[m] = v[i]*inv;
  }
}

// ---------------- K3: y1 = conv_exp(attn) stats (recompute, no store) ----------------
__global__ __launch_bounds__(256) void k_y1stats(const float* __restrict__ attn,
                                                 const float* __restrict__ w_exp,
                                                 float* __restrict__ part) {
  __shared__ float wse[HID*Hh];
  __shared__ float red2[4*72];
  const int t = threadIdx.x;
  for (int i = t; i < HID*Hh; i += 256) wse[i] = w_exp[i];
  __syncthreads();
  float s1[36] = {}, s2[36] = {};
  const int stride = gridDim.x * 256;
  for (int s = blockIdx.x*256 + t; s < SAMP; s += stride) {
    int b = s / NN2, p = s - b*NN2;
    float a[12];
#pragma unroll
    for (int h = 0; h < 12; h++) a[h] = attn[((size_t)(b*12+h))*NN2 + p];
#pragma unroll
    for (int c = 0; c < 36; c++) {
      float y = 0.0f;
#pragma unroll
      for (int h = 0; h < 12; h++) y = fmaf(wse[c*12+h], a[h], y);
      s1[c] += y; s2[c] += y*y;
    }
  }
#pragma unroll
  for (int c = 0; c < 36; c++) {
#pragma unroll
    for (int off = 32; off; off >>= 1) {
      s1[c] += __shfl_xor(s1[c], off, 64);
      s2[c] += __shfl_xor(s2[c], off, 64);
    }
  }
  const int w = t >> 6;
  if ((t & 63) == 0) {
#pragma unroll
    for (int c = 0; c < 36; c++) { red2[w*72 + c] = s1[c]; red2[w*72 + 36 + c] = s2[c]; }
  }
  __syncthreads();
  if (t < 72)
    part[(size_t)blockIdx.x*72 + t] = red2[t] + red2[72+t] + red2[144+t] + red2[216+t];
}

// ---------------- hierarchical deterministic reduce: part[nb][stride] -> dsum[stride] ----------------
__global__ __launch_bounds__(256) void k_reduce(const float* __restrict__ part, int nb,
                                               int stride, double* __restrict__ dsum) {
  __shared__ double sh[256];
  const int c = blockIdx.x;       // one block per channel-stat
  const int t = threadIdx.x;
  double s = 0.0;
  for (int i = t; i < nb; i += 256) s += (double)part[(size_t)i*stride + c];
  sh[t] = s;
  __syncthreads();
  for (int o = 128; o; o >>= 1) {
    if (t < o) sh[t] += sh[t + o];
    __syncthreads();
  }
  if (t == 0) dsum[c] = sh[0];
}

// ---------------- dsum -> BN affine (36 ch) ----------------
__global__ void k_bnaffine36(const double* __restrict__ dsum,
                             const float* __restrict__ g, const float* __restrict__ beta,
                             float* __restrict__ stats, int off) {
  int c = threadIdx.x;
  if (c >= 36) return;
  double m = dsum[c] / (double)SAMP;
  double v = dsum[36 + c] / (double)SAMP - m*m;
  float a = g[c] * rsqrtf((float)v + 1e-5f);
  stats[off + c] = a;
  stats[off + 36 + c] = beta[c] - (float)m * a;
}

// ---- tiled DLA recompute, channel-chunked (3 groups of 12).
// MODE 0: y2 stats -> part[blk][72].  MODE 1: z write (to zout) + z stats -> part[blk][24].
template<int MODE>
__global__ __launch_bounds__(256) void k_dla(const float* __restrict__ attn,
                                             const float* __restrict__ w_exp,
                                             const float* __restrict__ w_dw,
                                             const float* __restrict__ w_pro,
                                             const float* __restrict__ stats,
                                             float* __restrict__ zout,
                                             float* __restrict__ part) {
  __shared__ float a_s[12*256];
  __shared__ float y_s[12*256];
  __shared__ float wse[432];
  __shared__ float wdw[324];
  __shared__ float wpr[432];
  __shared__ float aff[144];
  __shared__ float red2[4*24];
  const int t = threadIdx.x;
  const int blk = blockIdx.x;
  const int b = blk / 196, tile = blk - b*196;
  const int tyq = tile / 14;
  const int ty0 = tyq * 14, tx0 = (tile - tyq*14) * 14;
  for (int i = t; i < 432; i += 256) wse[i] = w_exp[i];
  for (int i = t; i < 324; i += 256) wdw[i] = w_dw[i];
  if (MODE == 1) for (int i = t; i < 432; i += 256) wpr[i] = w_pro[i];
  if (t < 144) aff[t] = stats[t];
  // this thread's halo coordinate (pos = t in the 16x16 halo)
  const int hy = ty0 + (t >> 4) - 1, hx = tx0 + (t & 15) - 1;
  const bool inb = (hy >= 0) && (hy < 196) && (hx >= 0) && (hx < 196);
  // halo load: attn [12][16][16] (zero outside image)
#pragma unroll
  for (int ch = 0; ch < 12; ch++)
    a_s[ch*256 + t] = inb ? attn[((size_t)(b*12+ch))*NN2 + (size_t)hy*196 + hx] : 0.0f;

  const bool act = (t < 196);
  const int py = t / 14, px = t - py*14;
  const int base = (py+1)*16 + (px+1);
  const int w = t >> 6;
  float z[12] = {};

  for (int g = 0; g < 3; g++) {
    __syncthreads();   // a_s ready (g=0) / prev group's y_s & red2 reads done
    // y1c = clip(bn1(conv_exp)) for this group's 12 channels; 0 outside image
#pragma unroll
    for (int cl = 0; cl < 12; cl++) {
      const int c = g*12 + cl;
      float y = 0.0f;
#pragma unroll
      for (int h = 0; h < 12; h++) y = fmaf(wse[c*12+h], a_s[h*256+t], y);
      y = y*aff[c] + aff[36+c];
      y = fminf(fmaxf(y, 0.0f), 6.0f);
      y_s[cl*256 + t] = inb ? y : 0.0f;
    }
    __syncthreads();
    float s1g[12], s2g[12];
#pragma unroll
    for (int cl = 0; cl < 12; cl++) { s1g[cl] = 0.0f; s2g[cl] = 0.0f; }
    if (act) {
#pragma unroll
      for (int cl = 0; cl < 12; cl++) {
        const int c = g*12 + cl;
        const float* ys = &y_s[cl*256];
        const float* wd = &wdw[c*9];
        float y2 = 0.0f;
#pragma unroll
        for (int di = 0; di < 3; di++)
#pragma unroll
          for (int dj = 0; dj < 3; dj++)
            y2 = fmaf(wd[di*3+dj], ys[base + (di-1)*16 + (dj-1)], y2);
        if (MODE == 0) { s1g[cl] = y2; s2g[cl] = y2*y2; }
        else {
          float y2c = y2*aff[72+c] + aff[108+c];
          y2c = fminf(fmaxf(y2c, 0.0f), 6.0f);
#pragma unroll
          for (int cc = 0; cc < 12; cc++) z[cc] = fmaf(wpr[cc*36+c], y2c, z[cc]);
        }
      }
    }
    if (MODE == 0) {
#pragma unroll
      for (int cl = 0; cl < 12; cl++) {
#pragma unroll
        for (int off = 32; off; off >>= 1) {
          s1g[cl] += __shfl_xor(s1g[cl], off, 64);
          s2g[cl] += __shfl_xor(s2g[cl], off, 64);
        }
      }
      if ((t & 63) == 0) {
#pragma unroll
        for (int cl = 0; cl < 12; cl++) {
          red2[w*24 + cl] = s1g[cl];
          red2[w*24 + 12 + cl] = s2g[cl];
        }
      }
      __syncthreads();
      if (t < 24) {
        float v = red2[t] + red2[24+t] + red2[48+t] + red2[72+t];
        int cl = (t < 12) ? t : (t - 12);
        int off36 = (t < 12) ? 0 : 36;
        part[(size_t)blk*72 + off36 + g*12 + cl] = v;
      }
    }
  }

  if (MODE == 1) {
    float s1g[12], s2g[12];
    if (act) {
      const int oy = ty0 + py, ox = tx0 + px;
#pragma unroll
      for (int cc = 0; cc < 12; cc++) {
        zout[((size_t)(b*12+cc))*NN2 + (size_t)oy*196 + ox] = z[cc];
        s1g[cc] = z[cc]; s2g[cc] = z[cc]*z[cc];
      }
    } else {
#pragma unroll
      for (int cc = 0; cc < 12; cc++) { s1g[cc] = 0.0f; s2g[cc] = 0.0f; }
    }
#pragma unroll
    for (int cc = 0; cc < 12; cc++) {
#pragma unroll
      for (int off = 32; off; off >>= 1) {
        s1g[cc] += __shfl_xor(s1g[cc], off, 64);
        s2g[cc] += __shfl_xor(s2g[cc], off, 64);
      }
    }
    __syncthreads();   // y_s/red2 free
    if ((t & 63) == 0) {
#pragma unroll
      for (int cc = 0; cc < 12; cc++) {
        red2[w*24 + cc] = s1g[cc];
        red2[w*24 + 12 + cc] = s2g[cc];
      }
    }
    __syncthreads();
    if (t < 24)
      part[(size_t)blk*24 + t] = red2[t] + red2[24+t] + red2[48+t] + red2[72+t];
  }
}

// ---------------- combined bn3 + adapt_bn affine (from dsum[24]) ----------------
__global__ void k_bnfinal(const double* __restrict__ dsum,
                          const float* __restrict__ g3, const float* __restrict__ b3,
                          const float* __restrict__ ag, const float* __restrict__ ab,
                          float* __restrict__ stats) {
  int c = threadIdx.x;
  if (c >= 12) return;
  (void)b3; // bn3 beta cancels exactly in the composed affine
  double m = dsum[c] / (double)SAMP;
  double v = dsum[12 + c] / (double)SAMP - m*m;
  float r1 = rsqrtf((float)v + 1e-5f);
  float vt = g3[c]*g3[c]*(float)v*r1*r1;
  float r2 = rsqrtf(vt + 1e-5f);
  float A = g3[c]*ag[c]*r1*r2;
  stats[144 + c] = A;
  stats[156 + c] = ab[c] - (float)m*A;
}

// ---------------- in-place final affine on z -> attn_r ----------------
__global__ __launch_bounds__(256) void k_zaffine(float* __restrict__ z,
                                                 const float* __restrict__ stats) {
  const unsigned j = blockIdx.x*256 + threadIdx.x;   // float4 index, ATT/4 total
  const unsigned i = j*4;                             // element index
  const int ch = (int)((i / (unsigned)NN2) % 12u);
  const float A = stats[144 + ch], Bc = stats[156 + ch];
  float4 v = ((float4*)z)[j];
  v.x = fmaf(v.x, A, Bc); v.y = fmaf(v.y, A, Bc);
  v.z = fmaf(v.z, A, Bc); v.w = fmaf(v.w, A, Bc);
  ((float4*)z)[j] = v;
}

// ---------------- PV: O = attn_r @ V -> out_pre [B,N,C] ----------------
__global__ __launch_bounds__(256) void k_pv(const float* __restrict__ attn_r,
                                            const float* __restrict__ vbuf,
                                            float* __restrict__ out_pre) {
  __shared__ float Vs[196*65];
  __shared__ float ar_s[16*200];
  const int t = threadIdx.x;
  const int bh = blockIdx.x;
  const int b = bh / 12, h = bh - b*12;
  const float* vp = vbuf + (size_t)bh * Nn * Dd;
#pragma unroll
  for (int i = 0; i < 49; i++) {
    int idx = t + i*256;
    Vs[(idx >> 6)*65 + (idx & 63)] = vp[idx];
  }
  const float* arp = attn_r + (size_t)bh * NN2;
  const int dd = t & 63, wy = t >> 6;
  for (int ch = 0; ch < 13; ch++) {
    const int r0 = ch*16;
    const int nrows = (r0 + 16 <= 196) ? 16 : (196 - r0);
    __syncthreads();
    for (int idx = t; idx < nrows*196; idx += 256) {
      int rr = idx / 196, m = idx - rr*196;
      ar_s[rr*200 + m] = arp[(size_t)(r0+rr)*196 + m];
    }
    __syncthreads();
    float acc[4] = {0,0,0,0};
#pragma unroll 2
    for (int m = 0; m < 196; m++) {
      float vv = Vs[m*65 + dd];
#pragma unroll
      for (int r = 0; r < 4; r++) acc[r] = fmaf(ar_s[(wy*4+r)*200 + m], vv, acc[r]);
    }
#pragma unroll
    for (int r = 0; r < 4; r++) {
      int rr = wy*4 + r;
      if (rr < nrows)
        out_pre[((size_t)(b*196 + r0 + rr))*Cc + h*64 + dd] = acc[r];
    }
  }
}

// ---------------- launch ----------------
extern "C" void kernel_launch(void* const* d_in, const int* in_sizes, int n_in,
                              void* d_out, int out_size, void* d_ws, size_t ws_size,
                              hipStream_t stream) {
  (void)in_sizes; (void)n_in; (void)out_size; (void)ws_size;
  const float* x      = (const float*)d_in[0];
  const float* w_qkv  = (const float*)d_in[1];
  const float* w_exp  = (const float*)d_in[2];
  const float* bn1_g  = (const float*)d_in[3];
  const float* bn1_b  = (const float*)d_in[4];
  const float* w_dw   = (const float*)d_in[5];
  const float* bn2_g  = (const float*)d_in[6];
  const float* bn2_b  = (const float*)d_in[7];
  const float* w_pro  = (const float*)d_in[8];
  const float* bn3_g  = (const float*)d_in[9];
  const float* bn3_b  = (const float*)d_in[10];
  const float* abn_g  = (const float*)d_in[11];
  const float* abn_b  = (const float*)d_in[12];
  const float* w_proj = (const float*)d_in[13];
  const float* b_proj = (const float*)d_in[14];

  float* out      = (float*)d_out;
  float* attn_out = out + (size_t)QSZ;     // d_out's attn_r region (S scratch -> z -> attn_r)
  float* ws    = (float*)d_ws;
  float* vbuf  = ws;                        // [QSZ]
  float* big   = ws + (size_t)QSZ;          // [ATT]: q,k -> attn -> out_pre
  float* qbuf  = big;
  float* kbuf  = big + (size_t)QSZ;
  float* stats = ws + (size_t)QSZ + ATT;    // [256]
  float* part  = stats + 256;               // [6272*72]
  double* dsum = (double*)(part + (size_t)6272*72); // [96] doubles (8B-aligned)

  k_gemm_qkv <<<dim3(36, 98), 256, 0, stream>>>(x, w_qkv, qbuf, kbuf, vbuf);
  k_qk       <<<dim3(384, 7, 7), 256, 0, stream>>>(qbuf, kbuf, attn_out);   // S -> d_out scratch
  k_softmax  <<<18816, 256, 0, stream>>>(attn_out, big);                    // attn -> ws (q,k dead)
  k_y1stats  <<<1024, 256, 0, stream>>>(big, w_exp, part);
  k_reduce   <<<72, 256, 0, stream>>>(part, 1024, 72, dsum);
  k_bnaffine36<<<1, 64, 0, stream>>>(dsum, bn1_g, bn1_b, stats, 0);
  k_dla<0>   <<<6272, 256, 0, stream>>>(big, w_exp, w_dw, nullptr, stats, nullptr, part);
  k_reduce   <<<72, 256, 0, stream>>>(part, 6272, 72, dsum);
  k_bnaffine36<<<1, 64, 0, stream>>>(dsum, bn2_g, bn2_b, stats, 72);
  k_dla<1>   <<<6272, 256, 0, stream>>>(big, w_exp, w_dw, w_pro, stats, attn_out, part);
  k_reduce   <<<24, 256, 0, stream>>>(part, 6272, 24, dsum);
  k_bnfinal  <<<1, 64, 0, stream>>>(dsum, bn3_g, bn3_b, abn_g, abn_b, stats);
  k_zaffine  <<<ATT/1024, 256, 0, stream>>>(attn_out, stats);               // z -> attn_r in place
  k_pv       <<<384, 256, 0, stream>>>(attn_out, vbuf, big);                // out_pre -> big[0..QSZ)
  k_gemm_proj<<<dim3(12, 98), 256, 0, stream>>>(big, w_proj, b_proj, out);
}

// Round 5
// 987.503 us; speedup vs baseline: 3.8034x; 1.3779x over previous
//
#include <hip/hip_runtime.h>
#include <hip/hip_bf16.h>
#include <math.h>

// ---------------- problem constants ----------------
constexpr int Bz  = 32;
constexpr int Nn  = 196;
constexpr int Cc  = 768;
constexpr int Hh  = 12;
constexpr int Dd  = 64;
constexpr int HID = 36;           // Hh * 3
constexpr int NN2 = Nn * Nn;      // 38416
constexpr int QSZ = Bz * Nn * Cc;          // 4,816,896
constexpr int ATT = Bz * Hh * NN2;         // 14,751,744
constexpr int SAMP = Bz * NN2;    // 1,229,312 samples per BN channel
constexpr float RS = 0.35355339059327373f; // 64^-0.25

typedef short bf16x8 __attribute__((ext_vector_type(8)));
typedef float f32x4  __attribute__((ext_vector_type(4)));

__device__ inline ushort f2b(float f) {
  __hip_bfloat16 h = __float2bfloat16(f);
  return *reinterpret_cast<ushort*>(&h);
}

// ---------------- f32 -> bf16 cast (8 elems/thread) ----------------
__global__ __launch_bounds__(256) void k_cast(const float* __restrict__ in,
                                              ushort* __restrict__ outp) {
  const int j = blockIdx.x*256 + threadIdx.x;       // 8-elem group
  float4 a = ((const float4*)in)[2*j];
  float4 b = ((const float4*)in)[2*j+1];
  ushort o[8] = { f2b(a.x), f2b(a.y), f2b(a.z), f2b(a.w),
                  f2b(b.x), f2b(b.y), f2b(b.z), f2b(b.w) };
  ((uint4*)outp)[j] = *(const uint4*)o;
}

// ---------------- bf16 MFMA GEMM: C = A[M,768] x B[N,768]^T ----------------
// EPI 0: qkv epilogue (RS scale on q,k; scatter to [B,H,N,D]); EPI 1: +bias, row-major out
template<int EPI>
__global__ __launch_bounds__(256) void k_mfma_gemm(const ushort* __restrict__ A,
                                                   const ushort* __restrict__ B,
                                                   const float* __restrict__ bias,
                                                   float* __restrict__ p0,
                                                   float* __restrict__ p1,
                                                   float* __restrict__ p2) {
  __shared__ ushort As[128*72];   // 128 rows x 64 k, stride 72 (pad kills bank conflicts)
  __shared__ ushort Bs[128*72];
  const int t = threadIdx.x;
  const int m0 = blockIdx.y*128, n0 = blockIdx.x*128;
  const int w = t>>6, lane = t&63;
  const int wr = w>>1, wc = w&1;         // wave -> 64x64 quadrant
  const int lrow = lane&15, lkb = lane>>4;
  f32x4 acc[4][4] = {};
  const int srow = t>>1, skoff = (t&1)*32;
  const ushort* aP = A + (size_t)(m0+srow)*768 + skoff;
  const ushort* bP = B + (size_t)(n0+srow)*768 + skoff;
  ushort* aw = &As[srow*72 + skoff];
  ushort* bw = &Bs[srow*72 + skoff];
  for (int k0 = 0; k0 < 768; k0 += 64) {
    uint4 a0 = *(const uint4*)(aP+k0),    a1 = *(const uint4*)(aP+k0+8);
    uint4 a2 = *(const uint4*)(aP+k0+16), a3 = *(const uint4*)(aP+k0+24);
    uint4 b0 = *(const uint4*)(bP+k0),    b1 = *(const uint4*)(bP+k0+8);
    uint4 b2 = *(const uint4*)(bP+k0+16), b3 = *(const uint4*)(bP+k0+24);
    __syncthreads();
    *(uint4*)(aw)    = a0; *(uint4*)(aw+8)  = a1;
    *(uint4*)(aw+16) = a2; *(uint4*)(aw+24) = a3;
    *(uint4*)(bw)    = b0; *(uint4*)(bw+8)  = b1;
    *(uint4*)(bw+16) = b2; *(uint4*)(bw+24) = b3;
    __syncthreads();
#pragma unroll
    for (int kk = 0; kk < 2; kk++) {
      bf16x8 af[4], bfr[4];
#pragma unroll
      for (int m = 0; m < 4; m++)
        af[m] = *(const bf16x8*)&As[(wr*64+m*16+lrow)*72 + kk*32 + lkb*8];
#pragma unroll
      for (int n = 0; n < 4; n++)
        bfr[n] = *(const bf16x8*)&Bs[(wc*64+n*16+lrow)*72 + kk*32 + lkb*8];
#pragma unroll
      for (int m = 0; m < 4; m++)
#pragma unroll
        for (int n = 0; n < 4; n++)
          acc[m][n] = __builtin_amdgcn_mfma_f32_16x16x32_bf16(af[m], bfr[n], acc[m][n], 0, 0, 0);
    }
  }
  const int r4 = lane>>4;
#pragma unroll
  for (int m = 0; m < 4; m++) {
#pragma unroll
    for (int r = 0; r < 4; r++) {
      const int grow = m0 + wr*64 + m*16 + r4*4 + r;
      if (EPI == 0) {
        const int b = grow/196, nn = grow - b*196;
#pragma unroll
        for (int n = 0; n < 4; n++) {
          const int gcol = n0 + wc*64 + n*16 + lrow;
          const int three = gcol/768, rem = gcol - three*768;
          const int h = rem>>6, dd = rem&63;
          float v = acc[m][n][r] * (three < 2 ? RS : 1.0f);
          float* base = (three == 0) ? p0 : (three == 1) ? p1 : p2;
          base[((size_t)(b*12+h)*196 + nn)*64 + dd] = v;
        }
      } else {
#pragma unroll
        for (int n = 0; n < 4; n++) {
          const int gcol = n0 + wc*64 + n*16 + lrow;
          p0[(size_t)grow*768 + gcol] = acc[m][n][r] + bias[gcol];
        }
      }
    }
  }
}

// ---------------- K2a: S = Q K^T (batched, 32x32 tiles) ----------------
__global__ __launch_bounds__(256) void k_qk(const float* __restrict__ qbuf,
                                            const float* __restrict__ kbuf,
                                            float* __restrict__ S) {
  __shared__ float Qs[32][68];
  __shared__ float Ks[32][68];
  const int t = threadIdx.x;
  const int bh = blockIdx.x;
  const int r0 = blockIdx.y * 32, c0 = blockIdx.z * 32;
  const float* qp = qbuf + (size_t)bh * Nn * Dd;
  const float* kp = kbuf + (size_t)bh * Nn * Dd;
#pragma unroll
  for (int i = 0; i < 2; i++) {
    int idx = t + i*256;            // float4 index
    int row = idx >> 4, kv = idx & 15;
    float4 qv = make_float4(0,0,0,0), kk4 = make_float4(0,0,0,0);
    int gr = r0 + row;
    if (gr < Nn) qv = *(const float4*)(qp + (size_t)gr*Dd + kv*4);
    int gc = c0 + row;
    if (gc < Nn) kk4 = *(const float4*)(kp + (size_t)gc*Dd + kv*4);
    *(float4*)&Qs[row][kv*4] = qv;
    *(float4*)&Ks[row][kv*4] = kk4;
  }
  __syncthreads();
  const int tx = t & 15, ty = t >> 4;
  float acc[2][2] = {};
#pragma unroll
  for (int kk = 0; kk < 64; kk++) {
    float a0 = Qs[ty*2+0][kk], a1 = Qs[ty*2+1][kk];
    float b0 = Ks[tx*2+0][kk], b1 = Ks[tx*2+1][kk];
    acc[0][0] = fmaf(a0,b0,acc[0][0]); acc[0][1] = fmaf(a0,b1,acc[0][1]);
    acc[1][0] = fmaf(a1,b0,acc[1][0]); acc[1][1] = fmaf(a1,b1,acc[1][1]);
  }
#pragma unroll
  for (int i = 0; i < 2; i++) {
    int rr = r0 + ty*2 + i;
    if (rr >= Nn) continue;
#pragma unroll
    for (int j = 0; j < 2; j++) {
      int cc2 = c0 + tx*2 + j;
      if (cc2 < Nn) S[((size_t)bh*Nn + rr)*Nn + cc2] = acc[i][j];
    }
  }
}

// ---------------- K2b: row softmax, src -> dst ----------------
__global__ __launch_bounds__(256) void k_softmax(const float* __restrict__ src,
                                                 float* __restrict__ dst) {
  const int row = blockIdx.x*4 + (threadIdx.x >> 6);
  const int lane = threadIdx.x & 63;
  const float* p = src + (size_t)row * Nn;
  float* o = dst + (size_t)row * Nn;
  float v[4];
  float mx = -1e30f;
#pragma unroll
  for (int i = 0; i < 4; i++) {
    int m = lane + i*64;
    v[i] = (m < Nn) ? p[m] : -1e30f;
    mx = fmaxf(mx, v[i]);
  }
#pragma unroll
  for (int off = 32; off; off >>= 1) mx = fmaxf(mx, __shfl_xor(mx, off, 64));
  float sum = 0.0f;
#pragma unroll
  for (int i = 0; i < 4; i++) {
    int m = lane + i*64;
    v[i] = (m < Nn) ? __expf(v[i]-mx) : 0.0f;
    sum += v[i];
  }
#pragma unroll
  for (int off = 32; off; off >>= 1) sum += __shfl_xor(sum, off, 64);
  float inv = 1.0f / sum;
#pragma unroll
  for (int i = 0; i < 4; i++) {
    int m = lane + i*64;
    if (m < Nn) o[m] = v[i]*inv;
  }
}

// ---------------- K3: y1 = conv_exp(attn) stats (recompute, no store) ----------------
__global__ __launch_bounds__(256) void k_y1stats(const float* __restrict__ attn,
                                                 const float* __restrict__ w_exp,
                                                 float* __restrict__ part) {
  __shared__ float wse[HID*Hh];
  __shared__ float red2[4*72];
  const int t = threadIdx.x;
  for (int i = t; i < HID*Hh; i += 256) wse[i] = w_exp[i];
  __syncthreads();
  float s1[36] = {}, s2[36] = {};
  const int stride = gridDim.x * 256;
  for (int s = blockIdx.x*256 + t; s < SAMP; s += stride) {
    int b = s / NN2, p = s - b*NN2;
    float a[12];
#pragma unroll
    for (int h = 0; h < 12; h++) a[h] = attn[((size_t)(b*12+h))*NN2 + p];
#pragma unroll
    for (int c = 0; c < 36; c++) {
      float y = 0.0f;
#pragma unroll
      for (int h = 0; h < 12; h++) y = fmaf(wse[c*12+h], a[h], y);
      s1[c] += y; s2[c] += y*y;
    }
  }
#pragma unroll
  for (int c = 0; c < 36; c++) {
#pragma unroll
    for (int off = 32; off; off >>= 1) {
      s1[c] += __shfl_xor(s1[c], off, 64);
      s2[c] += __shfl_xor(s2[c], off, 64);
    }
  }
  const int w = t >> 6;
  if ((t & 63) == 0) {
#pragma unroll
    for (int c = 0; c < 36; c++) { red2[w*72 + c] = s1[c]; red2[w*72 + 36 + c] = s2[c]; }
  }
  __syncthreads();
  if (t < 72)
    part[(size_t)blockIdx.x*72 + t] = red2[t] + red2[72+t] + red2[144+t] + red2[216+t];
}

// ---------------- hierarchical deterministic reduce: part[nb][stride] -> dsum[stride] ----------------
__global__ __launch_bounds__(256) void k_reduce(const float* __restrict__ part, int nb,
                                               int stride, double* __restrict__ dsum) {
  __shared__ double sh[256];
  const int c = blockIdx.x;       // one block per channel-stat
  const int t = threadIdx.x;
  double s = 0.0;
  for (int i = t; i < nb; i += 256) s += (double)part[(size_t)i*stride + c];
  sh[t] = s;
  __syncthreads();
  for (int o = 128; o; o >>= 1) {
    if (t < o) sh[t] += sh[t + o];
    __syncthreads();
  }
  if (t == 0) dsum[c] = sh[0];
}

// ---------------- dsum -> BN affine (36 ch) ----------------
__global__ void k_bnaffine36(const double* __restrict__ dsum,
                             const float* __restrict__ g, const float* __restrict__ beta,
                             float* __restrict__ stats, int off) {
  int c = threadIdx.x;
  if (c >= 36) return;
  double m = dsum[c] / (double)SAMP;
  double v = dsum[36 + c] / (double)SAMP - m*m;
  float a = g[c] * rsqrtf((float)v + 1e-5f);
  stats[off + c] = a;
  stats[off + 36 + c] = beta[c] - (float)m * a;
}

// ---- tiled DLA recompute, channel-chunked (3 groups of 12).
// MODE 0: y2 stats -> part[blk][72].  MODE 1: z write (to zout) + z stats -> part[blk][24].
template<int MODE>
__global__ __launch_bounds__(256) void k_dla(const float* __restrict__ attn,
                                             const float* __restrict__ w_exp,
                                             const float* __restrict__ w_dw,
                                             const float* __restrict__ w_pro,
                                             const float* __restrict__ stats,
                                             float* __restrict__ zout,
                                             float* __restrict__ part) {
  __shared__ float a_s[12*256];
  __shared__ float y_s[12*256];
  __shared__ float wse[432];
  __shared__ float wdw[324];
  __shared__ float wpr[432];
  __shared__ float aff[144];
  __shared__ float red2[4*24];
  const int t = threadIdx.x;
  const int blk = blockIdx.x;
  const int b = blk / 196, tile = blk - b*196;
  const int tyq = tile / 14;
  const int ty0 = tyq * 14, tx0 = (tile - tyq*14) * 14;
  for (int i = t; i < 432; i += 256) wse[i] = w_exp[i];
  for (int i = t; i < 324; i += 256) wdw[i] = w_dw[i];
  if (MODE == 1) for (int i = t; i < 432; i += 256) wpr[i] = w_pro[i];
  if (t < 144) aff[t] = stats[t];
  // this thread's halo coordinate (pos = t in the 16x16 halo)
  const int hy = ty0 + (t >> 4) - 1, hx = tx0 + (t & 15) - 1;
  const bool inb = (hy >= 0) && (hy < 196) && (hx >= 0) && (hx < 196);
  // halo load: attn [12][16][16] (zero outside image)
#pragma unroll
  for (int ch = 0; ch < 12; ch++)
    a_s[ch*256 + t] = inb ? attn[((size_t)(b*12+ch))*NN2 + (size_t)hy*196 + hx] : 0.0f;

  const bool act = (t < 196);
  const int py = t / 14, px = t - py*14;
  const int base = (py+1)*16 + (px+1);
  const int w = t >> 6;
  float z[12] = {};

  for (int g = 0; g < 3; g++) {
    __syncthreads();   // a_s ready (g=0) / prev group's y_s & red2 reads done
    // y1c = clip(bn1(conv_exp)) for this group's 12 channels; 0 outside image
#pragma unroll
    for (int cl = 0; cl < 12; cl++) {
      const int c = g*12 + cl;
      float y = 0.0f;
#pragma unroll
      for (int h = 0; h < 12; h++) y = fmaf(wse[c*12+h], a_s[h*256+t], y);
      y = y*aff[c] + aff[36+c];
      y = fminf(fmaxf(y, 0.0f), 6.0f);
      y_s[cl*256 + t] = inb ? y : 0.0f;
    }
    __syncthreads();
    float s1g[12], s2g[12];
#pragma unroll
    for (int cl = 0; cl < 12; cl++) { s1g[cl] = 0.0f; s2g[cl] = 0.0f; }
    if (act) {
#pragma unroll
      for (int cl = 0; cl < 12; cl++) {
        const int c = g*12 + cl;
        const float* ys = &y_s[cl*256];
        const float* wd = &wdw[c*9];
        float y2 = 0.0f;
#pragma unroll
        for (int di = 0; di < 3; di++)
#pragma unroll
          for (int dj = 0; dj < 3; dj++)
            y2 = fmaf(wd[di*3+dj], ys[base + (di-1)*16 + (dj-1)], y2);
        if (MODE == 0) { s1g[cl] = y2; s2g[cl] = y2*y2; }
        else {
          float y2c = y2*aff[72+c] + aff[108+c];
          y2c = fminf(fmaxf(y2c, 0.0f), 6.0f);
#pragma unroll
          for (int cc = 0; cc < 12; cc++) z[cc] = fmaf(wpr[cc*36+c], y2c, z[cc]);
        }
      }
    }
    if (MODE == 0) {
#pragma unroll
      for (int cl = 0; cl < 12; cl++) {
#pragma unroll
        for (int off = 32; off; off >>= 1) {
          s1g[cl] += __shfl_xor(s1g[cl], off, 64);
          s2g[cl] += __shfl_xor(s2g[cl], off, 64);
        }
      }
      if ((t & 63) == 0) {
#pragma unroll
        for (int cl = 0; cl < 12; cl++) {
          red2[w*24 + cl] = s1g[cl];
          red2[w*24 + 12 + cl] = s2g[cl];
        }
      }
      __syncthreads();
      if (t < 24) {
        float v = red2[t] + red2[24+t] + red2[48+t] + red2[72+t];
        int cl = (t < 12) ? t : (t - 12);
        int off36 = (t < 12) ? 0 : 36;
        part[(size_t)blk*72 + off36 + g*12 + cl] = v;
      }
    }
  }

  if (MODE == 1) {
    float s1g[12], s2g[12];
    if (act) {
      const int oy = ty0 + py, ox = tx0 + px;
#pragma unroll
      for (int cc = 0; cc < 12; cc++) {
        zout[((size_t)(b*12+cc))*NN2 + (size_t)oy*196 + ox] = z[cc];
        s1g[cc] = z[cc]; s2g[cc] = z[cc]*z[cc];
      }
    } else {
#pragma unroll
      for (int cc = 0; cc < 12; cc++) { s1g[cc] = 0.0f; s2g[cc] = 0.0f; }
    }
#pragma unroll
    for (int cc = 0; cc < 12; cc++) {
#pragma unroll
      for (int off = 32; off; off >>= 1) {
        s1g[cc] += __shfl_xor(s1g[cc], off, 64);
        s2g[cc] += __shfl_xor(s2g[cc], off, 64);
      }
    }
    __syncthreads();   // y_s/red2 free
    if ((t & 63) == 0) {
#pragma unroll
      for (int cc = 0; cc < 12; cc++) {
        red2[w*24 + cc] = s1g[cc];
        red2[w*24 + 12 + cc] = s2g[cc];
      }
    }
    __syncthreads();
    if (t < 24)
      part[(size_t)blk*24 + t] = red2[t] + red2[24+t] + red2[48+t] + red2[72+t];
  }
}

// ---------------- combined bn3 + adapt_bn affine (from dsum[24]) ----------------
__global__ void k_bnfinal(const double* __restrict__ dsum,
                          const float* __restrict__ g3, const float* __restrict__ b3,
                          const float* __restrict__ ag, const float* __restrict__ ab,
                          float* __restrict__ stats) {
  int c = threadIdx.x;
  if (c >= 12) return;
  (void)b3; // bn3 beta cancels exactly in the composed affine
  double m = dsum[c] / (double)SAMP;
  double v = dsum[12 + c] / (double)SAMP - m*m;
  float r1 = rsqrtf((float)v + 1e-5f);
  float vt = g3[c]*g3[c]*(float)v*r1*r1;
  float r2 = rsqrtf(vt + 1e-5f);
  float A = g3[c]*ag[c]*r1*r2;
  stats[144 + c] = A;
  stats[156 + c] = ab[c] - (float)m*A;
}

// ---------------- in-place final affine on z -> attn_r ----------------
__global__ __launch_bounds__(256) void k_zaffine(float* __restrict__ z,
                                                 const float* __restrict__ stats) {
  const unsigned j = blockIdx.x*256 + threadIdx.x;   // float4 index, ATT/4 total
  const unsigned i = j*4;                             // element index
  const int ch = (int)((i / (unsigned)NN2) % 12u);
  const float A = stats[144 + ch], Bc = stats[156 + ch];
  float4 v = ((float4*)z)[j];
  v.x = fmaf(v.x, A, Bc); v.y = fmaf(v.y, A, Bc);
  v.z = fmaf(v.z, A, Bc); v.w = fmaf(v.w, A, Bc);
  ((float4*)z)[j] = v;
}

// ---------------- PV: O = attn_r @ V -> out_pre bf16 [B,N,C] ----------------
__global__ __launch_bounds__(256) void k_pv(const float* __restrict__ attn_r,
                                            const float* __restrict__ vbuf,
                                            ushort* __restrict__ out_pre) {
  __shared__ float Vs[196*65];
  __shared__ float ar_s[16*200];
  const int t = threadIdx.x;
  const int bh = blockIdx.x;
  const int b = bh / 12, h = bh - b*12;
  const float* vp = vbuf + (size_t)bh * Nn * Dd;
#pragma unroll
  for (int i = 0; i < 49; i++) {
    int idx = t + i*256;
    Vs[(idx >> 6)*65 + (idx & 63)] = vp[idx];
  }
  const float* arp = attn_r + (size_t)bh * NN2;
  const int dd = t & 63, wy = t >> 6;
  for (int ch = 0; ch < 13; ch++) {
    const int r0 = ch*16;
    const int nrows = (r0 + 16 <= 196) ? 16 : (196 - r0);
    __syncthreads();
    for (int idx = t; idx < nrows*196; idx += 256) {
      int rr = idx / 196, m = idx - rr*196;
      ar_s[rr*200 + m] = arp[(size_t)(r0+rr)*196 + m];
    }
    __syncthreads();
    float acc[4] = {0,0,0,0};
#pragma unroll 2
    for (int m = 0; m < 196; m++) {
      float vv = Vs[m*65 + dd];
#pragma unroll
      for (int r = 0; r < 4; r++) acc[r] = fmaf(ar_s[(wy*4+r)*200 + m], vv, acc[r]);
    }
#pragma unroll
    for (int r = 0; r < 4; r++) {
      int rr = wy*4 + r;
      if (rr < nrows)
        out_pre[((size_t)(b*196 + r0 + rr))*Cc + h*64 + dd] = f2b(acc[r]);
    }
  }
}

// ---------------- launch ----------------
extern "C" void kernel_launch(void* const* d_in, const int* in_sizes, int n_in,
                              void* d_out, int out_size, void* d_ws, size_t ws_size,
                              hipStream_t stream) {
  (void)in_sizes; (void)n_in; (void)out_size; (void)ws_size;
  const float* x      = (const float*)d_in[0];
  const float* w_qkv  = (const float*)d_in[1];
  const float* w_exp  = (const float*)d_in[2];
  const float* bn1_g  = (const float*)d_in[3];
  const float* bn1_b  = (const float*)d_in[4];
  const float* w_dw   = (const float*)d_in[5];
  const float* bn2_g  = (const float*)d_in[6];
  const float* bn2_b  = (const float*)d_in[7];
  const float* w_pro  = (const float*)d_in[8];
  const float* bn3_g  = (const float*)d_in[9];
  const float* bn3_b  = (const float*)d_in[10];
  const float* abn_g  = (const float*)d_in[11];
  const float* abn_b  = (const float*)d_in[12];
  const float* w_proj = (const float*)d_in[13];
  const float* b_proj = (const float*)d_in[14];

  float* out      = (float*)d_out;
  float* attn_out = out + (size_t)QSZ;     // d_out's attn_r region (S scratch -> z -> attn_r)
  float* ws    = (float*)d_ws;
  float* vbuf  = ws;                        // [QSZ]
  float* big   = ws + (size_t)QSZ;          // [ATT]: q,k -> attn -> out_pre(bf16)
  float* qbuf  = big;
  float* kbuf  = big + (size_t)QSZ;
  float* stats = ws + (size_t)QSZ + ATT;    // [256]
  float* part  = stats + 256;               // [6272*72]
  double* dsum = (double*)(part + (size_t)6272*72); // [96] doubles (8B-aligned)

  // bf16 staging buffers in dead regions:
  ushort* xb   = (ushort*)out;              // [QSZ] bf16 — out[0..QSZ) untouched until proj
  ushort* wqb  = xb + (size_t)QSZ;          // [2304*768] bf16
  ushort* opb  = (ushort*)big;              // out_pre bf16 (attn in big dead by then)
  ushort* wpb  = (ushort*)part;             // w_proj bf16 (part dead after last reduce)

  k_cast <<<QSZ/2048, 256, 0, stream>>>(x, xb);
  k_cast <<<(2304*768)/2048, 256, 0, stream>>>(w_qkv, wqb);
  k_mfma_gemm<0><<<dim3(18, 49), 256, 0, stream>>>(xb, wqb, nullptr, qbuf, kbuf, vbuf);
  k_qk       <<<dim3(384, 7, 7), 256, 0, stream>>>(qbuf, kbuf, attn_out);   // S -> d_out scratch
  k_softmax  <<<18816, 256, 0, stream>>>(attn_out, big);                    // attn -> ws (q,k dead)
  k_y1stats  <<<1024, 256, 0, stream>>>(big, w_exp, part);
  k_reduce   <<<72, 256, 0, stream>>>(part, 1024, 72, dsum);
  k_bnaffine36<<<1, 64, 0, stream>>>(dsum, bn1_g, bn1_b, stats, 0);
  k_dla<0>   <<<6272, 256, 0, stream>>>(big, w_exp, w_dw, nullptr, stats, nullptr, part);
  k_reduce   <<<72, 256, 0, stream>>>(part, 6272, 72, dsum);
  k_bnaffine36<<<1, 64, 0, stream>>>(dsum, bn2_g, bn2_b, stats, 72);
  k_dla<1>   <<<6272, 256, 0, stream>>>(big, w_exp, w_dw, w_pro, stats, attn_out, part);
  k_reduce   <<<24, 256, 0, stream>>>(part, 6272, 24, dsum);
  k_bnfinal  <<<1, 64, 0, stream>>>(dsum, bn3_g, bn3_b, abn_g, abn_b, stats);
  k_cast     <<<(768*768)/2048, 256, 0, stream>>>(w_proj, wpb);             // part now dead
  k_zaffine  <<<ATT/1024, 256, 0, stream>>>(attn_out, stats);               // z -> attn_r in place
  k_pv       <<<384, 256, 0, stream>>>(attn_out, vbuf, opb);                // out_pre(bf16) -> big
  k_mfma_gemm<1><<<dim3(6, 49), 256, 0, stream>>>(opb, wpb, b_proj, out, nullptr, nullptr);
}

// Round 6
// 933.363 us; speedup vs baseline: 4.0240x; 1.0580x over previous
//
#include <hip/hip_runtime.h>
#include <hip/hip_bf16.h>
#include <math.h>

// ---------------- problem constants ----------------
constexpr int Bz  = 32;
constexpr int Nn  = 196;
constexpr int Cc  = 768;
constexpr int Hh  = 12;
constexpr int Dd  = 64;
constexpr int HID = 36;           // Hh * 3
constexpr int NN2 = Nn * Nn;      // 38416
constexpr int QSZ = Bz * Nn * Cc;          // 4,816,896
constexpr int ATT = Bz * Hh * NN2;         // 14,751,744
constexpr int SAMP = Bz * NN2;    // 1,229,312 samples per BN channel
constexpr float RS = 0.35355339059327373f; // 64^-0.25

typedef short bf16x8 __attribute__((ext_vector_type(8)));
typedef float f32x4  __attribute__((ext_vector_type(4)));

__device__ inline ushort f2b(float f) {
  __hip_bfloat16 h = __float2bfloat16(f);
  return *reinterpret_cast<ushort*>(&h);
}

// ---------------- f32 -> bf16 cast (8 elems/thread) ----------------
__global__ __launch_bounds__(256) void k_cast(const float* __restrict__ in,
                                              ushort* __restrict__ outp) {
  const int j = blockIdx.x*256 + threadIdx.x;       // 8-elem group
  float4 a = ((const float4*)in)[2*j];
  float4 b = ((const float4*)in)[2*j+1];
  ushort o[8] = { f2b(a.x), f2b(a.y), f2b(a.z), f2b(a.w),
                  f2b(b.x), f2b(b.y), f2b(b.z), f2b(b.w) };
  ((uint4*)outp)[j] = *(const uint4*)o;
}

// ---------------- bf16 MFMA GEMM: C = A[M,768] x B[N,768]^T ----------------
// EPI 0: qkv epilogue (RS scale on q,k; scatter to [B,H,N,D]); EPI 1: +bias, row-major out
template<int EPI>
__global__ __launch_bounds__(256) void k_mfma_gemm(const ushort* __restrict__ A,
                                                   const ushort* __restrict__ B,
                                                   const float* __restrict__ bias,
                                                   float* __restrict__ p0,
                                                   float* __restrict__ p1,
                                                   float* __restrict__ p2) {
  __shared__ ushort As[128*72];   // 128 rows x 64 k, stride 72 (pad kills bank conflicts)
  __shared__ ushort Bs[128*72];
  const int t = threadIdx.x;
  const int m0 = blockIdx.y*128, n0 = blockIdx.x*128;
  const int w = t>>6, lane = t&63;
  const int wr = w>>1, wc = w&1;         // wave -> 64x64 quadrant
  const int lrow = lane&15, lkb = lane>>4;
  f32x4 acc[4][4] = {};
  const int srow = t>>1, skoff = (t&1)*32;
  const ushort* aP = A + (size_t)(m0+srow)*768 + skoff;
  const ushort* bP = B + (size_t)(n0+srow)*768 + skoff;
  ushort* aw = &As[srow*72 + skoff];
  ushort* bw = &Bs[srow*72 + skoff];
  for (int k0 = 0; k0 < 768; k0 += 64) {
    uint4 a0 = *(const uint4*)(aP+k0),    a1 = *(const uint4*)(aP+k0+8);
    uint4 a2 = *(const uint4*)(aP+k0+16), a3 = *(const uint4*)(aP+k0+24);
    uint4 b0 = *(const uint4*)(bP+k0),    b1 = *(const uint4*)(bP+k0+8);
    uint4 b2 = *(const uint4*)(bP+k0+16), b3 = *(const uint4*)(bP+k0+24);
    __syncthreads();
    *(uint4*)(aw)    = a0; *(uint4*)(aw+8)  = a1;
    *(uint4*)(aw+16) = a2; *(uint4*)(aw+24) = a3;
    *(uint4*)(bw)    = b0; *(uint4*)(bw+8)  = b1;
    *(uint4*)(bw+16) = b2; *(uint4*)(bw+24) = b3;
    __syncthreads();
#pragma unroll
    for (int kk = 0; kk < 2; kk++) {
      bf16x8 af[4], bfr[4];
#pragma unroll
      for (int m = 0; m < 4; m++)
        af[m] = *(const bf16x8*)&As[(wr*64+m*16+lrow)*72 + kk*32 + lkb*8];
#pragma unroll
      for (int n = 0; n < 4; n++)
        bfr[n] = *(const bf16x8*)&Bs[(wc*64+n*16+lrow)*72 + kk*32 + lkb*8];
#pragma unroll
      for (int m = 0; m < 4; m++)
#pragma unroll
        for (int n = 0; n < 4; n++)
          acc[m][n] = __builtin_amdgcn_mfma_f32_16x16x32_bf16(af[m], bfr[n], acc[m][n], 0, 0, 0);
    }
  }
  const int r4 = lane>>4;
#pragma unroll
  for (int m = 0; m < 4; m++) {
#pragma unroll
    for (int r = 0; r < 4; r++) {
      const int grow = m0 + wr*64 + m*16 + r4*4 + r;
      if (EPI == 0) {
        const int b = grow/196, nn = grow - b*196;
#pragma unroll
        for (int n = 0; n < 4; n++) {
          const int gcol = n0 + wc*64 + n*16 + lrow;
          const int three = gcol/768, rem = gcol - three*768;
          const int h = rem>>6, dd = rem&63;
          float v = acc[m][n][r] * (three < 2 ? RS : 1.0f);
          float* base = (three == 0) ? p0 : (three == 1) ? p1 : p2;
          base[((size_t)(b*12+h)*196 + nn)*64 + dd] = v;
        }
      } else {
#pragma unroll
        for (int n = 0; n < 4; n++) {
          const int gcol = n0 + wc*64 + n*16 + lrow;
          p0[(size_t)grow*768 + gcol] = acc[m][n][r] + bias[gcol];
        }
      }
    }
  }
}

// ---------------- K2a: S = Q K^T (batched, 32x32 tiles) ----------------
__global__ __launch_bounds__(256) void k_qk(const float* __restrict__ qbuf,
                                            const float* __restrict__ kbuf,
                                            float* __restrict__ S) {
  __shared__ float Qs[32][68];
  __shared__ float Ks[32][68];
  const int t = threadIdx.x;
  const int bh = blockIdx.x;
  const int r0 = blockIdx.y * 32, c0 = blockIdx.z * 32;
  const float* qp = qbuf + (size_t)bh * Nn * Dd;
  const float* kp = kbuf + (size_t)bh * Nn * Dd;
#pragma unroll
  for (int i = 0; i < 2; i++) {
    int idx = t + i*256;            // float4 index
    int row = idx >> 4, kv = idx & 15;
    float4 qv = make_float4(0,0,0,0), kk4 = make_float4(0,0,0,0);
    int gr = r0 + row;
    if (gr < Nn) qv = *(const float4*)(qp + (size_t)gr*Dd + kv*4);
    int gc = c0 + row;
    if (gc < Nn) kk4 = *(const float4*)(kp + (size_t)gc*Dd + kv*4);
    *(float4*)&Qs[row][kv*4] = qv;
    *(float4*)&Ks[row][kv*4] = kk4;
  }
  __syncthreads();
  const int tx = t & 15, ty = t >> 4;
  float acc[2][2] = {};
#pragma unroll
  for (int kk = 0; kk < 64; kk++) {
    float a0 = Qs[ty*2+0][kk], a1 = Qs[ty*2+1][kk];
    float b0 = Ks[tx*2+0][kk], b1 = Ks[tx*2+1][kk];
    acc[0][0] = fmaf(a0,b0,acc[0][0]); acc[0][1] = fmaf(a0,b1,acc[0][1]);
    acc[1][0] = fmaf(a1,b0,acc[1][0]); acc[1][1] = fmaf(a1,b1,acc[1][1]);
  }
#pragma unroll
  for (int i = 0; i < 2; i++) {
    int rr = r0 + ty*2 + i;
    if (rr >= Nn) continue;
#pragma unroll
    for (int j = 0; j < 2; j++) {
      int cc2 = c0 + tx*2 + j;
      if (cc2 < Nn) S[((size_t)bh*Nn + rr)*Nn + cc2] = acc[i][j];
    }
  }
}

// ---------------- K2b: row softmax, src -> dst ----------------
__global__ __launch_bounds__(256) void k_softmax(const float* __restrict__ src,
                                                 float* __restrict__ dst) {
  const int row = blockIdx.x*4 + (threadIdx.x >> 6);
  const int lane = threadIdx.x & 63;
  const float* p = src + (size_t)row * Nn;
  float* o = dst + (size_t)row * Nn;
  float v[4];
  float mx = -1e30f;
#pragma unroll
  for (int i = 0; i < 4; i++) {
    int m = lane + i*64;
    v[i] = (m < Nn) ? p[m] : -1e30f;
    mx = fmaxf(mx, v[i]);
  }
#pragma unroll
  for (int off = 32; off; off >>= 1) mx = fmaxf(mx, __shfl_xor(mx, off, 64));
  float sum = 0.0f;
#pragma unroll
  for (int i = 0; i < 4; i++) {
    int m = lane + i*64;
    v[i] = (m < Nn) ? __expf(v[i]-mx) : 0.0f;
    sum += v[i];
  }
#pragma unroll
  for (int off = 32; off; off >>= 1) sum += __shfl_xor(sum, off, 64);
  float inv = 1.0f / sum;
#pragma unroll
  for (int i = 0; i < 4; i++) {
    int m = lane + i*64;
    if (m < Nn) o[m] = v[i]*inv;
  }
}

// ---------------- K3: y1 = conv_exp(attn) stats (recompute, no store) ----------------
__global__ __launch_bounds__(256) void k_y1stats(const float* __restrict__ attn,
                                                 const float* __restrict__ w_exp,
                                                 float* __restrict__ part) {
  __shared__ float wse[HID*Hh];
  __shared__ float red2[4*72];
  const int t = threadIdx.x;
  for (int i = t; i < HID*Hh; i += 256) wse[i] = w_exp[i];
  __syncthreads();
  float s1[36] = {}, s2[36] = {};
  const int stride = gridDim.x * 256;
  for (int s = blockIdx.x*256 + t; s < SAMP; s += stride) {
    int b = s / NN2, p = s - b*NN2;
    float a[12];
#pragma unroll
    for (int h = 0; h < 12; h++) a[h] = attn[((size_t)(b*12+h))*NN2 + p];
#pragma unroll
    for (int c = 0; c < 36; c++) {
      float y = 0.0f;
#pragma unroll
      for (int h = 0; h < 12; h++) y = fmaf(wse[c*12+h], a[h], y);
      s1[c] += y; s2[c] += y*y;
    }
  }
#pragma unroll
  for (int c = 0; c < 36; c++) {
#pragma unroll
    for (int off = 32; off; off >>= 1) {
      s1[c] += __shfl_xor(s1[c], off, 64);
      s2[c] += __shfl_xor(s2[c], off, 64);
    }
  }
  const int w = t >> 6;
  if ((t & 63) == 0) {
#pragma unroll
    for (int c = 0; c < 36; c++) { red2[w*72 + c] = s1[c]; red2[w*72 + 36 + c] = s2[c]; }
  }
  __syncthreads();
  if (t < 72)
    part[(size_t)blockIdx.x*72 + t] = red2[t] + red2[72+t] + red2[144+t] + red2[216+t];
}

// ---------------- hierarchical deterministic reduce: part[nb][stride] -> dsum[stride] ----------------
__global__ __launch_bounds__(256) void k_reduce(const float* __restrict__ part, int nb,
                                               int stride, double* __restrict__ dsum) {
  __shared__ double sh[256];
  const int c = blockIdx.x;       // one block per channel-stat
  const int t = threadIdx.x;
  double s = 0.0;
  for (int i = t; i < nb; i += 256) s += (double)part[(size_t)i*stride + c];
  sh[t] = s;
  __syncthreads();
  for (int o = 128; o; o >>= 1) {
    if (t < o) sh[t] += sh[t + o];
    __syncthreads();
  }
  if (t == 0) dsum[c] = sh[0];
}

// ---------------- dsum -> BN affine (36 ch) ----------------
__global__ void k_bnaffine36(const double* __restrict__ dsum,
                             const float* __restrict__ g, const float* __restrict__ beta,
                             float* __restrict__ stats, int off) {
  int c = threadIdx.x;
  if (c >= 36) return;
  double m = dsum[c] / (double)SAMP;
  double v = dsum[36 + c] / (double)SAMP - m*m;
  float a = g[c] * rsqrtf((float)v + 1e-5f);
  stats[off + c] = a;
  stats[off + 36 + c] = beta[c] - (float)m * a;
}

// ---- tiled DLA recompute, channel-chunked (3 groups of 12), attn in REGISTERS.
// MODE 0: y2 stats -> part[blk][72].  MODE 1: z write (to zout) + z stats -> part[blk][24].
template<int MODE>
__global__ __launch_bounds__(256) void k_dla(const float* __restrict__ attn,
                                             const float* __restrict__ w_exp,
                                             const float* __restrict__ w_dw,
                                             const float* __restrict__ w_pro,
                                             const float* __restrict__ stats,
                                             float* __restrict__ zout,
                                             float* __restrict__ part) {
  __shared__ float y_s[12*256];
  __shared__ float wse[432];
  __shared__ float wdw[324];
  __shared__ float wpr[432];
  __shared__ float aff[144];
  __shared__ float red2[4*24];
  const int t = threadIdx.x;
  const int blk = blockIdx.x;
  const int b = blk / 196, tile = blk - b*196;
  const int tyq = tile / 14;
  const int ty0 = tyq * 14, tx0 = (tile - tyq*14) * 14;
  for (int i = t; i < 432; i += 256) wse[i] = w_exp[i];
  for (int i = t; i < 324; i += 256) wdw[i] = w_dw[i];
  if (MODE == 1) for (int i = t; i < 432; i += 256) wpr[i] = w_pro[i];
  if (t < 144) aff[t] = stats[t];
  // this thread's halo coordinate (pos = t in the 16x16 halo)
  const int hy = ty0 + (t >> 4) - 1, hx = tx0 + (t & 15) - 1;
  const bool inb = (hy >= 0) && (hy < 196) && (hx >= 0) && (hx < 196);
  // halo attn values -> REGISTERS (each thread only ever uses its own position)
  float a[12];
#pragma unroll
  for (int ch = 0; ch < 12; ch++)
    a[ch] = inb ? attn[((size_t)(b*12+ch))*NN2 + (size_t)hy*196 + hx] : 0.0f;

  const bool act = (t < 196);
  const int py = t / 14, px = t - py*14;
  const int base = (py+1)*16 + (px+1);
  const int w = t >> 6;
  float z[12] = {};

  for (int g = 0; g < 3; g++) {
    __syncthreads();   // g=0: weights/aff staged; g>0: prev group's y_s/red2 reads done
    // y1c = clip(bn1(conv_exp)) for this group's 12 channels; 0 outside image
#pragma unroll
    for (int cl = 0; cl < 12; cl++) {
      const int c = g*12 + cl;
      float y = 0.0f;
#pragma unroll
      for (int h = 0; h < 12; h++) y = fmaf(wse[c*12+h], a[h], y);
      y = y*aff[c] + aff[36+c];
      y = fminf(fmaxf(y, 0.0f), 6.0f);
      y_s[cl*256 + t] = inb ? y : 0.0f;
    }
    __syncthreads();
    float s1g[12], s2g[12];
#pragma unroll
    for (int cl = 0; cl < 12; cl++) { s1g[cl] = 0.0f; s2g[cl] = 0.0f; }
    if (act) {
#pragma unroll
      for (int cl = 0; cl < 12; cl++) {
        const int c = g*12 + cl;
        const float* ys = &y_s[cl*256];
        const float* wd = &wdw[c*9];
        float y2 = 0.0f;
#pragma unroll
        for (int di = 0; di < 3; di++)
#pragma unroll
          for (int dj = 0; dj < 3; dj++)
            y2 = fmaf(wd[di*3+dj], ys[base + (di-1)*16 + (dj-1)], y2);
        if (MODE == 0) { s1g[cl] = y2; s2g[cl] = y2*y2; }
        else {
          float y2c = y2*aff[72+c] + aff[108+c];
          y2c = fminf(fmaxf(y2c, 0.0f), 6.0f);
#pragma unroll
          for (int cc = 0; cc < 12; cc++) z[cc] = fmaf(wpr[cc*36+c], y2c, z[cc]);
        }
      }
    }
    if (MODE == 0) {
#pragma unroll
      for (int cl = 0; cl < 12; cl++) {
#pragma unroll
        for (int off = 32; off; off >>= 1) {
          s1g[cl] += __shfl_xor(s1g[cl], off, 64);
          s2g[cl] += __shfl_xor(s2g[cl], off, 64);
        }
      }
      if ((t & 63) == 0) {
#pragma unroll
        for (int cl = 0; cl < 12; cl++) {
          red2[w*24 + cl] = s1g[cl];
          red2[w*24 + 12 + cl] = s2g[cl];
        }
      }
      __syncthreads();
      if (t < 24) {
        float v = red2[t] + red2[24+t] + red2[48+t] + red2[72+t];
        int cl = (t < 12) ? t : (t - 12);
        int off36 = (t < 12) ? 0 : 36;
        part[(size_t)blk*72 + off36 + g*12 + cl] = v;
      }
    }
  }

  if (MODE == 1) {
    float s1g[12], s2g[12];
    if (act) {
      const int oy = ty0 + py, ox = tx0 + px;
#pragma unroll
      for (int cc = 0; cc < 12; cc++) {
        zout[((size_t)(b*12+cc))*NN2 + (size_t)oy*196 + ox] = z[cc];
        s1g[cc] = z[cc]; s2g[cc] = z[cc]*z[cc];
      }
    } else {
#pragma unroll
      for (int cc = 0; cc < 12; cc++) { s1g[cc] = 0.0f; s2g[cc] = 0.0f; }
    }
#pragma unroll
    for (int cc = 0; cc < 12; cc++) {
#pragma unroll
      for (int off = 32; off; off >>= 1) {
        s1g[cc] += __shfl_xor(s1g[cc], off, 64);
        s2g[cc] += __shfl_xor(s2g[cc], off, 64);
      }
    }
    __syncthreads();   // y_s/red2 free
    if ((t & 63) == 0) {
#pragma unroll
      for (int cc = 0; cc < 12; cc++) {
        red2[w*24 + cc] = s1g[cc];
        red2[w*24 + 12 + cc] = s2g[cc];
      }
    }
    __syncthreads();
    if (t < 24)
      part[(size_t)blk*24 + t] = red2[t] + red2[24+t] + red2[48+t] + red2[72+t];
  }
}

// ---------------- combined bn3 + adapt_bn affine (from dsum[24]) ----------------
__global__ void k_bnfinal(const double* __restrict__ dsum,
                          const float* __restrict__ g3, const float* __restrict__ b3,
                          const float* __restrict__ ag, const float* __restrict__ ab,
                          float* __restrict__ stats) {
  int c = threadIdx.x;
  if (c >= 12) return;
  (void)b3; // bn3 beta cancels exactly in the composed affine
  double m = dsum[c] / (double)SAMP;
  double v = dsum[12 + c] / (double)SAMP - m*m;
  float r1 = rsqrtf((float)v + 1e-5f);
  float vt = g3[c]*g3[c]*(float)v*r1*r1;
  float r2 = rsqrtf(vt + 1e-5f);
  float A = g3[c]*ag[c]*r1*r2;
  stats[144 + c] = A;
  stats[156 + c] = ab[c] - (float)m*A;
}

// ---------------- PV: attn_r = z*Af+Bf (in-place write), O = attn_r @ V -> out_pre bf16 ----------------
__global__ __launch_bounds__(256) void k_pv(float* __restrict__ attn_r,
                                            const float* __restrict__ vbuf,
                                            const float* __restrict__ stats,
                                            ushort* __restrict__ out_pre) {
  __shared__ float Vs[196*65];
  __shared__ float ar_s[16*200];
  const int t = threadIdx.x;
  const int bh = blockIdx.x;
  const int b = bh / 12, h = bh - b*12;
  const float Af = stats[144 + h], Bf = stats[156 + h];
  const float* vp = vbuf + (size_t)bh * Nn * Dd;
#pragma unroll
  for (int i = 0; i < 49; i++) {
    int idx = t + i*256;
    Vs[(idx >> 6)*65 + (idx & 63)] = vp[idx];
  }
  float* arp = attn_r + (size_t)bh * NN2;
  const int dd = t & 63, wy = t >> 6;
  for (int ch = 0; ch < 13; ch++) {
    const int r0 = ch*16;
    const int nrows = (r0 + 16 <= 196) ? 16 : (196 - r0);
    __syncthreads();
    for (int idx = t; idx < nrows*196; idx += 256) {
      int rr = idx / 196, m = idx - rr*196;
      float val = fmaf(arp[(size_t)(r0+rr)*196 + m], Af, Bf);
      arp[(size_t)(r0+rr)*196 + m] = val;     // z -> attn_r in place
      ar_s[rr*200 + m] = val;
    }
    __syncthreads();
    float acc[4] = {0,0,0,0};
#pragma unroll 2
    for (int m = 0; m < 196; m++) {
      float vv = Vs[m*65 + dd];
#pragma unroll
      for (int r = 0; r < 4; r++) acc[r] = fmaf(ar_s[(wy*4+r)*200 + m], vv, acc[r]);
    }
#pragma unroll
    for (int r = 0; r < 4; r++) {
      int rr = wy*4 + r;
      if (rr < nrows)
        out_pre[((size_t)(b*196 + r0 + rr))*Cc + h*64 + dd] = f2b(acc[r]);
    }
  }
}

// ---------------- launch ----------------
extern "C" void kernel_launch(void* const* d_in, const int* in_sizes, int n_in,
                              void* d_out, int out_size, void* d_ws, size_t ws_size,
                              hipStream_t stream) {
  (void)in_sizes; (void)n_in; (void)out_size; (void)ws_size;
  const float* x      = (const float*)d_in[0];
  const float* w_qkv  = (const float*)d_in[1];
  const float* w_exp  = (const float*)d_in[2];
  const float* bn1_g  = (const float*)d_in[3];
  const float* bn1_b  = (const float*)d_in[4];
  const float* w_dw   = (const float*)d_in[5];
  const float* bn2_g  = (const float*)d_in[6];
  const float* bn2_b  = (const float*)d_in[7];
  const float* w_pro  = (const float*)d_in[8];
  const float* bn3_g  = (const float*)d_in[9];
  const float* bn3_b  = (const float*)d_in[10];
  const float* abn_g  = (const float*)d_in[11];
  const float* abn_b  = (const float*)d_in[12];
  const float* w_proj = (const float*)d_in[13];
  const float* b_proj = (const float*)d_in[14];

  float* out      = (float*)d_out;
  float* attn_out = out + (size_t)QSZ;     // d_out's attn_r region (S scratch -> z -> attn_r)
  float* ws    = (float*)d_ws;
  float* vbuf  = ws;                        // [QSZ]
  float* big   = ws + (size_t)QSZ;          // [ATT]: q,k -> attn -> out_pre(bf16)
  float* qbuf  = big;
  float* kbuf  = big + (size_t)QSZ;
  float* stats = ws + (size_t)QSZ + ATT;    // [256]
  float* part  = stats + 256;               // [6272*72]
  double* dsum = (double*)(part + (size_t)6272*72); // [96] doubles (8B-aligned)

  // bf16 staging buffers in dead regions:
  ushort* xb   = (ushort*)out;              // [QSZ] bf16 — out[0..QSZ) untouched until proj
  ushort* wqb  = xb + (size_t)QSZ;          // [2304*768] bf16
  ushort* opb  = (ushort*)big;              // out_pre bf16 (attn in big dead by then)
  ushort* wpb  = (ushort*)part;             // w_proj bf16 (part dead after last reduce)

  k_cast <<<QSZ/2048, 256, 0, stream>>>(x, xb);
  k_cast <<<(2304*768)/2048, 256, 0, stream>>>(w_qkv, wqb);
  k_mfma_gemm<0><<<dim3(18, 49), 256, 0, stream>>>(xb, wqb, nullptr, qbuf, kbuf, vbuf);
  k_qk       <<<dim3(384, 7, 7), 256, 0, stream>>>(qbuf, kbuf, attn_out);   // S -> d_out scratch
  k_softmax  <<<18816, 256, 0, stream>>>(attn_out, big);                    // attn -> ws (q,k dead)
  k_y1stats  <<<1024, 256, 0, stream>>>(big, w_exp, part);
  k_reduce   <<<72, 256, 0, stream>>>(part, 1024, 72, dsum);
  k_bnaffine36<<<1, 64, 0, stream>>>(dsum, bn1_g, bn1_b, stats, 0);
  k_dla<0>   <<<6272, 256, 0, stream>>>(big, w_exp, w_dw, nullptr, stats, nullptr, part);
  k_reduce   <<<72, 256, 0, stream>>>(part, 6272, 72, dsum);
  k_bnaffine36<<<1, 64, 0, stream>>>(dsum, bn2_g, bn2_b, stats, 72);
  k_dla<1>   <<<6272, 256, 0, stream>>>(big, w_exp, w_dw, w_pro, stats, attn_out, part);
  k_reduce   <<<24, 256, 0, stream>>>(part, 6272, 24, dsum);
  k_bnfinal  <<<1, 64, 0, stream>>>(dsum, bn3_g, bn3_b, abn_g, abn_b, stats);
  k_cast     <<<(768*768)/2048, 256, 0, stream>>>(w_proj, wpb);             // part now dead
  k_pv       <<<384, 256, 0, stream>>>(attn_out, vbuf, stats, opb);         // affine+PV fused
  k_mfma_gemm<1><<<dim3(6, 49), 256, 0, stream>>>(opb, wpb, b_proj, out, nullptr, nullptr);
}

// Round 7
// 724.545 us; speedup vs baseline: 5.1837x; 1.2882x over previous
//
#include <hip/hip_runtime.h>
#include <hip/hip_bf16.h>
#include <math.h>

// ---------------- problem constants ----------------
constexpr int Bz  = 32;
constexpr int Nn  = 196;
constexpr int Cc  = 768;
constexpr int Hh  = 12;
constexpr int Dd  = 64;
constexpr int HID = 36;           // Hh * 3
constexpr int NN2 = Nn * Nn;      // 38416
constexpr int QSZ = Bz * Nn * Cc;          // 4,816,896
constexpr int ATT = Bz * Hh * NN2;         // 14,751,744
constexpr int SAMP = Bz * NN2;    // 1,229,312 samples per BN channel
constexpr float RS = 0.35355339059327373f; // 64^-0.25

typedef short bf16x8 __attribute__((ext_vector_type(8)));
typedef float f32x4  __attribute__((ext_vector_type(4)));

__device__ inline ushort f2b(float f) {
  __hip_bfloat16 h = __float2bfloat16(f);
  return *reinterpret_cast<ushort*>(&h);
}

// ---------------- f32 -> bf16 cast (8 elems/thread) ----------------
__global__ __launch_bounds__(256) void k_cast(const float* __restrict__ in,
                                              ushort* __restrict__ outp) {
  const int j = blockIdx.x*256 + threadIdx.x;       // 8-elem group
  float4 a = ((const float4*)in)[2*j];
  float4 b = ((const float4*)in)[2*j+1];
  ushort o[8] = { f2b(a.x), f2b(a.y), f2b(a.z), f2b(a.w),
                  f2b(b.x), f2b(b.y), f2b(b.z), f2b(b.w) };
  ((uint4*)outp)[j] = *(const uint4*)o;
}

// ---------------- bf16 MFMA GEMM: C = A[M,768] x B[N,768]^T ----------------
// EPI 0: qkv epilogue (RS scale on q,k; scatter to [B,H,N,D]); EPI 1: +bias, row-major out
template<int EPI>
__global__ __launch_bounds__(256) void k_mfma_gemm(const ushort* __restrict__ A,
                                                   const ushort* __restrict__ B,
                                                   const float* __restrict__ bias,
                                                   float* __restrict__ p0,
                                                   float* __restrict__ p1,
                                                   float* __restrict__ p2) {
  __shared__ ushort As[128*72];   // 128 rows x 64 k, stride 72 (pad kills bank conflicts)
  __shared__ ushort Bs[128*72];
  const int t = threadIdx.x;
  const int m0 = blockIdx.y*128, n0 = blockIdx.x*128;
  const int w = t>>6, lane = t&63;
  const int wr = w>>1, wc = w&1;         // wave -> 64x64 quadrant
  const int lrow = lane&15, lkb = lane>>4;
  f32x4 acc[4][4] = {};
  const int srow = t>>1, skoff = (t&1)*32;
  const ushort* aP = A + (size_t)(m0+srow)*768 + skoff;
  const ushort* bP = B + (size_t)(n0+srow)*768 + skoff;
  ushort* aw = &As[srow*72 + skoff];
  ushort* bw = &Bs[srow*72 + skoff];
  for (int k0 = 0; k0 < 768; k0 += 64) {
    uint4 a0 = *(const uint4*)(aP+k0),    a1 = *(const uint4*)(aP+k0+8);
    uint4 a2 = *(const uint4*)(aP+k0+16), a3 = *(const uint4*)(aP+k0+24);
    uint4 b0 = *(const uint4*)(bP+k0),    b1 = *(const uint4*)(bP+k0+8);
    uint4 b2 = *(const uint4*)(bP+k0+16), b3 = *(const uint4*)(bP+k0+24);
    __syncthreads();
    *(uint4*)(aw)    = a0; *(uint4*)(aw+8)  = a1;
    *(uint4*)(aw+16) = a2; *(uint4*)(aw+24) = a3;
    *(uint4*)(bw)    = b0; *(uint4*)(bw+8)  = b1;
    *(uint4*)(bw+16) = b2; *(uint4*)(bw+24) = b3;
    __syncthreads();
#pragma unroll
    for (int kk = 0; kk < 2; kk++) {
      bf16x8 af[4], bfr[4];
#pragma unroll
      for (int m = 0; m < 4; m++)
        af[m] = *(const bf16x8*)&As[(wr*64+m*16+lrow)*72 + kk*32 + lkb*8];
#pragma unroll
      for (int n = 0; n < 4; n++)
        bfr[n] = *(const bf16x8*)&Bs[(wc*64+n*16+lrow)*72 + kk*32 + lkb*8];
#pragma unroll
      for (int m = 0; m < 4; m++)
#pragma unroll
        for (int n = 0; n < 4; n++)
          acc[m][n] = __builtin_amdgcn_mfma_f32_16x16x32_bf16(af[m], bfr[n], acc[m][n], 0, 0, 0);
    }
  }
  const int r4 = lane>>4;
#pragma unroll
  for (int m = 0; m < 4; m++) {
#pragma unroll
    for (int r = 0; r < 4; r++) {
      const int grow = m0 + wr*64 + m*16 + r4*4 + r;
      if (EPI == 0) {
        const int b = grow/196, nn = grow - b*196;
#pragma unroll
        for (int n = 0; n < 4; n++) {
          const int gcol = n0 + wc*64 + n*16 + lrow;
          const int three = gcol/768, rem = gcol - three*768;
          const int h = rem>>6, dd = rem&63;
          float v = acc[m][n][r] * (three < 2 ? RS : 1.0f);
          float* base = (three == 0) ? p0 : (three == 1) ? p1 : p2;
          base[((size_t)(b*12+h)*196 + nn)*64 + dd] = v;
        }
      } else {
#pragma unroll
        for (int n = 0; n < 4; n++) {
          const int gcol = n0 + wc*64 + n*16 + lrow;
          p0[(size_t)grow*768 + gcol] = acc[m][n][r] + bias[gcol];
        }
      }
    }
  }
}

// ---------------- K2a: S = Q K^T (batched, 32x32 tiles) ----------------
__global__ __launch_bounds__(256) void k_qk(const float* __restrict__ qbuf,
                                            const float* __restrict__ kbuf,
                                            float* __restrict__ S) {
  __shared__ float Qs[32][68];
  __shared__ float Ks[32][68];
  const int t = threadIdx.x;
  const int bh = blockIdx.x;
  const int r0 = blockIdx.y * 32, c0 = blockIdx.z * 32;
  const float* qp = qbuf + (size_t)bh * Nn * Dd;
  const float* kp = kbuf + (size_t)bh * Nn * Dd;
#pragma unroll
  for (int i = 0; i < 2; i++) {
    int idx = t + i*256;            // float4 index
    int row = idx >> 4, kv = idx & 15;
    float4 qv = make_float4(0,0,0,0), kk4 = make_float4(0,0,0,0);
    int gr = r0 + row;
    if (gr < Nn) qv = *(const float4*)(qp + (size_t)gr*Dd + kv*4);
    int gc = c0 + row;
    if (gc < Nn) kk4 = *(const float4*)(kp + (size_t)gc*Dd + kv*4);
    *(float4*)&Qs[row][kv*4] = qv;
    *(float4*)&Ks[row][kv*4] = kk4;
  }
  __syncthreads();
  const int tx = t & 15, ty = t >> 4;
  float acc[2][2] = {};
#pragma unroll
  for (int kk = 0; kk < 64; kk++) {
    float a0 = Qs[ty*2+0][kk], a1 = Qs[ty*2+1][kk];
    float b0 = Ks[tx*2+0][kk], b1 = Ks[tx*2+1][kk];
    acc[0][0] = fmaf(a0,b0,acc[0][0]); acc[0][1] = fmaf(a0,b1,acc[0][1]);
    acc[1][0] = fmaf(a1,b0,acc[1][0]); acc[1][1] = fmaf(a1,b1,acc[1][1]);
  }
#pragma unroll
  for (int i = 0; i < 2; i++) {
    int rr = r0 + ty*2 + i;
    if (rr >= Nn) continue;
#pragma unroll
    for (int j = 0; j < 2; j++) {
      int cc2 = c0 + tx*2 + j;
      if (cc2 < Nn) S[((size_t)bh*Nn + rr)*Nn + cc2] = acc[i][j];
    }
  }
}

// ---------------- K2b: row softmax, src -> dst ----------------
__global__ __launch_bounds__(256) void k_softmax(const float* __restrict__ src,
                                                 float* __restrict__ dst) {
  const int row = blockIdx.x*4 + (threadIdx.x >> 6);
  const int lane = threadIdx.x & 63;
  const float* p = src + (size_t)row * Nn;
  float* o = dst + (size_t)row * Nn;
  float v[4];
  float mx = -1e30f;
#pragma unroll
  for (int i = 0; i < 4; i++) {
    int m = lane + i*64;
    v[i] = (m < Nn) ? p[m] : -1e30f;
    mx = fmaxf(mx, v[i]);
  }
#pragma unroll
  for (int off = 32; off; off >>= 1) mx = fmaxf(mx, __shfl_xor(mx, off, 64));
  float sum = 0.0f;
#pragma unroll
  for (int i = 0; i < 4; i++) {
    int m = lane + i*64;
    v[i] = (m < Nn) ? __expf(v[i]-mx) : 0.0f;
    sum += v[i];
  }
#pragma unroll
  for (int off = 32; off; off >>= 1) sum += __shfl_xor(sum, off, 64);
  float inv = 1.0f / sum;
#pragma unroll
  for (int i = 0; i < 4; i++) {
    int m = lane + i*64;
    if (m < Nn) o[m] = v[i]*inv;
  }
}

// ---------------- K3: y1 = conv_exp(attn) stats (recompute, no store) ----------------
// weights via wave-uniform global reads (scalar loads); grid 256 blocks
__global__ __launch_bounds__(256) void k_y1stats(const float* __restrict__ attn,
                                                 const float* __restrict__ w_exp,
                                                 float* __restrict__ part) {
  __shared__ float red2[4*72];
  const int t = threadIdx.x;
  float s1[36] = {}, s2[36] = {};
  const int stride = gridDim.x * 256;
  for (int s = blockIdx.x*256 + t; s < SAMP; s += stride) {
    int b = s / NN2, p = s - b*NN2;
    float a[12];
#pragma unroll
    for (int h = 0; h < 12; h++) a[h] = attn[((size_t)(b*12+h))*NN2 + p];
#pragma unroll
    for (int c = 0; c < 36; c++) {
      float y = 0.0f;
#pragma unroll
      for (int h = 0; h < 12; h++) y = fmaf(w_exp[c*12+h], a[h], y);
      s1[c] += y; s2[c] += y*y;
    }
  }
#pragma unroll
  for (int c = 0; c < 36; c++) {
#pragma unroll
    for (int off = 32; off; off >>= 1) {
      s1[c] += __shfl_xor(s1[c], off, 64);
      s2[c] += __shfl_xor(s2[c], off, 64);
    }
  }
  const int w = t >> 6;
  if ((t & 63) == 0) {
#pragma unroll
    for (int c = 0; c < 36; c++) { red2[w*72 + c] = s1[c]; red2[w*72 + 36 + c] = s2[c]; }
  }
  __syncthreads();
  if (t < 72)
    part[(size_t)blockIdx.x*72 + t] = red2[t] + red2[72+t] + red2[144+t] + red2[216+t];
}

// ---------------- hierarchical deterministic reduce: part[nb][stride] -> dsum[stride] ----------------
__global__ __launch_bounds__(256) void k_reduce(const float* __restrict__ part, int nb,
                                               int stride, double* __restrict__ dsum) {
  __shared__ double sh[256];
  const int c = blockIdx.x;       // one block per channel-stat
  const int t = threadIdx.x;
  double s = 0.0;
  for (int i = t; i < nb; i += 256) s += (double)part[(size_t)i*stride + c];
  sh[t] = s;
  __syncthreads();
  for (int o = 128; o; o >>= 1) {
    if (t < o) sh[t] += sh[t + o];
    __syncthreads();
  }
  if (t == 0) dsum[c] = sh[0];
}

// ---------------- dsum -> BN affine (36 ch) ----------------
__global__ void k_bnaffine36(const double* __restrict__ dsum,
                             const float* __restrict__ g, const float* __restrict__ beta,
                             float* __restrict__ stats, int off) {
  int c = threadIdx.x;
  if (c >= 36) return;
  double m = dsum[c] / (double)SAMP;
  double v = dsum[36 + c] / (double)SAMP - m*m;
  float a = g[c] * rsqrtf((float)v + 1e-5f);
  stats[off + c] = a;
  stats[off + 36 + c] = beta[c] - (float)m * a;
}

// ---- tiled DLA recompute, channel-chunked (3 groups of 12), attn in registers,
// weights via wave-uniform global reads (scalar loads), LDS-staged stat reduction.
// MODE 0: y2 stats -> part[blk][72].  MODE 1: z write (to zout) + z stats -> part[blk][24].
template<int MODE>
__global__ __launch_bounds__(256) void k_dla(const float* __restrict__ attn,
                                             const float* __restrict__ w_exp,
                                             const float* __restrict__ w_dw,
                                             const float* __restrict__ w_pro,
                                             const float* __restrict__ stats,
                                             float* __restrict__ zout,
                                             float* __restrict__ part) {
  __shared__ float y_s[12*256];   // per-group y1c halo tiles
  __shared__ float z2[12*200];    // staged y2 / z inner-pixel values for reduction
  const int t = threadIdx.x;
  const int blk = blockIdx.x;
  const int b = blk / 196, tile = blk - b*196;
  const int tyq = tile / 14;
  const int ty0 = tyq * 14, tx0 = (tile - tyq*14) * 14;
  // this thread's halo coordinate
  const int hy = ty0 + (t >> 4) - 1, hx = tx0 + (t & 15) - 1;
  const bool inb = (hy >= 0) && (hy < 196) && (hx >= 0) && (hx < 196);
  float a[12];
#pragma unroll
  for (int ch = 0; ch < 12; ch++)
    a[ch] = inb ? attn[((size_t)(b*12+ch))*NN2 + (size_t)hy*196 + hx] : 0.0f;

  const bool act = (t < 196);
  const int py = t / 14, px = t - py*14;
  const int base = (py+1)*16 + (px+1);
  float z[12] = {};
  // reduction role: stat rs = t>>3 (24 used), segment seg = t&7 over pixels
  const int rs = t >> 3;
  const int seg = t & 7;
  const int pix0 = seg*25;
  const int pcnt = (seg == 7) ? 21 : 25;

  for (int g = 0; g < 3; g++) {
    __syncthreads();   // y_s free (prev group's reads done)
#pragma unroll
    for (int cl = 0; cl < 12; cl++) {
      const int c = g*12 + cl;
      float y = 0.0f;
#pragma unroll
      for (int h = 0; h < 12; h++) y = fmaf(w_exp[c*12+h], a[h], y);
      y = y*stats[c] + stats[36+c];
      y = fminf(fmaxf(y, 0.0f), 6.0f);
      y_s[cl*256 + t] = inb ? y : 0.0f;
    }
    __syncthreads();
    float y2v[12];
    if (act) {
#pragma unroll
      for (int cl = 0; cl < 12; cl++) {
        const int c = g*12 + cl;
        const float* ys = &y_s[cl*256];
        float y2 = 0.0f;
#pragma unroll
        for (int di = 0; di < 3; di++)
#pragma unroll
          for (int dj = 0; dj < 3; dj++)
            y2 = fmaf(w_dw[c*9 + di*3 + dj], ys[base + (di-1)*16 + (dj-1)], y2);
        y2v[cl] = y2;
        if (MODE == 1) {
          float y2c = y2*stats[72+c] + stats[108+c];
          y2c = fminf(fmaxf(y2c, 0.0f), 6.0f);
#pragma unroll
          for (int cc = 0; cc < 12; cc++) z[cc] = fmaf(w_pro[cc*36+c], y2c, z[cc]);
        }
      }
    }
    if (MODE == 0) {
      __syncthreads();  // prev reduction's z2 reads done
      if (act) {
#pragma unroll
        for (int cl = 0; cl < 12; cl++) z2[cl*200 + t] = y2v[cl];
      }
      __syncthreads();
      if (rs < 24) {
        const int cl = rs % 12, wh = rs / 12;
        float s = 0.0f;
        for (int i = 0; i < pcnt; i++) {
          float v = z2[cl*200 + pix0 + i];
          s += wh ? v*v : v;
        }
        s += __shfl_xor(s, 1, 64);
        s += __shfl_xor(s, 2, 64);
        s += __shfl_xor(s, 4, 64);
        if (seg == 0)
          part[(size_t)blk*72 + wh*36 + g*12 + cl] = s;
      }
    }
  }

  if (MODE == 1) {
    if (act) {
      const int oy = ty0 + py, ox = tx0 + px;
#pragma unroll
      for (int cc = 0; cc < 12; cc++) {
        zout[((size_t)(b*12+cc))*NN2 + (size_t)oy*196 + ox] = z[cc];
        z2[cc*200 + t] = z[cc];
      }
    }
    __syncthreads();
    if (rs < 24) {
      const int cl = rs % 12, wh = rs / 12;
      float s = 0.0f;
      for (int i = 0; i < pcnt; i++) {
        float v = z2[cl*200 + pix0 + i];
        s += wh ? v*v : v;
      }
      s += __shfl_xor(s, 1, 64);
      s += __shfl_xor(s, 2, 64);
      s += __shfl_xor(s, 4, 64);
      if (seg == 0)
        part[(size_t)blk*24 + wh*12 + cl] = s;
    }
  }
}

// ---------------- combined bn3 + adapt_bn affine (from dsum[24]) ----------------
__global__ void k_bnfinal(const double* __restrict__ dsum,
                          const float* __restrict__ g3, const float* __restrict__ b3,
                          const float* __restrict__ ag, const float* __restrict__ ab,
                          float* __restrict__ stats) {
  int c = threadIdx.x;
  if (c >= 12) return;
  (void)b3; // bn3 beta cancels exactly in the composed affine
  double m = dsum[c] / (double)SAMP;
  double v = dsum[12 + c] / (double)SAMP - m*m;
  float r1 = rsqrtf((float)v + 1e-5f);
  float vt = g3[c]*g3[c]*(float)v*r1*r1;
  float r2 = rsqrtf(vt + 1e-5f);
  float A = g3[c]*ag[c]*r1*r2;
  stats[144 + c] = A;
  stats[156 + c] = ab[c] - (float)m*A;
}

// ---------------- PV: attn_r = z*Af+Bf (in-place write), O = attn_r @ V -> out_pre bf16 ----------------
__global__ __launch_bounds__(256) void k_pv(float* __restrict__ attn_r,
                                            const float* __restrict__ vbuf,
                                            const float* __restrict__ stats,
                                            ushort* __restrict__ out_pre) {
  __shared__ float Vs[196*65];
  __shared__ float ar_s[16*200];
  const int t = threadIdx.x;
  const int bh = blockIdx.x;
  const int b = bh / 12, h = bh - b*12;
  const float Af = stats[144 + h], Bf = stats[156 + h];
  const float* vp = vbuf + (size_t)bh * Nn * Dd;
#pragma unroll
  for (int i = 0; i < 49; i++) {
    int idx = t + i*256;
    Vs[(idx >> 6)*65 + (idx & 63)] = vp[idx];
  }
  float* arp = attn_r + (size_t)bh * NN2;
  const int dd = t & 63, wy = t >> 6;
  for (int ch = 0; ch < 13; ch++) {
    const int r0 = ch*16;
    const int nrows = (r0 + 16 <= 196) ? 16 : (196 - r0);
    __syncthreads();
    for (int idx = t; idx < nrows*196; idx += 256) {
      int rr = idx / 196, m = idx - rr*196;
      float val = fmaf(arp[(size_t)(r0+rr)*196 + m], Af, Bf);
      arp[(size_t)(r0+rr)*196 + m] = val;     // z -> attn_r in place
      ar_s[rr*200 + m] = val;
    }
    __syncthreads();
    float acc[4] = {0,0,0,0};
#pragma unroll 2
    for (int m = 0; m < 196; m++) {
      float vv = Vs[m*65 + dd];
#pragma unroll
      for (int r = 0; r < 4; r++) acc[r] = fmaf(ar_s[(wy*4+r)*200 + m], vv, acc[r]);
    }
#pragma unroll
    for (int r = 0; r < 4; r++) {
      int rr = wy*4 + r;
      if (rr < nrows)
        out_pre[((size_t)(b*196 + r0 + rr))*Cc + h*64 + dd] = f2b(acc[r]);
    }
  }
}

// ---------------- launch ----------------
extern "C" void kernel_launch(void* const* d_in, const int* in_sizes, int n_in,
                              void* d_out, int out_size, void* d_ws, size_t ws_size,
                              hipStream_t stream) {
  (void)in_sizes; (void)n_in; (void)out_size; (void)ws_size;
  const float* x      = (const float*)d_in[0];
  const float* w_qkv  = (const float*)d_in[1];
  const float* w_exp  = (const float*)d_in[2];
  const float* bn1_g  = (const float*)d_in[3];
  const float* bn1_b  = (const float*)d_in[4];
  const float* w_dw   = (const float*)d_in[5];
  const float* bn2_g  = (const float*)d_in[6];
  const float* bn2_b  = (const float*)d_in[7];
  const float* w_pro  = (const float*)d_in[8];
  const float* bn3_g  = (const float*)d_in[9];
  const float* bn3_b  = (const float*)d_in[10];
  const float* abn_g  = (const float*)d_in[11];
  const float* abn_b  = (const float*)d_in[12];
  const float* w_proj = (const float*)d_in[13];
  const float* b_proj = (const float*)d_in[14];

  float* out      = (float*)d_out;
  float* attn_out = out + (size_t)QSZ;     // d_out's attn_r region (S scratch -> z -> attn_r)
  float* ws    = (float*)d_ws;
  float* vbuf  = ws;                        // [QSZ]
  float* big   = ws + (size_t)QSZ;          // [ATT]: q,k -> attn -> out_pre(bf16)
  float* qbuf  = big;
  float* kbuf  = big + (size_t)QSZ;
  float* stats = ws + (size_t)QSZ + ATT;    // [256]
  float* part  = stats + 256;               // [6272*72]
  double* dsum = (double*)(part + (size_t)6272*72); // [96] doubles (8B-aligned)

  // bf16 staging buffers in dead regions:
  ushort* xb   = (ushort*)out;              // [QSZ] bf16 — out[0..QSZ) untouched until proj
  ushort* wqb  = xb + (size_t)QSZ;          // [2304*768] bf16
  ushort* opb  = (ushort*)big;              // out_pre bf16 (attn in big dead by then)
  ushort* wpb  = (ushort*)part;             // w_proj bf16 (part dead after last reduce)

  k_cast <<<QSZ/2048, 256, 0, stream>>>(x, xb);
  k_cast <<<(2304*768)/2048, 256, 0, stream>>>(w_qkv, wqb);
  k_mfma_gemm<0><<<dim3(18, 49), 256, 0, stream>>>(xb, wqb, nullptr, qbuf, kbuf, vbuf);
  k_qk       <<<dim3(384, 7, 7), 256, 0, stream>>>(qbuf, kbuf, attn_out);   // S -> d_out scratch
  k_softmax  <<<18816, 256, 0, stream>>>(attn_out, big);                    // attn -> ws (q,k dead)
  k_y1stats  <<<256, 256, 0, stream>>>(big, w_exp, part);
  k_reduce   <<<72, 256, 0, stream>>>(part, 256, 72, dsum);
  k_bnaffine36<<<1, 64, 0, stream>>>(dsum, bn1_g, bn1_b, stats, 0);
  k_dla<0>   <<<6272, 256, 0, stream>>>(big, w_exp, w_dw, nullptr, stats, nullptr, part);
  k_reduce   <<<72, 256, 0, stream>>>(part, 6272, 72, dsum);
  k_bnaffine36<<<1, 64, 0, stream>>>(dsum, bn2_g, bn2_b, stats, 72);
  k_dla<1>   <<<6272, 256, 0, stream>>>(big, w_exp, w_dw, w_pro, stats, attn_out, part);
  k_reduce   <<<24, 256, 0, stream>>>(part, 6272, 24, dsum);
  k_bnfinal  <<<1, 64, 0, stream>>>(dsum, bn3_g, bn3_b, abn_g, abn_b, stats);
  k_cast     <<<(768*768)/2048, 256, 0, stream>>>(w_proj, wpb);             // part now dead
  k_pv       <<<384, 256, 0, stream>>>(attn_out, vbuf, stats, opb);         // affine+PV fused
  k_mfma_gemm<1><<<dim3(6, 49), 256, 0, stream>>>(opb, wpb, b_proj, out, nullptr, nullptr);
}

// Round 8
// 543.170 us; speedup vs baseline: 6.9146x; 1.3339x over previous
//
#include <hip/hip_runtime.h>
#include <hip/hip_bf16.h>
#include <math.h>

// ---------------- problem constants ----------------
constexpr int Bz  = 32;
constexpr int Nn  = 196;
constexpr int Cc  = 768;
constexpr int Hh  = 12;
constexpr int Dd  = 64;
constexpr int HID = 36;           // Hh * 3
constexpr int NN2 = Nn * Nn;      // 38416
constexpr int QSZ = Bz * Nn * Cc;          // 4,816,896
constexpr int ATT = Bz * Hh * NN2;         // 14,751,744
constexpr int SAMP = Bz * NN2;    // 1,229,312 samples per BN channel
constexpr float RS = 0.35355339059327373f; // 64^-0.25

typedef short bf16x8 __attribute__((ext_vector_type(8)));
typedef float f32x4  __attribute__((ext_vector_type(4)));

__device__ inline ushort f2b(float f) {
  __hip_bfloat16 h = __float2bfloat16(f);
  return *reinterpret_cast<ushort*>(&h);
}
__device__ inline float b2f(ushort u) {
  union { float f; unsigned i; } x; x.i = ((unsigned)u) << 16; return x.f;
}

// ---------------- f32 -> bf16 cast (8 elems/thread) ----------------
__global__ __launch_bounds__(256) void k_cast(const float* __restrict__ in,
                                              ushort* __restrict__ outp) {
  const int j = blockIdx.x*256 + threadIdx.x;       // 8-elem group
  float4 a = ((const float4*)in)[2*j];
  float4 b = ((const float4*)in)[2*j+1];
  ushort o[8] = { f2b(a.x), f2b(a.y), f2b(a.z), f2b(a.w),
                  f2b(b.x), f2b(b.y), f2b(b.z), f2b(b.w) };
  ((uint4*)outp)[j] = *(const uint4*)o;
}

// ---------------- bf16 MFMA GEMM: C = A[M,768] x B[N,768]^T ----------------
// EPI 0: qkv epilogue (RS scale q,k; bf16 scatter to [B,H,N,D]); EPI 1: +bias, f32 row-major
template<int EPI>
__global__ __launch_bounds__(256) void k_mfma_gemm(const ushort* __restrict__ A,
                                                   const ushort* __restrict__ B,
                                                   const float* __restrict__ bias,
                                                   void* __restrict__ o0,
                                                   void* __restrict__ o1,
                                                   void* __restrict__ o2) {
  __shared__ ushort As[128*72];   // 128 rows x 64 k, stride 72 (pad kills bank conflicts)
  __shared__ ushort Bs[128*72];
  const int t = threadIdx.x;
  const int m0 = blockIdx.y*128, n0 = blockIdx.x*128;
  const int w = t>>6, lane = t&63;
  const int wr = w>>1, wc = w&1;         // wave -> 64x64 quadrant
  const int lrow = lane&15, lkb = lane>>4;
  f32x4 acc[4][4] = {};
  const int srow = t>>1, skoff = (t&1)*32;
  const ushort* aP = A + (size_t)(m0+srow)*768 + skoff;
  const ushort* bP = B + (size_t)(n0+srow)*768 + skoff;
  ushort* aw = &As[srow*72 + skoff];
  ushort* bw = &Bs[srow*72 + skoff];
  for (int k0 = 0; k0 < 768; k0 += 64) {
    uint4 a0 = *(const uint4*)(aP+k0),    a1 = *(const uint4*)(aP+k0+8);
    uint4 a2 = *(const uint4*)(aP+k0+16), a3 = *(const uint4*)(aP+k0+24);
    uint4 b0 = *(const uint4*)(bP+k0),    b1 = *(const uint4*)(bP+k0+8);
    uint4 b2 = *(const uint4*)(bP+k0+16), b3 = *(const uint4*)(bP+k0+24);
    __syncthreads();
    *(uint4*)(aw)    = a0; *(uint4*)(aw+8)  = a1;
    *(uint4*)(aw+16) = a2; *(uint4*)(aw+24) = a3;
    *(uint4*)(bw)    = b0; *(uint4*)(bw+8)  = b1;
    *(uint4*)(bw+16) = b2; *(uint4*)(bw+24) = b3;
    __syncthreads();
#pragma unroll
    for (int kk = 0; kk < 2; kk++) {
      bf16x8 af[4], bfr[4];
#pragma unroll
      for (int m = 0; m < 4; m++)
        af[m] = *(const bf16x8*)&As[(wr*64+m*16+lrow)*72 + kk*32 + lkb*8];
#pragma unroll
      for (int n = 0; n < 4; n++)
        bfr[n] = *(const bf16x8*)&Bs[(wc*64+n*16+lrow)*72 + kk*32 + lkb*8];
#pragma unroll
      for (int m = 0; m < 4; m++)
#pragma unroll
        for (int n = 0; n < 4; n++)
          acc[m][n] = __builtin_amdgcn_mfma_f32_16x16x32_bf16(af[m], bfr[n], acc[m][n], 0, 0, 0);
    }
  }
  const int r4 = lane>>4;
#pragma unroll
  for (int m = 0; m < 4; m++) {
#pragma unroll
    for (int r = 0; r < 4; r++) {
      const int grow = m0 + wr*64 + m*16 + r4*4 + r;
      if (EPI == 0) {
        ushort* q = (ushort*)o0; ushort* k = (ushort*)o1; ushort* v = (ushort*)o2;
        const int b = grow/196, nn = grow - b*196;
#pragma unroll
        for (int n = 0; n < 4; n++) {
          const int gcol = n0 + wc*64 + n*16 + lrow;
          const int three = gcol/768, rem = gcol - three*768;
          const int h = rem>>6, dd = rem&63;
          float val = acc[m][n][r] * (three < 2 ? RS : 1.0f);
          ushort* base = (three == 0) ? q : (three == 1) ? k : v;
          base[((size_t)(b*12+h)*196 + nn)*64 + dd] = f2b(val);
        }
      } else {
        float* outp = (float*)o0;
#pragma unroll
        for (int n = 0; n < 4; n++) {
          const int gcol = n0 + wc*64 + n*16 + lrow;
          outp[(size_t)grow*768 + gcol] = acc[m][n][r] + bias[gcol];
        }
      }
    }
  }
}

// ---------------- fused QK^T (MFMA) + row softmax -> attn f32 ----------------
// grid (384, 7): bh, 32-row tile. K staged in LDS bf16, Q fragments in regs.
__global__ __launch_bounds__(256) void k_qks(const ushort* __restrict__ qb,
                                             const ushort* __restrict__ kb,
                                             float* __restrict__ attn) {
  __shared__ ushort K_lds[208*68];   // 28288 B
  __shared__ float  S_lds[32*210];   // 26880 B, stride 210 (~2-way banking)
  __shared__ float  sms[32];
  const int t = threadIdx.x;
  const int bh = blockIdx.x;
  const int r0 = blockIdx.y * 32;
  const ushort* kp = kb + (size_t)bh*Nn*Dd;
  const ushort* qp = qb + (size_t)bh*Nn*Dd;
  // K rows 0..195 -> LDS (8 bf16 per iter)
  for (int i = t; i < 1568; i += 256) {
    int row = i >> 3, ko = (i & 7)*8;
    *(uint4*)&K_lds[row*68 + ko] = *(const uint4*)(kp + (size_t)row*64 + ko);
  }
  // zero pad rows 196..207
  for (int i = t; i < 408; i += 256)
    ((unsigned*)&K_lds[196*68])[i] = 0u;
  const int w = t >> 6, lane = t & 63;
  const int mt = w >> 1;                 // wave's 16-row tile (0/1)
  const int lrow = lane & 15, lk = lane >> 4;
  int qrow = r0 + mt*16 + lrow; if (qrow > 195) qrow = 195;   // clamp (rows unused)
  bf16x8 aq0 = *(const bf16x8*)(qp + (size_t)qrow*64 + lk*8);
  bf16x8 aq1 = *(const bf16x8*)(qp + (size_t)qrow*64 + 32 + lk*8);
  __syncthreads();
  for (int nt = (w & 1); nt < 13; nt += 2) {
    f32x4 acc = {};
    bf16x8 b0 = *(const bf16x8*)&K_lds[(nt*16 + lrow)*68 + lk*8];
    acc = __builtin_amdgcn_mfma_f32_16x16x32_bf16(aq0, b0, acc, 0, 0, 0);
    bf16x8 b1 = *(const bf16x8*)&K_lds[(nt*16 + lrow)*68 + 32 + lk*8];
    acc = __builtin_amdgcn_mfma_f32_16x16x32_bf16(aq1, b1, acc, 0, 0, 0);
#pragma unroll
    for (int r = 0; r < 4; r++)
      S_lds[(mt*16 + lk*4 + r)*210 + nt*16 + lrow] = acc[r];
  }
  __syncthreads();
  // softmax: 8 threads per row
  const int sr = t >> 3, sj = t & 7;
  float mx = -1e30f;
  for (int c = sj; c < 196; c += 8) mx = fmaxf(mx, S_lds[sr*210 + c]);
  mx = fmaxf(mx, __shfl_xor(mx, 1, 64));
  mx = fmaxf(mx, __shfl_xor(mx, 2, 64));
  mx = fmaxf(mx, __shfl_xor(mx, 4, 64));
  float sum = 0.0f;
  for (int c = sj; c < 196; c += 8) {
    float e = __expf(S_lds[sr*210 + c] - mx);
    S_lds[sr*210 + c] = e;
    sum += e;
  }
  sum += __shfl_xor(sum, 1, 64);
  sum += __shfl_xor(sum, 2, 64);
  sum += __shfl_xor(sum, 4, 64);
  if (sj == 0) sms[sr] = 1.0f / sum;
  __syncthreads();
  const int nvalid = (r0 + 32 <= 196) ? 32 : (196 - r0);
  for (int idx = t; idx < nvalid*196; idx += 256) {
    int rr = idx / 196, cc = idx - rr*196;
    attn[((size_t)bh*196 + r0 + rr)*196 + cc] = S_lds[rr*210 + cc] * sms[rr];
  }
}

// ---------------- K3: y1 = conv_exp(attn) stats (recompute, no store) ----------------
__global__ __launch_bounds__(256) void k_y1stats(const float* __restrict__ attn,
                                                 const float* __restrict__ w_exp,
                                                 float* __restrict__ part) {
  __shared__ float red2[4*72];
  const int t = threadIdx.x;
  float s1[36] = {}, s2[36] = {};
  const int stride = gridDim.x * 256;
  for (int s = blockIdx.x*256 + t; s < SAMP; s += stride) {
    int b = s / NN2, p = s - b*NN2;
    float a[12];
#pragma unroll
    for (int h = 0; h < 12; h++) a[h] = attn[((size_t)(b*12+h))*NN2 + p];
#pragma unroll
    for (int c = 0; c < 36; c++) {
      float y = 0.0f;
#pragma unroll
      for (int h = 0; h < 12; h++) y = fmaf(w_exp[c*12+h], a[h], y);
      s1[c] += y; s2[c] += y*y;
    }
  }
#pragma unroll
  for (int c = 0; c < 36; c++) {
#pragma unroll
    for (int off = 32; off; off >>= 1) {
      s1[c] += __shfl_xor(s1[c], off, 64);
      s2[c] += __shfl_xor(s2[c], off, 64);
    }
  }
  const int w = t >> 6;
  if ((t & 63) == 0) {
#pragma unroll
    for (int c = 0; c < 36; c++) { red2[w*72 + c] = s1[c]; red2[w*72 + 36 + c] = s2[c]; }
  }
  __syncthreads();
  if (t < 72)
    part[(size_t)blockIdx.x*72 + t] = red2[t] + red2[72+t] + red2[144+t] + red2[216+t];
}

// ---------------- hierarchical deterministic reduce ----------------
__global__ __launch_bounds__(256) void k_reduce(const float* __restrict__ part, int nb,
                                               int stride, double* __restrict__ dsum) {
  __shared__ double sh[256];
  const int c = blockIdx.x;
  const int t = threadIdx.x;
  double s = 0.0;
  for (int i = t; i < nb; i += 256) s += (double)part[(size_t)i*stride + c];
  sh[t] = s;
  __syncthreads();
  for (int o = 128; o; o >>= 1) {
    if (t < o) sh[t] += sh[t + o];
    __syncthreads();
  }
  if (t == 0) dsum[c] = sh[0];
}

// ---------------- dsum -> BN affine (36 ch) ----------------
__global__ void k_bnaffine36(const double* __restrict__ dsum,
                             const float* __restrict__ g, const float* __restrict__ beta,
                             float* __restrict__ stats, int off) {
  int c = threadIdx.x;
  if (c >= 36) return;
  double m = dsum[c] / (double)SAMP;
  double v = dsum[36 + c] / (double)SAMP - m*m;
  float a = g[c] * rsqrtf((float)v + 1e-5f);
  stats[off + c] = a;
  stats[off + 36 + c] = beta[c] - (float)m * a;
}

// ---- tiled DLA recompute (unchanged structure from round 7) ----
template<int MODE>
__global__ __launch_bounds__(256) void k_dla(const float* __restrict__ attn,
                                             const float* __restrict__ w_exp,
                                             const float* __restrict__ w_dw,
                                             const float* __restrict__ w_pro,
                                             const float* __restrict__ stats,
                                             float* __restrict__ zout,
                                             float* __restrict__ part) {
  __shared__ float y_s[12*256];
  __shared__ float z2[12*200];
  const int t = threadIdx.x;
  const int blk = blockIdx.x;
  const int b = blk / 196, tile = blk - b*196;
  const int tyq = tile / 14;
  const int ty0 = tyq * 14, tx0 = (tile - tyq*14) * 14;
  const int hy = ty0 + (t >> 4) - 1, hx = tx0 + (t & 15) - 1;
  const bool inb = (hy >= 0) && (hy < 196) && (hx >= 0) && (hx < 196);
  float a[12];
#pragma unroll
  for (int ch = 0; ch < 12; ch++)
    a[ch] = inb ? attn[((size_t)(b*12+ch))*NN2 + (size_t)hy*196 + hx] : 0.0f;

  const bool act = (t < 196);
  const int py = t / 14, px = t - py*14;
  const int base = (py+1)*16 + (px+1);
  float z[12] = {};
  const int rs = t >> 3;
  const int seg = t & 7;
  const int pix0 = seg*25;
  const int pcnt = (seg == 7) ? 21 : 25;

  for (int g = 0; g < 3; g++) {
    __syncthreads();
#pragma unroll
    for (int cl = 0; cl < 12; cl++) {
      const int c = g*12 + cl;
      float y = 0.0f;
#pragma unroll
      for (int h = 0; h < 12; h++) y = fmaf(w_exp[c*12+h], a[h], y);
      y = y*stats[c] + stats[36+c];
      y = fminf(fmaxf(y, 0.0f), 6.0f);
      y_s[cl*256 + t] = inb ? y : 0.0f;
    }
    __syncthreads();
    float y2v[12];
    if (act) {
#pragma unroll
      for (int cl = 0; cl < 12; cl++) {
        const int c = g*12 + cl;
        const float* ys = &y_s[cl*256];
        float y2 = 0.0f;
#pragma unroll
        for (int di = 0; di < 3; di++)
#pragma unroll
          for (int dj = 0; dj < 3; dj++)
            y2 = fmaf(w_dw[c*9 + di*3 + dj], ys[base + (di-1)*16 + (dj-1)], y2);
        y2v[cl] = y2;
        if (MODE == 1) {
          float y2c = y2*stats[72+c] + stats[108+c];
          y2c = fminf(fmaxf(y2c, 0.0f), 6.0f);
#pragma unroll
          for (int cc = 0; cc < 12; cc++) z[cc] = fmaf(w_pro[cc*36+c], y2c, z[cc]);
        }
      }
    }
    if (MODE == 0) {
      __syncthreads();
      if (act) {
#pragma unroll
        for (int cl = 0; cl < 12; cl++) z2[cl*200 + t] = y2v[cl];
      }
      __syncthreads();
      if (rs < 24) {
        const int cl = rs % 12, wh = rs / 12;
        float s = 0.0f;
        for (int i = 0; i < pcnt; i++) {
          float v = z2[cl*200 + pix0 + i];
          s += wh ? v*v : v;
        }
        s += __shfl_xor(s, 1, 64);
        s += __shfl_xor(s, 2, 64);
        s += __shfl_xor(s, 4, 64);
        if (seg == 0)
          part[(size_t)blk*72 + wh*36 + g*12 + cl] = s;
      }
    }
  }

  if (MODE == 1) {
    if (act) {
      const int oy = ty0 + py, ox = tx0 + px;
#pragma unroll
      for (int cc = 0; cc < 12; cc++) {
        zout[((size_t)(b*12+cc))*NN2 + (size_t)oy*196 + ox] = z[cc];
        z2[cc*200 + t] = z[cc];
      }
    }
    __syncthreads();
    if (rs < 24) {
      const int cl = rs % 12, wh = rs / 12;
      float s = 0.0f;
      for (int i = 0; i < pcnt; i++) {
        float v = z2[cl*200 + pix0 + i];
        s += wh ? v*v : v;
      }
      s += __shfl_xor(s, 1, 64);
      s += __shfl_xor(s, 2, 64);
      s += __shfl_xor(s, 4, 64);
      if (seg == 0)
        part[(size_t)blk*24 + wh*12 + cl] = s;
    }
  }
}

// ---------------- combined bn3 + adapt_bn affine (from dsum[24]) ----------------
__global__ void k_bnfinal(const double* __restrict__ dsum,
                          const float* __restrict__ g3, const float* __restrict__ b3,
                          const float* __restrict__ ag, const float* __restrict__ ab,
                          float* __restrict__ stats) {
  int c = threadIdx.x;
  if (c >= 12) return;
  (void)b3; // bn3 beta cancels exactly in the composed affine
  double m = dsum[c] / (double)SAMP;
  double v = dsum[12 + c] / (double)SAMP - m*m;
  float r1 = rsqrtf((float)v + 1e-5f);
  float vt = g3[c]*g3[c]*(float)v*r1*r1;
  float r2 = rsqrtf(vt + 1e-5f);
  float A = g3[c]*ag[c]*r1*r2;
  stats[144 + c] = A;
  stats[156 + c] = ab[c] - (float)m*A;
}

// ---------------- PV: attn_r = z*Af+Bf (write), O = attn_r @ V -> out_pre bf16 ----------------
__global__ __launch_bounds__(256) void k_pv(const float* __restrict__ z,
                                            const ushort* __restrict__ v16,
                                            const float* __restrict__ stats,
                                            float* __restrict__ attn_r,
                                            ushort* __restrict__ out_pre) {
  __shared__ float Vs[196*65];
  __shared__ float ar_s[16*200];
  const int t = threadIdx.x;
  const int bh = blockIdx.x;
  const int b = bh / 12, h = bh - b*12;
  const float Af = stats[144 + h], Bf = stats[156 + h];
  const ushort* vp = v16 + (size_t)bh * Nn * Dd;
#pragma unroll
  for (int i = 0; i < 49; i++) {
    int idx = t + i*256;
    Vs[(idx >> 6)*65 + (idx & 63)] = b2f(vp[idx]);
  }
  const float* zp = z + (size_t)bh * NN2;
  float* arp = attn_r + (size_t)bh * NN2;
  const int dd = t & 63, wy = t >> 6;
  for (int ch = 0; ch < 13; ch++) {
    const int r0 = ch*16;
    const int nrows = (r0 + 16 <= 196) ? 16 : (196 - r0);
    __syncthreads();
    for (int idx = t; idx < nrows*196; idx += 256) {
      int rr = idx / 196, m = idx - rr*196;
      float val = fmaf(zp[(size_t)(r0+rr)*196 + m], Af, Bf);
      arp[(size_t)(r0+rr)*196 + m] = val;
      ar_s[rr*200 + m] = val;
    }
    __syncthreads();
    float acc[4] = {0,0,0,0};
#pragma unroll 2
    for (int m = 0; m < 196; m++) {
      float vv = Vs[m*65 + dd];
#pragma unroll
      for (int r = 0; r < 4; r++) acc[r] = fmaf(ar_s[(wy*4+r)*200 + m], vv, acc[r]);
    }
#pragma unroll
    for (int r = 0; r < 4; r++) {
      int rr = wy*4 + r;
      if (rr < nrows)
        out_pre[((size_t)(b*196 + r0 + rr))*Cc + h*64 + dd] = f2b(acc[r]);
    }
  }
}

// ---------------- launch ----------------
extern "C" void kernel_launch(void* const* d_in, const int* in_sizes, int n_in,
                              void* d_out, int out_size, void* d_ws, size_t ws_size,
                              hipStream_t stream) {
  (void)in_sizes; (void)n_in; (void)out_size; (void)ws_size;
  const float* x      = (const float*)d_in[0];
  const float* w_qkv  = (const float*)d_in[1];
  const float* w_exp  = (const float*)d_in[2];
  const float* bn1_g  = (const float*)d_in[3];
  const float* bn1_b  = (const float*)d_in[4];
  const float* w_dw   = (const float*)d_in[5];
  const float* bn2_g  = (const float*)d_in[6];
  const float* bn2_b  = (const float*)d_in[7];
  const float* w_pro  = (const float*)d_in[8];
  const float* bn3_g  = (const float*)d_in[9];
  const float* bn3_b  = (const float*)d_in[10];
  const float* abn_g  = (const float*)d_in[11];
  const float* abn_b  = (const float*)d_in[12];
  const float* w_proj = (const float*)d_in[13];
  const float* b_proj = (const float*)d_in[14];

  float* out      = (float*)d_out;
  float* attn_out = out + (size_t)QSZ;      // d_out attn_r region: attn -> attn_r
  float* ws    = (float*)d_ws;
  // ws layout (floats):
  //  [0, QSZ/2)        v bf16 [QSZ ushorts]
  //  [QSZ/2, QSZ)      out_pre bf16 [QSZ ushorts]
  //  [QSZ, QSZ+ATT)    big: {q bf16, k bf16} -> z f32 [ATT]
  //  [QSZ+ATT, +256)   stats
  //  then part [6272*72], dsum[96] doubles
  ushort* vb16 = (ushort*)ws;
  ushort* opb  = (ushort*)ws + (size_t)QSZ;
  float*  big  = ws + (size_t)QSZ;
  ushort* qb16 = (ushort*)big;
  ushort* kb16 = qb16 + (size_t)QSZ;
  float* stats = ws + (size_t)QSZ + ATT;
  float* part  = stats + 256;
  double* dsum = (double*)(part + (size_t)6272*72);

  // bf16 staging in dead d_out region:
  ushort* xb   = (ushort*)out;              // x bf16 (out[0..QSZ) untouched until proj)
  ushort* wqb  = xb + (size_t)QSZ;          // w_qkv bf16
  ushort* wpb  = (ushort*)part;             // w_proj bf16 (part dead after last reduce)

  k_cast <<<QSZ/2048, 256, 0, stream>>>(x, xb);
  k_cast <<<(2304*768)/2048, 256, 0, stream>>>(w_qkv, wqb);
  k_mfma_gemm<0><<<dim3(18, 49), 256, 0, stream>>>(xb, wqb, nullptr, qb16, kb16, vb16);
  k_qks      <<<dim3(384, 7), 256, 0, stream>>>(qb16, kb16, attn_out);      // attn -> d_out scratch
  k_y1stats  <<<256, 256, 0, stream>>>(attn_out, w_exp, part);
  k_reduce   <<<72, 256, 0, stream>>>(part, 256, 72, dsum);
  k_bnaffine36<<<1, 64, 0, stream>>>(dsum, bn1_g, bn1_b, stats, 0);
  k_dla<0>   <<<6272, 256, 0, stream>>>(attn_out, w_exp, w_dw, nullptr, stats, nullptr, part);
  k_reduce   <<<72, 256, 0, stream>>>(part, 6272, 72, dsum);
  k_bnaffine36<<<1, 64, 0, stream>>>(dsum, bn2_g, bn2_b, stats, 72);
  k_dla<1>   <<<6272, 256, 0, stream>>>(attn_out, w_exp, w_dw, w_pro, stats, big, part);  // z -> big
  k_reduce   <<<24, 256, 0, stream>>>(part, 6272, 24, dsum);
  k_bnfinal  <<<1, 64, 0, stream>>>(dsum, bn3_g, bn3_b, abn_g, abn_b, stats);
  k_cast     <<<(768*768)/2048, 256, 0, stream>>>(w_proj, wpb);             // part now dead
  k_pv       <<<384, 256, 0, stream>>>(big, vb16, stats, attn_out, opb);    // attn_r + out_pre
  k_mfma_gemm<1><<<dim3(6, 49), 256, 0, stream>>>(opb, wpb, b_proj, out, nullptr, nullptr);
}

// Round 9
// 464.826 us; speedup vs baseline: 8.0801x; 1.1685x over previous
//
#include <hip/hip_runtime.h>
#include <hip/hip_bf16.h>
#include <math.h>

// ---------------- problem constants ----------------
constexpr int Bz  = 32;
constexpr int Nn  = 196;
constexpr int Cc  = 768;
constexpr int Hh  = 12;
constexpr int Dd  = 64;
constexpr int HID = 36;           // Hh * 3
constexpr int NN2 = Nn * Nn;      // 38416
constexpr int QSZ = Bz * Nn * Cc;          // 4,816,896
constexpr int ATT = Bz * Hh * NN2;         // 14,751,744
constexpr int SAMP = Bz * NN2;    // 1,229,312 samples per BN channel
constexpr float RS = 0.35355339059327373f; // 64^-0.25

typedef short bf16x8 __attribute__((ext_vector_type(8)));
typedef float f32x4  __attribute__((ext_vector_type(4)));

__device__ inline ushort f2b(float f) {
  __hip_bfloat16 h = __float2bfloat16(f);
  return *reinterpret_cast<ushort*>(&h);
}
__device__ inline float b2f(ushort u) {
  union { float f; unsigned i; } x; x.i = ((unsigned)u) << 16; return x.f;
}

// ---------------- f32 -> bf16 cast (8 elems/thread) ----------------
__global__ __launch_bounds__(256) void k_cast(const float* __restrict__ in,
                                              ushort* __restrict__ outp) {
  const int j = blockIdx.x*256 + threadIdx.x;       // 8-elem group
  float4 a = ((const float4*)in)[2*j];
  float4 b = ((const float4*)in)[2*j+1];
  ushort o[8] = { f2b(a.x), f2b(a.y), f2b(a.z), f2b(a.w),
                  f2b(b.x), f2b(b.y), f2b(b.z), f2b(b.w) };
  ((uint4*)outp)[j] = *(const uint4*)o;
}

// ---------------- bf16 MFMA GEMM: C = A[M,768] x B[N,768]^T ----------------
// EPI 0: qkv epilogue (RS scale q,k; bf16 scatter to [B,H,N,D]); EPI 1: +bias, f32 row-major
template<int EPI>
__global__ __launch_bounds__(256) void k_mfma_gemm(const ushort* __restrict__ A,
                                                   const ushort* __restrict__ B,
                                                   const float* __restrict__ bias,
                                                   void* __restrict__ o0,
                                                   void* __restrict__ o1,
                                                   void* __restrict__ o2) {
  __shared__ ushort As[128*72];   // 128 rows x 64 k, stride 72 (pad kills bank conflicts)
  __shared__ ushort Bs[128*72];
  const int t = threadIdx.x;
  const int m0 = blockIdx.y*128, n0 = blockIdx.x*128;
  const int w = t>>6, lane = t&63;
  const int wr = w>>1, wc = w&1;         // wave -> 64x64 quadrant
  const int lrow = lane&15, lkb = lane>>4;
  f32x4 acc[4][4] = {};
  const int srow = t>>1, skoff = (t&1)*32;
  const ushort* aP = A + (size_t)(m0+srow)*768 + skoff;
  const ushort* bP = B + (size_t)(n0+srow)*768 + skoff;
  ushort* aw = &As[srow*72 + skoff];
  ushort* bw = &Bs[srow*72 + skoff];
  for (int k0 = 0; k0 < 768; k0 += 64) {
    uint4 a0 = *(const uint4*)(aP+k0),    a1 = *(const uint4*)(aP+k0+8);
    uint4 a2 = *(const uint4*)(aP+k0+16), a3 = *(const uint4*)(aP+k0+24);
    uint4 b0 = *(const uint4*)(bP+k0),    b1 = *(const uint4*)(bP+k0+8);
    uint4 b2 = *(const uint4*)(bP+k0+16), b3 = *(const uint4*)(bP+k0+24);
    __syncthreads();
    *(uint4*)(aw)    = a0; *(uint4*)(aw+8)  = a1;
    *(uint4*)(aw+16) = a2; *(uint4*)(aw+24) = a3;
    *(uint4*)(bw)    = b0; *(uint4*)(bw+8)  = b1;
    *(uint4*)(bw+16) = b2; *(uint4*)(bw+24) = b3;
    __syncthreads();
#pragma unroll
    for (int kk = 0; kk < 2; kk++) {
      bf16x8 af[4], bfr[4];
#pragma unroll
      for (int m = 0; m < 4; m++)
        af[m] = *(const bf16x8*)&As[(wr*64+m*16+lrow)*72 + kk*32 + lkb*8];
#pragma unroll
      for (int n = 0; n < 4; n++)
        bfr[n] = *(const bf16x8*)&Bs[(wc*64+n*16+lrow)*72 + kk*32 + lkb*8];
#pragma unroll
      for (int m = 0; m < 4; m++)
#pragma unroll
        for (int n = 0; n < 4; n++)
          acc[m][n] = __builtin_amdgcn_mfma_f32_16x16x32_bf16(af[m], bfr[n], acc[m][n], 0, 0, 0);
    }
  }
  const int r4 = lane>>4;
#pragma unroll
  for (int m = 0; m < 4; m++) {
#pragma unroll
    for (int r = 0; r < 4; r++) {
      const int grow = m0 + wr*64 + m*16 + r4*4 + r;
      if (EPI == 0) {
        ushort* q = (ushort*)o0; ushort* k = (ushort*)o1; ushort* v = (ushort*)o2;
        const int b = grow/196, nn = grow - b*196;
#pragma unroll
        for (int n = 0; n < 4; n++) {
          const int gcol = n0 + wc*64 + n*16 + lrow;
          const int three = gcol/768, rem = gcol - three*768;
          const int h = rem>>6, dd = rem&63;
          float val = acc[m][n][r] * (three < 2 ? RS : 1.0f);
          ushort* base = (three == 0) ? q : (three == 1) ? k : v;
          base[((size_t)(b*12+h)*196 + nn)*64 + dd] = f2b(val);
        }
      } else {
        float* outp = (float*)o0;
#pragma unroll
        for (int n = 0; n < 4; n++) {
          const int gcol = n0 + wc*64 + n*16 + lrow;
          outp[(size_t)grow*768 + gcol] = acc[m][n][r] + bias[gcol];
        }
      }
    }
  }
}

// ---------------- fused QK^T (MFMA) + row softmax -> attn f32 ----------------
__global__ __launch_bounds__(256) void k_qks(const ushort* __restrict__ qb,
                                             const ushort* __restrict__ kb,
                                             float* __restrict__ attn) {
  __shared__ ushort K_lds[208*68];   // 28288 B
  __shared__ float  S_lds[32*210];   // 26880 B, stride 210 (~2-way banking)
  __shared__ float  sms[32];
  const int t = threadIdx.x;
  const int bh = blockIdx.x;
  const int r0 = blockIdx.y * 32;
  const ushort* kp = kb + (size_t)bh*Nn*Dd;
  const ushort* qp = qb + (size_t)bh*Nn*Dd;
  for (int i = t; i < 1568; i += 256) {
    int row = i >> 3, ko = (i & 7)*8;
    *(uint4*)&K_lds[row*68 + ko] = *(const uint4*)(kp + (size_t)row*64 + ko);
  }
  for (int i = t; i < 408; i += 256)
    ((unsigned*)&K_lds[196*68])[i] = 0u;
  const int w = t >> 6, lane = t & 63;
  const int mt = w >> 1;
  const int lrow = lane & 15, lk = lane >> 4;
  int qrow = r0 + mt*16 + lrow; if (qrow > 195) qrow = 195;
  bf16x8 aq0 = *(const bf16x8*)(qp + (size_t)qrow*64 + lk*8);
  bf16x8 aq1 = *(const bf16x8*)(qp + (size_t)qrow*64 + 32 + lk*8);
  __syncthreads();
  for (int nt = (w & 1); nt < 13; nt += 2) {
    f32x4 acc = {};
    bf16x8 b0 = *(const bf16x8*)&K_lds[(nt*16 + lrow)*68 + lk*8];
    acc = __builtin_amdgcn_mfma_f32_16x16x32_bf16(aq0, b0, acc, 0, 0, 0);
    bf16x8 b1 = *(const bf16x8*)&K_lds[(nt*16 + lrow)*68 + 32 + lk*8];
    acc = __builtin_amdgcn_mfma_f32_16x16x32_bf16(aq1, b1, acc, 0, 0, 0);
#pragma unroll
    for (int r = 0; r < 4; r++)
      S_lds[(mt*16 + lk*4 + r)*210 + nt*16 + lrow] = acc[r];
  }
  __syncthreads();
  const int sr = t >> 3, sj = t & 7;
  float mx = -1e30f;
  for (int c = sj; c < 196; c += 8) mx = fmaxf(mx, S_lds[sr*210 + c]);
  mx = fmaxf(mx, __shfl_xor(mx, 1, 64));
  mx = fmaxf(mx, __shfl_xor(mx, 2, 64));
  mx = fmaxf(mx, __shfl_xor(mx, 4, 64));
  float sum = 0.0f;
  for (int c = sj; c < 196; c += 8) {
    float e = __expf(S_lds[sr*210 + c] - mx);
    S_lds[sr*210 + c] = e;
    sum += e;
  }
  sum += __shfl_xor(sum, 1, 64);
  sum += __shfl_xor(sum, 2, 64);
  sum += __shfl_xor(sum, 4, 64);
  if (sj == 0) sms[sr] = 1.0f / sum;
  __syncthreads();
  const int nvalid = (r0 + 32 <= 196) ? 32 : (196 - r0);
  for (int idx = t; idx < nvalid*196; idx += 256) {
    int rr = idx / 196, cc = idx - rr*196;
    attn[((size_t)bh*196 + r0 + rr)*196 + cc] = S_lds[rr*210 + cc] * sms[rr];
  }
}

// ---------------- K3: Gram matrix M[h,h'] = sum attn_h * attn_h' (78 upper-tri entries) ----------------
__global__ __launch_bounds__(256) void k_gram(const float* __restrict__ attn,
                                              float* __restrict__ part) {
  __shared__ float red2[4*78];
  const int t = threadIdx.x;
  float m[78] = {};
  const int stride = gridDim.x * 256;
  for (int s = blockIdx.x*256 + t; s < SAMP; s += stride) {
    int b = s / NN2, p = s - b*NN2;
    float a[12];
#pragma unroll
    for (int h = 0; h < 12; h++) a[h] = attn[((size_t)(b*12+h))*NN2 + p];
    int idx = 0;
#pragma unroll
    for (int h = 0; h < 12; h++)
#pragma unroll
      for (int h2 = h; h2 < 12; h2++, idx++) m[idx] = fmaf(a[h], a[h2], m[idx]);
  }
#pragma unroll
  for (int i = 0; i < 78; i++) {
#pragma unroll
    for (int off = 32; off; off >>= 1) m[i] += __shfl_xor(m[i], off, 64);
  }
  const int w = t >> 6;
  if ((t & 63) == 0) {
#pragma unroll
    for (int i = 0; i < 78; i++) red2[w*78 + i] = m[i];
  }
  __syncthreads();
  if (t < 78)
    part[(size_t)blockIdx.x*78 + t] = red2[t] + red2[78+t] + red2[156+t] + red2[234+t];
}

// ---------------- hierarchical deterministic reduce ----------------
__global__ __launch_bounds__(256) void k_reduce(const float* __restrict__ part, int nb,
                                               int stride, double* __restrict__ dsum) {
  __shared__ double sh[256];
  const int c = blockIdx.x;
  const int t = threadIdx.x;
  double s = 0.0;
  for (int i = t; i < nb; i += 256) s += (double)part[(size_t)i*stride + c];
  sh[t] = s;
  __syncthreads();
  for (int o = 128; o; o >>= 1) {
    if (t < o) sh[t] += sh[t + o];
    __syncthreads();
  }
  if (t == 0) dsum[c] = sh[0];
}

// ---------------- bn1 affine from Gram (dsum[78]) ----------------
__global__ void k_bn1gram(const double* __restrict__ dsum,
                          const float* __restrict__ w_exp,
                          const float* __restrict__ g, const float* __restrict__ beta,
                          float* __restrict__ stats) {
  int c = threadIdx.x;
  if (c >= 36) return;
  float wv[12];
  float mean = 0.0f;
#pragma unroll
  for (int h = 0; h < 12; h++) { wv[h] = w_exp[c*12+h]; mean += wv[h]; }
  mean *= (1.0f/196.0f);            // softmax rows sum to 1 -> exact channel mean
  double e2 = 0.0;
  int idx = 0;
#pragma unroll
  for (int h = 0; h < 12; h++)
#pragma unroll
    for (int h2 = h; h2 < 12; h2++, idx++) {
      double coef = (double)wv[h] * (double)wv[h2] * (h == h2 ? 1.0 : 2.0);
      e2 += coef * dsum[idx];
    }
  double var = e2 / (double)SAMP - (double)mean*mean;
  float a = g[c] * rsqrtf((float)var + 1e-5f);
  stats[c] = a;
  stats[36 + c] = beta[c] - mean * a;
}

// ---- tiled DLA recompute (unchanged structure) ----
template<int MODE>
__global__ __launch_bounds__(256) void k_dla(const float* __restrict__ attn,
                                             const float* __restrict__ w_exp,
                                             const float* __restrict__ w_dw,
                                             const float* __restrict__ w_pro,
                                             const float* __restrict__ stats,
                                             float* __restrict__ zout,
                                             float* __restrict__ part) {
  __shared__ float y_s[12*256];
  __shared__ float z2[12*200];
  const int t = threadIdx.x;
  const int blk = blockIdx.x;
  const int b = blk / 196, tile = blk - b*196;
  const int tyq = tile / 14;
  const int ty0 = tyq * 14, tx0 = (tile - tyq*14) * 14;
  const int hy = ty0 + (t >> 4) - 1, hx = tx0 + (t & 15) - 1;
  const bool inb = (hy >= 0) && (hy < 196) && (hx >= 0) && (hx < 196);
  float a[12];
#pragma unroll
  for (int ch = 0; ch < 12; ch++)
    a[ch] = inb ? attn[((size_t)(b*12+ch))*NN2 + (size_t)hy*196 + hx] : 0.0f;

  const bool act = (t < 196);
  const int py = t / 14, px = t - py*14;
  const int base = (py+1)*16 + (px+1);
  float z[12] = {};
  const int rs = t >> 3;
  const int seg = t & 7;
  const int pix0 = seg*25;
  const int pcnt = (seg == 7) ? 21 : 25;

  for (int g = 0; g < 3; g++) {
    __syncthreads();
#pragma unroll
    for (int cl = 0; cl < 12; cl++) {
      const int c = g*12 + cl;
      float y = 0.0f;
#pragma unroll
      for (int h = 0; h < 12; h++) y = fmaf(w_exp[c*12+h], a[h], y);
      y = y*stats[c] + stats[36+c];
      y = fminf(fmaxf(y, 0.0f), 6.0f);
      y_s[cl*256 + t] = inb ? y : 0.0f;
    }
    __syncthreads();
    float y2v[12];
    if (act) {
#pragma unroll
      for (int cl = 0; cl < 12; cl++) {
        const int c = g*12 + cl;
        const float* ys = &y_s[cl*256];
        float y2 = 0.0f;
#pragma unroll
        for (int di = 0; di < 3; di++)
#pragma unroll
          for (int dj = 0; dj < 3; dj++)
            y2 = fmaf(w_dw[c*9 + di*3 + dj], ys[base + (di-1)*16 + (dj-1)], y2);
        y2v[cl] = y2;
        if (MODE == 1) {
          float y2c = y2*stats[72+c] + stats[108+c];
          y2c = fminf(fmaxf(y2c, 0.0f), 6.0f);
#pragma unroll
          for (int cc = 0; cc < 12; cc++) z[cc] = fmaf(w_pro[cc*36+c], y2c, z[cc]);
        }
      }
    }
    if (MODE == 0) {
      __syncthreads();
      if (act) {
#pragma unroll
        for (int cl = 0; cl < 12; cl++) z2[cl*200 + t] = y2v[cl];
      }
      __syncthreads();
      if (rs < 24) {
        const int cl = rs % 12, wh = rs / 12;
        float s = 0.0f;
        for (int i = 0; i < pcnt; i++) {
          float v = z2[cl*200 + pix0 + i];
          s += wh ? v*v : v;
        }
        s += __shfl_xor(s, 1, 64);
        s += __shfl_xor(s, 2, 64);
        s += __shfl_xor(s, 4, 64);
        if (seg == 0)
          part[(size_t)blk*72 + wh*36 + g*12 + cl] = s;
      }
    }
  }

  if (MODE == 1) {
    if (act) {
      const int oy = ty0 + py, ox = tx0 + px;
#pragma unroll
      for (int cc = 0; cc < 12; cc++) {
        zout[((size_t)(b*12+cc))*NN2 + (size_t)oy*196 + ox] = z[cc];
        z2[cc*200 + t] = z[cc];
      }
    }
    __syncthreads();
    if (rs < 24) {
      const int cl = rs % 12, wh = rs / 12;
      float s = 0.0f;
      for (int i = 0; i < pcnt; i++) {
        float v = z2[cl*200 + pix0 + i];
        s += wh ? v*v : v;
      }
      s += __shfl_xor(s, 1, 64);
      s += __shfl_xor(s, 2, 64);
      s += __shfl_xor(s, 4, 64);
      if (seg == 0)
        part[(size_t)blk*24 + wh*12 + cl] = s;
    }
  }
}

// ---------------- dsum -> BN affine (36 ch, bn2) ----------------
__global__ void k_bnaffine36(const double* __restrict__ dsum,
                             const float* __restrict__ g, const float* __restrict__ beta,
                             float* __restrict__ stats, int off) {
  int c = threadIdx.x;
  if (c >= 36) return;
  double m = dsum[c] / (double)SAMP;
  double v = dsum[36 + c] / (double)SAMP - m*m;
  float a = g[c] * rsqrtf((float)v + 1e-5f);
  stats[off + c] = a;
  stats[off + 36 + c] = beta[c] - (float)m * a;
}

// ---------------- combined bn3 + adapt_bn affine (from dsum[24]) ----------------
__global__ void k_bnfinal(const double* __restrict__ dsum,
                          const float* __restrict__ g3, const float* __restrict__ b3,
                          const float* __restrict__ ag, const float* __restrict__ ab,
                          float* __restrict__ stats) {
  int c = threadIdx.x;
  if (c >= 12) return;
  (void)b3; // bn3 beta cancels exactly in the composed affine
  double m = dsum[c] / (double)SAMP;
  double v = dsum[12 + c] / (double)SAMP - m*m;
  float r1 = rsqrtf((float)v + 1e-5f);
  float vt = g3[c]*g3[c]*(float)v*r1*r1;
  float r2 = rsqrtf(vt + 1e-5f);
  float A = g3[c]*ag[c]*r1*r2;
  stats[144 + c] = A;
  stats[156 + c] = ab[c] - (float)m*A;
}

// ---------------- PV: attn_r = z*Af+Bf (write), O = attn_r @ V -> out_pre bf16 ----------------
__global__ __launch_bounds__(256) void k_pv(const float* __restrict__ z,
                                            const ushort* __restrict__ v16,
                                            const float* __restrict__ stats,
                                            float* __restrict__ attn_r,
                                            ushort* __restrict__ out_pre) {
  __shared__ float Vs[196*65];
  __shared__ float ar_s[16*200];
  const int t = threadIdx.x;
  const int bh = blockIdx.x;
  const int b = bh / 12, h = bh - b*12;
  const float Af = stats[144 + h], Bf = stats[156 + h];
  const ushort* vp = v16 + (size_t)bh * Nn * Dd;
#pragma unroll
  for (int i = 0; i < 49; i++) {
    int idx = t + i*256;
    Vs[(idx >> 6)*65 + (idx & 63)] = b2f(vp[idx]);
  }
  const float* zp = z + (size_t)bh * NN2;
  float* arp = attn_r + (size_t)bh * NN2;
  const int dd = t & 63, wy = t >> 6;
  for (int ch = 0; ch < 13; ch++) {
    const int r0 = ch*16;
    const int nrows = (r0 + 16 <= 196) ? 16 : (196 - r0);
    __syncthreads();
    for (int idx = t; idx < nrows*196; idx += 256) {
      int rr = idx / 196, m = idx - rr*196;
      float val = fmaf(zp[(size_t)(r0+rr)*196 + m], Af, Bf);
      arp[(size_t)(r0+rr)*196 + m] = val;
      ar_s[rr*200 + m] = val;
    }
    __syncthreads();
    float acc[4] = {0,0,0,0};
#pragma unroll 2
    for (int m = 0; m < 196; m++) {
      float vv = Vs[m*65 + dd];
#pragma unroll
      for (int r = 0; r < 4; r++) acc[r] = fmaf(ar_s[(wy*4+r)*200 + m], vv, acc[r]);
    }
#pragma unroll
    for (int r = 0; r < 4; r++) {
      int rr = wy*4 + r;
      if (rr < nrows)
        out_pre[((size_t)(b*196 + r0 + rr))*Cc + h*64 + dd] = f2b(acc[r]);
    }
  }
}

// ---------------- launch ----------------
extern "C" void kernel_launch(void* const* d_in, const int* in_sizes, int n_in,
                              void* d_out, int out_size, void* d_ws, size_t ws_size,
                              hipStream_t stream) {
  (void)in_sizes; (void)n_in; (void)out_size; (void)ws_size;
  const float* x      = (const float*)d_in[0];
  const float* w_qkv  = (const float*)d_in[1];
  const float* w_exp  = (const float*)d_in[2];
  const float* bn1_g  = (const float*)d_in[3];
  const float* bn1_b  = (const float*)d_in[4];
  const float* w_dw   = (const float*)d_in[5];
  const float* bn2_g  = (const float*)d_in[6];
  const float* bn2_b  = (const float*)d_in[7];
  const float* w_pro  = (const float*)d_in[8];
  const float* bn3_g  = (const float*)d_in[9];
  const float* bn3_b  = (const float*)d_in[10];
  const float* abn_g  = (const float*)d_in[11];
  const float* abn_b  = (const float*)d_in[12];
  const float* w_proj = (const float*)d_in[13];
  const float* b_proj = (const float*)d_in[14];

  float* out      = (float*)d_out;
  float* attn_out = out + (size_t)QSZ;      // d_out attn_r region: attn -> attn_r
  float* ws    = (float*)d_ws;
  ushort* vb16 = (ushort*)ws;
  ushort* opb  = (ushort*)ws + (size_t)QSZ;
  float*  big  = ws + (size_t)QSZ;
  ushort* qb16 = (ushort*)big;
  ushort* kb16 = qb16 + (size_t)QSZ;
  float* stats = ws + (size_t)QSZ + ATT;
  float* part  = stats + 256;
  double* dsum = (double*)(part + (size_t)6272*72);

  // bf16 staging in dead d_out region:
  ushort* xb   = (ushort*)out;              // x bf16 (out[0..QSZ) untouched until proj)
  ushort* wqb  = xb + (size_t)QSZ;          // w_qkv bf16
  ushort* wpb  = (ushort*)part;             // w_proj bf16 (part dead after last reduce)

  k_cast <<<QSZ/2048, 256, 0, stream>>>(x, xb);
  k_cast <<<(2304*768)/2048, 256, 0, stream>>>(w_qkv, wqb);
  k_mfma_gemm<0><<<dim3(18, 49), 256, 0, stream>>>(xb, wqb, nullptr, qb16, kb16, vb16);
  k_qks      <<<dim3(384, 7), 256, 0, stream>>>(qb16, kb16, attn_out);      // attn -> d_out scratch
  k_gram     <<<512, 256, 0, stream>>>(attn_out, part);
  k_reduce   <<<78, 256, 0, stream>>>(part, 512, 78, dsum);
  k_bn1gram  <<<1, 64, 0, stream>>>(dsum, w_exp, bn1_g, bn1_b, stats);
  k_dla<0>   <<<6272, 256, 0, stream>>>(attn_out, w_exp, w_dw, nullptr, stats, nullptr, part);
  k_reduce   <<<72, 256, 0, stream>>>(part, 6272, 72, dsum);
  k_bnaffine36<<<1, 64, 0, stream>>>(dsum, bn2_g, bn2_b, stats, 72);
  k_dla<1>   <<<6272, 256, 0, stream>>>(attn_out, w_exp, w_dw, w_pro, stats, big, part);  // z -> big
  k_reduce   <<<24, 256, 0, stream>>>(part, 6272, 24, dsum);
  k_bnfinal  <<<1, 64, 0, stream>>>(dsum, bn3_g, bn3_b, abn_g, abn_b, stats);
  k_cast     <<<(768*768)/2048, 256, 0, stream>>>(w_proj, wpb);             // part now dead
  k_pv       <<<384, 256, 0, stream>>>(big, vb16, stats, attn_out, opb);    // attn_r + out_pre
  k_mfma_gemm<1><<<dim3(6, 49), 256, 0, stream>>>(opb, wpb, b_proj, out, nullptr, nullptr);
}

// Round 10
// 423.890 us; speedup vs baseline: 8.8604x; 1.0966x over previous
//
#include <hip/hip_runtime.h>
#include <hip/hip_bf16.h>
#include <math.h>

// ---------------- problem constants ----------------
constexpr int Bz  = 32;
constexpr int Nn  = 196;
constexpr int Cc  = 768;
constexpr int Hh  = 12;
constexpr int Dd  = 64;
constexpr int HID = 36;           // Hh * 3
constexpr int NN2 = Nn * Nn;      // 38416
constexpr int QSZ = Bz * Nn * Cc;          // 4,816,896
constexpr int ATT = Bz * Hh * NN2;         // 14,751,744
constexpr int SAMP = Bz * NN2;    // 1,229,312 samples per BN channel
constexpr float RS = 0.35355339059327373f; // 64^-0.25

typedef short bf16x8 __attribute__((ext_vector_type(8)));
typedef float f32x4  __attribute__((ext_vector_type(4)));

__device__ inline ushort f2b(float f) {
  __hip_bfloat16 h = __float2bfloat16(f);
  return *reinterpret_cast<ushort*>(&h);
}
__device__ inline float b2f(ushort u) {
  union { float f; unsigned i; } x; x.i = ((unsigned)u) << 16; return x.f;
}

// ---------------- f32 -> bf16 cast (8 elems/thread) ----------------
__global__ __launch_bounds__(256) void k_cast(const float* __restrict__ in,
                                              ushort* __restrict__ outp) {
  const int j = blockIdx.x*256 + threadIdx.x;       // 8-elem group
  float4 a = ((const float4*)in)[2*j];
  float4 b = ((const float4*)in)[2*j+1];
  ushort o[8] = { f2b(a.x), f2b(a.y), f2b(a.z), f2b(a.w),
                  f2b(b.x), f2b(b.y), f2b(b.z), f2b(b.w) };
  ((uint4*)outp)[j] = *(const uint4*)o;
}

// ---------------- bf16 MFMA GEMM: C = A[M,768] x B[N,768]^T ----------------
// EPI 0: qkv epilogue (RS scale q,k; bf16 scatter to [B,H,N,D]); EPI 1: +bias, f32 row-major
template<int EPI>
__global__ __launch_bounds__(256) void k_mfma_gemm(const ushort* __restrict__ A,
                                                   const ushort* __restrict__ B,
                                                   const float* __restrict__ bias,
                                                   void* __restrict__ o0,
                                                   void* __restrict__ o1,
                                                   void* __restrict__ o2) {
  __shared__ ushort As[128*72];   // 128 rows x 64 k, stride 72 (pad kills bank conflicts)
  __shared__ ushort Bs[128*72];
  const int t = threadIdx.x;
  const int m0 = blockIdx.y*128, n0 = blockIdx.x*128;
  const int w = t>>6, lane = t&63;
  const int wr = w>>1, wc = w&1;         // wave -> 64x64 quadrant
  const int lrow = lane&15, lkb = lane>>4;
  f32x4 acc[4][4] = {};
  const int srow = t>>1, skoff = (t&1)*32;
  const ushort* aP = A + (size_t)(m0+srow)*768 + skoff;
  const ushort* bP = B + (size_t)(n0+srow)*768 + skoff;
  ushort* aw = &As[srow*72 + skoff];
  ushort* bw = &Bs[srow*72 + skoff];
  for (int k0 = 0; k0 < 768; k0 += 64) {
    uint4 a0 = *(const uint4*)(aP+k0),    a1 = *(const uint4*)(aP+k0+8);
    uint4 a2 = *(const uint4*)(aP+k0+16), a3 = *(const uint4*)(aP+k0+24);
    uint4 b0 = *(const uint4*)(bP+k0),    b1 = *(const uint4*)(bP+k0+8);
    uint4 b2 = *(const uint4*)(bP+k0+16), b3 = *(const uint4*)(bP+k0+24);
    __syncthreads();
    *(uint4*)(aw)    = a0; *(uint4*)(aw+8)  = a1;
    *(uint4*)(aw+16) = a2; *(uint4*)(aw+24) = a3;
    *(uint4*)(bw)    = b0; *(uint4*)(bw+8)  = b1;
    *(uint4*)(bw+16) = b2; *(uint4*)(bw+24) = b3;
    __syncthreads();
#pragma unroll
    for (int kk = 0; kk < 2; kk++) {
      bf16x8 af[4], bfr[4];
#pragma unroll
      for (int m = 0; m < 4; m++)
        af[m] = *(const bf16x8*)&As[(wr*64+m*16+lrow)*72 + kk*32 + lkb*8];
#pragma unroll
      for (int n = 0; n < 4; n++)
        bfr[n] = *(const bf16x8*)&Bs[(wc*64+n*16+lrow)*72 + kk*32 + lkb*8];
#pragma unroll
      for (int m = 0; m < 4; m++)
#pragma unroll
        for (int n = 0; n < 4; n++)
          acc[m][n] = __builtin_amdgcn_mfma_f32_16x16x32_bf16(af[m], bfr[n], acc[m][n], 0, 0, 0);
    }
  }
  const int r4 = lane>>4;
#pragma unroll
  for (int m = 0; m < 4; m++) {
#pragma unroll
    for (int r = 0; r < 4; r++) {
      const int grow = m0 + wr*64 + m*16 + r4*4 + r;
      if (EPI == 0) {
        ushort* q = (ushort*)o0; ushort* k = (ushort*)o1; ushort* v = (ushort*)o2;
        const int b = grow/196, nn = grow - b*196;
#pragma unroll
        for (int n = 0; n < 4; n++) {
          const int gcol = n0 + wc*64 + n*16 + lrow;
          const int three = gcol/768, rem = gcol - three*768;
          const int h = rem>>6, dd = rem&63;
          float val = acc[m][n][r] * (three < 2 ? RS : 1.0f);
          ushort* base = (three == 0) ? q : (three == 1) ? k : v;
          base[((size_t)(b*12+h)*196 + nn)*64 + dd] = f2b(val);
        }
      } else {
        float* outp = (float*)o0;
#pragma unroll
        for (int n = 0; n < 4; n++) {
          const int gcol = n0 + wc*64 + n*16 + lrow;
          outp[(size_t)grow*768 + gcol] = acc[m][n][r] + bias[gcol];
        }
      }
    }
  }
}

// ---------------- fused QK^T (MFMA) + row softmax -> attn f32 ----------------
__global__ __launch_bounds__(256) void k_qks(const ushort* __restrict__ qb,
                                             const ushort* __restrict__ kb,
                                             float* __restrict__ attn) {
  __shared__ ushort K_lds[208*68];   // 28288 B
  __shared__ float  S_lds[32*210];   // 26880 B, stride 210 (~2-way banking)
  __shared__ float  sms[32];
  const int t = threadIdx.x;
  const int bh = blockIdx.x;
  const int r0 = blockIdx.y * 32;
  const ushort* kp = kb + (size_t)bh*Nn*Dd;
  const ushort* qp = qb + (size_t)bh*Nn*Dd;
  for (int i = t; i < 1568; i += 256) {
    int row = i >> 3, ko = (i & 7)*8;
    *(uint4*)&K_lds[row*68 + ko] = *(const uint4*)(kp + (size_t)row*64 + ko);
  }
  for (int i = t; i < 408; i += 256)
    ((unsigned*)&K_lds[196*68])[i] = 0u;
  const int w = t >> 6, lane = t & 63;
  const int mt = w >> 1;
  const int lrow = lane & 15, lk = lane >> 4;
  int qrow = r0 + mt*16 + lrow; if (qrow > 195) qrow = 195;
  bf16x8 aq0 = *(const bf16x8*)(qp + (size_t)qrow*64 + lk*8);
  bf16x8 aq1 = *(const bf16x8*)(qp + (size_t)qrow*64 + 32 + lk*8);
  __syncthreads();
  for (int nt = (w & 1); nt < 13; nt += 2) {
    f32x4 acc = {};
    bf16x8 b0 = *(const bf16x8*)&K_lds[(nt*16 + lrow)*68 + lk*8];
    acc = __builtin_amdgcn_mfma_f32_16x16x32_bf16(aq0, b0, acc, 0, 0, 0);
    bf16x8 b1 = *(const bf16x8*)&K_lds[(nt*16 + lrow)*68 + 32 + lk*8];
    acc = __builtin_amdgcn_mfma_f32_16x16x32_bf16(aq1, b1, acc, 0, 0, 0);
#pragma unroll
    for (int r = 0; r < 4; r++)
      S_lds[(mt*16 + lk*4 + r)*210 + nt*16 + lrow] = acc[r];
  }
  __syncthreads();
  const int sr = t >> 3, sj = t & 7;
  float mx = -1e30f;
  for (int c = sj; c < 196; c += 8) mx = fmaxf(mx, S_lds[sr*210 + c]);
  mx = fmaxf(mx, __shfl_xor(mx, 1, 64));
  mx = fmaxf(mx, __shfl_xor(mx, 2, 64));
  mx = fmaxf(mx, __shfl_xor(mx, 4, 64));
  float sum = 0.0f;
  for (int c = sj; c < 196; c += 8) {
    float e = __expf(S_lds[sr*210 + c] - mx);
    S_lds[sr*210 + c] = e;
    sum += e;
  }
  sum += __shfl_xor(sum, 1, 64);
  sum += __shfl_xor(sum, 2, 64);
  sum += __shfl_xor(sum, 4, 64);
  if (sj == 0) sms[sr] = 1.0f / sum;
  __syncthreads();
  const int nvalid = (r0 + 32 <= 196) ? 32 : (196 - r0);
  for (int idx = t; idx < nvalid*196; idx += 256) {
    int rr = idx / 196, cc = idx - rr*196;
    attn[((size_t)bh*196 + r0 + rr)*196 + cc] = S_lds[rr*210 + cc] * sms[rr];
  }
}

// ---------------- K3: Gram matrix M[h,h'] = sum attn_h * attn_h' (78 upper-tri entries) ----------------
__global__ __launch_bounds__(256) void k_gram(const float* __restrict__ attn,
                                              float* __restrict__ part) {
  __shared__ float red2[4*78];
  const int t = threadIdx.x;
  float m[78] = {};
  const int stride = gridDim.x * 256;
  for (int s = blockIdx.x*256 + t; s < SAMP; s += stride) {
    int b = s / NN2, p = s - b*NN2;
    float a[12];
#pragma unroll
    for (int h = 0; h < 12; h++) a[h] = attn[((size_t)(b*12+h))*NN2 + p];
    int idx = 0;
#pragma unroll
    for (int h = 0; h < 12; h++)
#pragma unroll
      for (int h2 = h; h2 < 12; h2++, idx++) m[idx] = fmaf(a[h], a[h2], m[idx]);
  }
#pragma unroll
  for (int i = 0; i < 78; i++) {
#pragma unroll
    for (int off = 32; off; off >>= 1) m[i] += __shfl_xor(m[i], off, 64);
  }
  const int w = t >> 6;
  if ((t & 63) == 0) {
#pragma unroll
    for (int i = 0; i < 78; i++) red2[w*78 + i] = m[i];
  }
  __syncthreads();
  if (t < 78)
    part[(size_t)blockIdx.x*78 + t] = red2[t] + red2[78+t] + red2[156+t] + red2[234+t];
}

// ---------------- hierarchical deterministic reduce ----------------
__global__ __launch_bounds__(256) void k_reduce(const float* __restrict__ part, int nb,
                                               int stride, double* __restrict__ dsum) {
  __shared__ double sh[256];
  const int c = blockIdx.x;
  const int t = threadIdx.x;
  double s = 0.0;
  for (int i = t; i < nb; i += 256) s += (double)part[(size_t)i*stride + c];
  sh[t] = s;
  __syncthreads();
  for (int o = 128; o; o >>= 1) {
    if (t < o) sh[t] += sh[t + o];
    __syncthreads();
  }
  if (t == 0) dsum[c] = sh[0];
}

// ---------------- bn1 affine from Gram (dsum[78]) ----------------
__global__ void k_bn1gram(const double* __restrict__ dsum,
                          const float* __restrict__ w_exp,
                          const float* __restrict__ g, const float* __restrict__ beta,
                          float* __restrict__ stats) {
  int c = threadIdx.x;
  if (c >= 36) return;
  float wv[12];
  float mean = 0.0f;
#pragma unroll
  for (int h = 0; h < 12; h++) { wv[h] = w_exp[c*12+h]; mean += wv[h]; }
  mean *= (1.0f/196.0f);            // softmax rows sum to 1 -> exact channel mean
  double e2 = 0.0;
  int idx = 0;
#pragma unroll
  for (int h = 0; h < 12; h++)
#pragma unroll
    for (int h2 = h; h2 < 12; h2++, idx++) {
      double coef = (double)wv[h] * (double)wv[h2] * (h == h2 ? 1.0 : 2.0);
      e2 += coef * dsum[idx];
    }
  double var = e2 / (double)SAMP - (double)mean*mean;
  float a = g[c] * rsqrtf((float)var + 1e-5f);
  stats[c] = a;
  stats[36 + c] = beta[c] - mean * a;
}

// ---- tiled DLA recompute (unchanged structure) ----
template<int MODE>
__global__ __launch_bounds__(256) void k_dla(const float* __restrict__ attn,
                                             const float* __restrict__ w_exp,
                                             const float* __restrict__ w_dw,
                                             const float* __restrict__ w_pro,
                                             const float* __restrict__ stats,
                                             float* __restrict__ zout,
                                             float* __restrict__ part) {
  __shared__ float y_s[12*256];
  __shared__ float z2[12*200];
  const int t = threadIdx.x;
  const int blk = blockIdx.x;
  const int b = blk / 196, tile = blk - b*196;
  const int tyq = tile / 14;
  const int ty0 = tyq * 14, tx0 = (tile - tyq*14) * 14;
  const int hy = ty0 + (t >> 4) - 1, hx = tx0 + (t & 15) - 1;
  const bool inb = (hy >= 0) && (hy < 196) && (hx >= 0) && (hx < 196);
  float a[12];
#pragma unroll
  for (int ch = 0; ch < 12; ch++)
    a[ch] = inb ? attn[((size_t)(b*12+ch))*NN2 + (size_t)hy*196 + hx] : 0.0f;

  const bool act = (t < 196);
  const int py = t / 14, px = t - py*14;
  const int base = (py+1)*16 + (px+1);
  float z[12] = {};
  const int rs = t >> 3;
  const int seg = t & 7;
  const int pix0 = seg*25;
  const int pcnt = (seg == 7) ? 21 : 25;

  for (int g = 0; g < 3; g++) {
    __syncthreads();
#pragma unroll
    for (int cl = 0; cl < 12; cl++) {
      const int c = g*12 + cl;
      float y = 0.0f;
#pragma unroll
      for (int h = 0; h < 12; h++) y = fmaf(w_exp[c*12+h], a[h], y);
      y = y*stats[c] + stats[36+c];
      y = fminf(fmaxf(y, 0.0f), 6.0f);
      y_s[cl*256 + t] = inb ? y : 0.0f;
    }
    __syncthreads();
    float y2v[12];
    if (act) {
#pragma unroll
      for (int cl = 0; cl < 12; cl++) {
        const int c = g*12 + cl;
        const float* ys = &y_s[cl*256];
        float y2 = 0.0f;
#pragma unroll
        for (int di = 0; di < 3; di++)
#pragma unroll
          for (int dj = 0; dj < 3; dj++)
            y2 = fmaf(w_dw[c*9 + di*3 + dj], ys[base + (di-1)*16 + (dj-1)], y2);
        y2v[cl] = y2;
        if (MODE == 1) {
          float y2c = y2*stats[72+c] + stats[108+c];
          y2c = fminf(fmaxf(y2c, 0.0f), 6.0f);
#pragma unroll
          for (int cc = 0; cc < 12; cc++) z[cc] = fmaf(w_pro[cc*36+c], y2c, z[cc]);
        }
      }
    }
    if (MODE == 0) {
      __syncthreads();
      if (act) {
#pragma unroll
        for (int cl = 0; cl < 12; cl++) z2[cl*200 + t] = y2v[cl];
      }
      __syncthreads();
      if (rs < 24) {
        const int cl = rs % 12, wh = rs / 12;
        float s = 0.0f;
        for (int i = 0; i < pcnt; i++) {
          float v = z2[cl*200 + pix0 + i];
          s += wh ? v*v : v;
        }
        s += __shfl_xor(s, 1, 64);
        s += __shfl_xor(s, 2, 64);
        s += __shfl_xor(s, 4, 64);
        if (seg == 0)
          part[(size_t)blk*72 + wh*36 + g*12 + cl] = s;
      }
    }
  }

  if (MODE == 1) {
    if (act) {
      const int oy = ty0 + py, ox = tx0 + px;
#pragma unroll
      for (int cc = 0; cc < 12; cc++) {
        zout[((size_t)(b*12+cc))*NN2 + (size_t)oy*196 + ox] = z[cc];
        z2[cc*200 + t] = z[cc];
      }
    }
    __syncthreads();
    if (rs < 24) {
      const int cl = rs % 12, wh = rs / 12;
      float s = 0.0f;
      for (int i = 0; i < pcnt; i++) {
        float v = z2[cl*200 + pix0 + i];
        s += wh ? v*v : v;
      }
      s += __shfl_xor(s, 1, 64);
      s += __shfl_xor(s, 2, 64);
      s += __shfl_xor(s, 4, 64);
      if (seg == 0)
        part[(size_t)blk*24 + wh*12 + cl] = s;
    }
  }
}

// ---------------- dsum -> BN affine (36 ch, bn2) ----------------
__global__ void k_bnaffine36(const double* __restrict__ dsum,
                             const float* __restrict__ g, const float* __restrict__ beta,
                             float* __restrict__ stats, int off) {
  int c = threadIdx.x;
  if (c >= 36) return;
  double m = dsum[c] / (double)SAMP;
  double v = dsum[36 + c] / (double)SAMP - m*m;
  float a = g[c] * rsqrtf((float)v + 1e-5f);
  stats[off + c] = a;
  stats[off + 36 + c] = beta[c] - (float)m * a;
}

// ---------------- combined bn3 + adapt_bn affine (from dsum[24]) ----------------
__global__ void k_bnfinal(const double* __restrict__ dsum,
                          const float* __restrict__ g3, const float* __restrict__ b3,
                          const float* __restrict__ ag, const float* __restrict__ ab,
                          float* __restrict__ stats) {
  int c = threadIdx.x;
  if (c >= 12) return;
  (void)b3; // bn3 beta cancels exactly in the composed affine
  double m = dsum[c] / (double)SAMP;
  double v = dsum[12 + c] / (double)SAMP - m*m;
  float r1 = rsqrtf((float)v + 1e-5f);
  float vt = g3[c]*g3[c]*(float)v*r1*r1;
  float r2 = rsqrtf(vt + 1e-5f);
  float A = g3[c]*ag[c]*r1*r2;
  stats[144 + c] = A;
  stats[156 + c] = ab[c] - (float)m*A;
}

// ---------------- MFMA PV: attn_r = z*Af+Bf (f32 write), O = P(bf16) @ V(bf16) -> out_pre bf16 ----------------
// grid (384, 7): bh, 32-row tile. Vt = V^T in LDS (conflict-free 2-step transpose).
__global__ __launch_bounds__(256) void k_pvm(const float* __restrict__ z,
                                             const ushort* __restrict__ v16,
                                             const float* __restrict__ stats,
                                             float* __restrict__ attn_r,
                                             ushort* __restrict__ out_pre) {
  constexpr int STR = 232;               // bf16 row stride (row step = 116 dwords == 20 mod 32)
  __shared__ ushort Vt[64*STR];          // 29696 B  V^T [d][m], m padded to 224
  __shared__ ushort U[32*STR];           // 14848 B  union: Vlin half (104*64) -> P tile
  const int t = threadIdx.x;
  const int bh = blockIdx.x;
  const int r0 = blockIdx.y * 32;
  const int b = bh / 12, h = bh - b*12;
  const float Af = stats[144 + h], Bf = stats[156 + h];
  const ushort* vp = v16 + (size_t)bh * Nn * Dd;

  // ---- two-step transpose: V[m][d] -> Vt[d][m], in halves of <=104 rows ----
#pragma unroll
  for (int half = 0; half < 2; half++) {
    const int mbase = half * 104;
    const int nm = half ? 92 : 104;
    for (int i = t; i < nm*8; i += 256) {              // coalesced V -> U (row-major)
      int lm = i >> 3, d0 = (i & 7)*8;
      *(uint4*)&U[lm*64 + d0] = *(const uint4*)(vp + (size_t)(mbase+lm)*64 + d0);
    }
    __syncthreads();
    const int ngrp = (nm + 7) >> 3;
    for (int i = t; i < 64*ngrp; i += 256) {           // strided read / contiguous write
      int d = i & 63, mg = i >> 6;
      int lm0 = mg*8;
      ushort tmp[8];
      int cnt = nm - lm0; if (cnt > 8) cnt = 8;
      for (int j = 0; j < cnt; j++) tmp[j] = U[(lm0+j)*64 + d];
      for (int j = cnt; j < 8; j++) tmp[j] = 0;
      *(uint4*)&Vt[d*STR + mbase + lm0] = *(uint4*)tmp;
    }
    __syncthreads();
  }
  // zero pad Vt m in [196, 232)
  for (int i = t; i < 64*36; i += 256) {
    int d = i / 36, m = 196 + i % 36;
    Vt[d*STR + m] = 0;
  }
  // ---- zero P, then stage P = bf16(z*Af+Bf), writing attn_r f32 exactly ----
  for (int i = t; i < 32*STR/8; i += 256)
    ((uint4*)U)[i] = make_uint4(0,0,0,0);
  __syncthreads();
  const int nvalid = (r0 + 32 <= 196) ? 32 : (196 - r0);
  const float* zp = z + (size_t)bh*NN2 + (size_t)r0*196;
  float* arp = attn_r + (size_t)bh*NN2 + (size_t)r0*196;
  for (int idx = t; idx < nvalid*196; idx += 256) {
    int rr = idx / 196, m = idx - rr*196;
    float val = fmaf(zp[(size_t)rr*196 + m], Af, Bf);
    arp[(size_t)rr*196 + m] = val;
    U[rr*STR + m] = f2b(val);
  }
  __syncthreads();
  // ---- MFMA: out[32][64] = P[32][224] x Vt^T ----
  const int w = t >> 6, lane = t & 63;
  const int mt = w >> 1, ct = w & 1;
  const int lr = lane & 15, lk = lane >> 4;
#pragma unroll
  for (int cn = 0; cn < 2; cn++) {
    const int n0 = ct*32 + cn*16;
    f32x4 acc = {};
#pragma unroll
    for (int ks = 0; ks < 7; ks++) {
      bf16x8 af = *(const bf16x8*)&U[(mt*16 + lr)*STR + ks*32 + lk*8];
      bf16x8 bf = *(const bf16x8*)&Vt[(n0 + lr)*STR + ks*32 + lk*8];
      acc = __builtin_amdgcn_mfma_f32_16x16x32_bf16(af, bf, acc, 0, 0, 0);
    }
#pragma unroll
    for (int r = 0; r < 4; r++) {
      int row = mt*16 + lk*4 + r;
      if (row < nvalid)
        out_pre[((size_t)(b*196 + r0 + row))*Cc + h*64 + n0 + lr] = f2b(acc[r]);
    }
  }
}

// ---------------- launch ----------------
extern "C" void kernel_launch(void* const* d_in, const int* in_sizes, int n_in,
                              void* d_out, int out_size, void* d_ws, size_t ws_size,
                              hipStream_t stream) {
  (void)in_sizes; (void)n_in; (void)out_size; (void)ws_size;
  const float* x      = (const float*)d_in[0];
  const float* w_qkv  = (const float*)d_in[1];
  const float* w_exp  = (const float*)d_in[2];
  const float* bn1_g  = (const float*)d_in[3];
  const float* bn1_b  = (const float*)d_in[4];
  const float* w_dw   = (const float*)d_in[5];
  const float* bn2_g  = (const float*)d_in[6];
  const float* bn2_b  = (const float*)d_in[7];
  const float* w_pro  = (const float*)d_in[8];
  const float* bn3_g  = (const float*)d_in[9];
  const float* bn3_b  = (const float*)d_in[10];
  const float* abn_g  = (const float*)d_in[11];
  const float* abn_b  = (const float*)d_in[12];
  const float* w_proj = (const float*)d_in[13];
  const float* b_proj = (const float*)d_in[14];

  float* out      = (float*)d_out;
  float* attn_out = out + (size_t)QSZ;      // d_out attn_r region: attn -> attn_r
  float* ws    = (float*)d_ws;
  ushort* vb16 = (ushort*)ws;
  ushort* opb  = (ushort*)ws + (size_t)QSZ;
  float*  big  = ws + (size_t)QSZ;
  ushort* qb16 = (ushort*)big;
  ushort* kb16 = qb16 + (size_t)QSZ;
  float* stats = ws + (size_t)QSZ + ATT;
  float* part  = stats + 256;
  double* dsum = (double*)(part + (size_t)6272*72);

  // bf16 staging in dead d_out region:
  ushort* xb   = (ushort*)out;              // x bf16 (out[0..QSZ) untouched until proj)
  ushort* wqb  = xb + (size_t)QSZ;          // w_qkv bf16
  ushort* wpb  = (ushort*)part;             // w_proj bf16 (part dead after last reduce)

  k_cast <<<QSZ/2048, 256, 0, stream>>>(x, xb);
  k_cast <<<(2304*768)/2048, 256, 0, stream>>>(w_qkv, wqb);
  k_mfma_gemm<0><<<dim3(18, 49), 256, 0, stream>>>(xb, wqb, nullptr, qb16, kb16, vb16);
  k_qks      <<<dim3(384, 7), 256, 0, stream>>>(qb16, kb16, attn_out);      // attn -> d_out scratch
  k_gram     <<<2048, 256, 0, stream>>>(attn_out, part);
  k_reduce   <<<78, 256, 0, stream>>>(part, 2048, 78, dsum);
  k_bn1gram  <<<1, 64, 0, stream>>>(dsum, w_exp, bn1_g, bn1_b, stats);
  k_dla<0>   <<<6272, 256, 0, stream>>>(attn_out, w_exp, w_dw, nullptr, stats, nullptr, part);
  k_reduce   <<<72, 256, 0, stream>>>(part, 6272, 72, dsum);
  k_bnaffine36<<<1, 64, 0, stream>>>(dsum, bn2_g, bn2_b, stats, 72);
  k_dla<1>   <<<6272, 256, 0, stream>>>(attn_out, w_exp, w_dw, w_pro, stats, big, part);  // z -> big
  k_reduce   <<<24, 256, 0, stream>>>(part, 6272, 24, dsum);
  k_bnfinal  <<<1, 64, 0, stream>>>(dsum, bn3_g, bn3_b, abn_g, abn_b, stats);
  k_cast     <<<(768*768)/2048, 256, 0, stream>>>(w_proj, wpb);             // part now dead
  k_pvm      <<<dim3(384, 7), 256, 0, stream>>>(big, vb16, stats, attn_out, opb);
  k_mfma_gemm<1><<<dim3(6, 49), 256, 0, stream>>>(opb, wpb, b_proj, out, nullptr, nullptr);
}

// Round 11
// 391.725 us; speedup vs baseline: 9.5879x; 1.0821x over previous
//
#include <hip/hip_runtime.h>
#include <hip/hip_bf16.h>
#include <hip/hip_fp16.h>
#include <math.h>

// ---------------- problem constants ----------------
constexpr int Bz  = 32;
constexpr int Nn  = 196;
constexpr int Cc  = 768;
constexpr int Hh  = 12;
constexpr int Dd  = 64;
constexpr int NN2 = Nn * Nn;      // 38416
constexpr int QSZ = Bz * Nn * Cc;          // 4,816,896
constexpr int ATT = Bz * Hh * NN2;         // 14,751,744
constexpr int SAMP = Bz * NN2;    // 1,229,312 samples per BN channel
constexpr float RS = 0.35355339059327373f; // 64^-0.25
// y2 cache geometry: 36*196 = 7056 fp16 per block; blocks 0..6075 cached (batches 0..30)
constexpr int CHUNK = 7056;
constexpr int NCACHE = 6076;      // 31 batches * 196 tiles
constexpr int RA_CAP = 4181;      // blocks in big region
constexpr int RB_CAP = 1365;      // blocks in d_out[0..QSZ) region

typedef short bf16x8 __attribute__((ext_vector_type(8)));
typedef float f32x4  __attribute__((ext_vector_type(4)));

__device__ inline ushort f2b(float f) {
  __hip_bfloat16 h = __float2bfloat16(f);
  return *reinterpret_cast<ushort*>(&h);
}
__device__ inline float b2f(ushort u) {
  union { float f; unsigned i; } x; x.i = ((unsigned)u) << 16; return x.f;
}
__device__ inline ushort f2h_(float f) {
  __half h = __float2half(f);
  return *reinterpret_cast<ushort*>(&h);
}
__device__ inline float h2f_(ushort u) {
  __half h = *reinterpret_cast<__half*>(&u);
  return __half2float(h);
}
__device__ inline const ushort* y2chunk_r(int blk, const ushort* rA, const ushort* rB,
                                          const ushort* rC) {
  if (blk < RA_CAP) return rA + (size_t)blk*CHUNK;
  if (blk < RA_CAP + RB_CAP) return rB + (size_t)(blk - RA_CAP)*CHUNK;
  return rC + (size_t)(blk - RA_CAP - RB_CAP)*CHUNK;
}
__device__ inline ushort* y2chunk_w(int blk, ushort* rA, ushort* rB, ushort* rC) {
  if (blk < RA_CAP) return rA + (size_t)blk*CHUNK;
  if (blk < RA_CAP + RB_CAP) return rB + (size_t)(blk - RA_CAP)*CHUNK;
  return rC + (size_t)(blk - RA_CAP - RB_CAP)*CHUNK;
}

// ---------------- f32 -> bf16 cast (8 elems/thread) ----------------
__global__ __launch_bounds__(256) void k_cast(const float* __restrict__ in,
                                              ushort* __restrict__ outp) {
  const int j = blockIdx.x*256 + threadIdx.x;       // 8-elem group
  float4 a = ((const float4*)in)[2*j];
  float4 b = ((const float4*)in)[2*j+1];
  ushort o[8] = { f2b(a.x), f2b(a.y), f2b(a.z), f2b(a.w),
                  f2b(b.x), f2b(b.y), f2b(b.z), f2b(b.w) };
  ((uint4*)outp)[j] = *(const uint4*)o;
}

// ---------------- bf16 MFMA GEMM: C = A[M,768] x B[N,768]^T ----------------
// EPI 0: qkv epilogue (RS scale q,k; bf16 scatter to [B,H,N,D]); EPI 1: +bias, f32 row-major
template<int EPI>
__global__ __launch_bounds__(256) void k_mfma_gemm(const ushort* __restrict__ A,
                                                   const ushort* __restrict__ B,
                                                   const float* __restrict__ bias,
                                                   void* __restrict__ o0,
                                                   void* __restrict__ o1,
                                                   void* __restrict__ o2) {
  __shared__ ushort As[128*72];
  __shared__ ushort Bs[128*72];
  const int t = threadIdx.x;
  const int m0 = blockIdx.y*128, n0 = blockIdx.x*128;
  const int w = t>>6, lane = t&63;
  const int wr = w>>1, wc = w&1;
  const int lrow = lane&15, lkb = lane>>4;
  f32x4 acc[4][4] = {};
  const int srow = t>>1, skoff = (t&1)*32;
  const ushort* aP = A + (size_t)(m0+srow)*768 + skoff;
  const ushort* bP = B + (size_t)(n0+srow)*768 + skoff;
  ushort* aw = &As[srow*72 + skoff];
  ushort* bw = &Bs[srow*72 + skoff];
  for (int k0 = 0; k0 < 768; k0 += 64) {
    uint4 a0 = *(const uint4*)(aP+k0),    a1 = *(const uint4*)(aP+k0+8);
    uint4 a2 = *(const uint4*)(aP+k0+16), a3 = *(const uint4*)(aP+k0+24);
    uint4 b0 = *(const uint4*)(bP+k0),    b1 = *(const uint4*)(bP+k0+8);
    uint4 b2 = *(const uint4*)(bP+k0+16), b3 = *(const uint4*)(bP+k0+24);
    __syncthreads();
    *(uint4*)(aw)    = a0; *(uint4*)(aw+8)  = a1;
    *(uint4*)(aw+16) = a2; *(uint4*)(aw+24) = a3;
    *(uint4*)(bw)    = b0; *(uint4*)(bw+8)  = b1;
    *(uint4*)(bw+16) = b2; *(uint4*)(bw+24) = b3;
    __syncthreads();
#pragma unroll
    for (int kk = 0; kk < 2; kk++) {
      bf16x8 af[4], bfr[4];
#pragma unroll
      for (int m = 0; m < 4; m++)
        af[m] = *(const bf16x8*)&As[(wr*64+m*16+lrow)*72 + kk*32 + lkb*8];
#pragma unroll
      for (int n = 0; n < 4; n++)
        bfr[n] = *(const bf16x8*)&Bs[(wc*64+n*16+lrow)*72 + kk*32 + lkb*8];
#pragma unroll
      for (int m = 0; m < 4; m++)
#pragma unroll
        for (int n = 0; n < 4; n++)
          acc[m][n] = __builtin_amdgcn_mfma_f32_16x16x32_bf16(af[m], bfr[n], acc[m][n], 0, 0, 0);
    }
  }
  const int r4 = lane>>4;
#pragma unroll
  for (int m = 0; m < 4; m++) {
#pragma unroll
    for (int r = 0; r < 4; r++) {
      const int grow = m0 + wr*64 + m*16 + r4*4 + r;
      if (EPI == 0) {
        ushort* q = (ushort*)o0; ushort* k = (ushort*)o1; ushort* v = (ushort*)o2;
        const int b = grow/196, nn = grow - b*196;
#pragma unroll
        for (int n = 0; n < 4; n++) {
          const int gcol = n0 + wc*64 + n*16 + lrow;
          const int three = gcol/768, rem = gcol - three*768;
          const int h = rem>>6, dd = rem&63;
          float val = acc[m][n][r] * (three < 2 ? RS : 1.0f);
          ushort* base = (three == 0) ? q : (three == 1) ? k : v;
          base[((size_t)(b*12+h)*196 + nn)*64 + dd] = f2b(val);
        }
      } else {
        float* outp = (float*)o0;
#pragma unroll
        for (int n = 0; n < 4; n++) {
          const int gcol = n0 + wc*64 + n*16 + lrow;
          outp[(size_t)grow*768 + gcol] = acc[m][n][r] + bias[gcol];
        }
      }
    }
  }
}

// ---------------- fused QK^T (MFMA) + register softmax -> attn f32 ----------------
// grid (384, 4): bh, 4 m-tile slots/block (slot = by*4 + wave, active if < 13).
__global__ __launch_bounds__(256) void k_qks(const ushort* __restrict__ qb,
                                             const ushort* __restrict__ kb,
                                             float* __restrict__ attn) {
  __shared__ ushort K_lds[208*68];   // 28288 B
  const int t = threadIdx.x;
  const int bh = blockIdx.x;
  const ushort* kp = kb + (size_t)bh*Nn*Dd;
  const ushort* qp = qb + (size_t)bh*Nn*Dd;
  for (int i = t; i < 1568; i += 256) {
    int row = i >> 3, ko = (i & 7)*8;
    *(uint4*)&K_lds[row*68 + ko] = *(const uint4*)(kp + (size_t)row*64 + ko);
  }
  for (int i = t; i < 408; i += 256)
    ((unsigned*)&K_lds[196*68])[i] = 0u;
  __syncthreads();
  const int w = t >> 6, lane = t & 63;
  const int slot = blockIdx.y*4 + w;       // m-tile 0..15 (13..15 idle)
  if (slot >= 13) return;
  const int lrow = lane & 15, lk = lane >> 4;
  int qrow = slot*16 + lrow; if (qrow > 195) qrow = 195;
  bf16x8 aq0 = *(const bf16x8*)(qp + (size_t)qrow*64 + lk*8);
  bf16x8 aq1 = *(const bf16x8*)(qp + (size_t)qrow*64 + 32 + lk*8);
  f32x4 acc[13];
#pragma unroll
  for (int nt = 0; nt < 13; nt++) {
    f32x4 a = {};
    bf16x8 b0 = *(const bf16x8*)&K_lds[(nt*16 + lrow)*68 + lk*8];
    a = __builtin_amdgcn_mfma_f32_16x16x32_bf16(aq0, b0, a, 0, 0, 0);
    bf16x8 b1 = *(const bf16x8*)&K_lds[(nt*16 + lrow)*68 + 32 + lk*8];
    acc[nt] = __builtin_amdgcn_mfma_f32_16x16x32_bf16(aq1, b1, a, 0, 0, 0);
  }
  // per-row softmax: row_local = lk*4 + r; cols at (nt*16 + lrow) across 16 lrow-lanes
  const bool tailok = (lrow < 4);          // nt==12 valid cols: 192..195
  float inv[4];
#pragma unroll
  for (int r = 0; r < 4; r++) {
    float mx = -1e30f;
#pragma unroll
    for (int nt = 0; nt < 12; nt++) mx = fmaxf(mx, acc[nt][r]);
    if (tailok) mx = fmaxf(mx, acc[12][r]);
    mx = fmaxf(mx, __shfl_xor(mx, 1, 64));
    mx = fmaxf(mx, __shfl_xor(mx, 2, 64));
    mx = fmaxf(mx, __shfl_xor(mx, 4, 64));
    mx = fmaxf(mx, __shfl_xor(mx, 8, 64));
    float s = 0.0f;
#pragma unroll
    for (int nt = 0; nt < 13; nt++) {
      bool valid = (nt < 12) || tailok;
      float e = valid ? __expf(acc[nt][r] - mx) : 0.0f;
      acc[nt][r] = e;
      s += e;
    }
    s += __shfl_xor(s, 1, 64);
    s += __shfl_xor(s, 2, 64);
    s += __shfl_xor(s, 4, 64);
    s += __shfl_xor(s, 8, 64);
    inv[r] = 1.0f / s;
  }
  const int rowb = slot*16 + lk*4;
#pragma unroll
  for (int r = 0; r < 4; r++) {
    const int row = rowb + r;
    if (row < 196) {
      float* op = attn + ((size_t)bh*196 + row)*196;
#pragma unroll
      for (int nt = 0; nt < 13; nt++) {
        int col = nt*16 + lrow;
        if (col < 196) op[col] = acc[nt][r]*inv[r];
      }
    }
  }
}

// ---------------- Gram matrix M[h,h'] = sum attn_h * attn_h' (78 upper-tri) ----------------
__global__ __launch_bounds__(256) void k_gram(const float* __restrict__ attn,
                                              float* __restrict__ part) {
  __shared__ float red2[4*78];
  const int t = threadIdx.x;
  float m[78] = {};
  const int stride = gridDim.x * 256;
  for (int s = blockIdx.x*256 + t; s < SAMP; s += stride) {
    int b = s / NN2, p = s - b*NN2;
    float a[12];
#pragma unroll
    for (int h = 0; h < 12; h++) a[h] = attn[((size_t)(b*12+h))*NN2 + p];
    int idx = 0;
#pragma unroll
    for (int h = 0; h < 12; h++)
#pragma unroll
      for (int h2 = h; h2 < 12; h2++, idx++) m[idx] = fmaf(a[h], a[h2], m[idx]);
  }
#pragma unroll
  for (int i = 0; i < 78; i++) {
#pragma unroll
    for (int off = 32; off; off >>= 1) m[i] += __shfl_xor(m[i], off, 64);
  }
  const int w = t >> 6;
  if ((t & 63) == 0) {
#pragma unroll
    for (int i = 0; i < 78; i++) red2[w*78 + i] = m[i];
  }
  __syncthreads();
  if (t < 78)
    part[(size_t)blockIdx.x*78 + t] = red2[t] + red2[78+t] + red2[156+t] + red2[234+t];
}

// ---------------- hierarchical deterministic reduce ----------------
__global__ __launch_bounds__(256) void k_reduce(const float* __restrict__ part, int nb,
                                               int stride, double* __restrict__ dsum) {
  __shared__ double sh[256];
  const int c = blockIdx.x;
  const int t = threadIdx.x;
  double s = 0.0;
  for (int i = t; i < nb; i += 256) s += (double)part[(size_t)i*stride + c];
  sh[t] = s;
  __syncthreads();
  for (int o = 128; o; o >>= 1) {
    if (t < o) sh[t] += sh[t + o];
    __syncthreads();
  }
  if (t == 0) dsum[c] = sh[0];
}

// ---------------- bn1 affine from Gram (dsum[78]) ----------------
__global__ void k_bn1gram(const double* __restrict__ dsum,
                          const float* __restrict__ w_exp,
                          const float* __restrict__ g, const float* __restrict__ beta,
                          float* __restrict__ stats) {
  int c = threadIdx.x;
  if (c >= 36) return;
  float wv[12];
  float mean = 0.0f;
#pragma unroll
  for (int h = 0; h < 12; h++) { wv[h] = w_exp[c*12+h]; mean += wv[h]; }
  mean *= (1.0f/196.0f);
  double e2 = 0.0;
  int idx = 0;
#pragma unroll
  for (int h = 0; h < 12; h++)
#pragma unroll
    for (int h2 = h; h2 < 12; h2++, idx++) {
      double coef = (double)wv[h] * (double)wv[h2] * (h == h2 ? 1.0 : 2.0);
      e2 += coef * dsum[idx];
    }
  double var = e2 / (double)SAMP - (double)mean*mean;
  float a = g[c] * rsqrtf((float)var + 1e-5f);
  stats[c] = a;
  stats[36 + c] = beta[c] - mean * a;
}

// ---- pass A: expand+dw; y2 stats -> part[blk][72]; y2 fp16 cached for blk < NCACHE ----
__global__ __launch_bounds__(256) void k_dlaA(const float* __restrict__ attn,
                                              const float* __restrict__ w_exp,
                                              const float* __restrict__ w_dw,
                                              const float* __restrict__ stats,
                                              ushort* __restrict__ rA,
                                              ushort* __restrict__ rB,
                                              ushort* __restrict__ rC,
                                              float* __restrict__ part) {
  __shared__ float y_s[12*256];
  __shared__ float z2[12*200];
  const int t = threadIdx.x;
  const int blk = blockIdx.x;
  const int b = blk / 196, tile = blk - b*196;
  const int tyq = tile / 14;
  const int ty0 = tyq * 14, tx0 = (tile - tyq*14) * 14;
  const int hy = ty0 + (t >> 4) - 1, hx = tx0 + (t & 15) - 1;
  const bool inb = (hy >= 0) && (hy < 196) && (hx >= 0) && (hx < 196);
  float a[12];
#pragma unroll
  for (int ch = 0; ch < 12; ch++)
    a[ch] = inb ? attn[((size_t)(b*12+ch))*NN2 + (size_t)hy*196 + hx] : 0.0f;

  const bool act = (t < 196);
  const int py = t / 14, px = t - py*14;
  const int base = (py+1)*16 + (px+1);
  const int rs = t >> 3;
  const int seg = t & 7;
  const int pix0 = seg*25;
  const int pcnt = (seg == 7) ? 21 : 25;
  ushort* ydst = (blk < NCACHE) ? y2chunk_w(blk, rA, rB, rC) : nullptr;

  for (int g = 0; g < 3; g++) {
    __syncthreads();
#pragma unroll
    for (int cl = 0; cl < 12; cl++) {
      const int c = g*12 + cl;
      float y = 0.0f;
#pragma unroll
      for (int h = 0; h < 12; h++) y = fmaf(w_exp[c*12+h], a[h], y);
      y = y*stats[c] + stats[36+c];
      y = fminf(fmaxf(y, 0.0f), 6.0f);
      y_s[cl*256 + t] = inb ? y : 0.0f;
    }
    __syncthreads();
    float y2v[12];
    if (act) {
#pragma unroll
      for (int cl = 0; cl < 12; cl++) {
        const int c = g*12 + cl;
        const float* ys = &y_s[cl*256];
        float y2 = 0.0f;
#pragma unroll
        for (int di = 0; di < 3; di++)
#pragma unroll
          for (int dj = 0; dj < 3; dj++)
            y2 = fmaf(w_dw[c*9 + di*3 + dj], ys[base + (di-1)*16 + (dj-1)], y2);
        y2v[cl] = y2;
      }
      if (ydst) {
#pragma unroll
        for (int cl = 0; cl < 12; cl++)
          ydst[(g*12 + cl)*196 + t] = f2h_(y2v[cl]);
      }
    }
    // y2 stats via LDS staging
    __syncthreads();
    if (act) {
#pragma unroll
      for (int cl = 0; cl < 12; cl++) z2[cl*200 + t] = y2v[cl];
    }
    __syncthreads();
    if (rs < 24) {
      const int cl = rs % 12, wh = rs / 12;
      float s = 0.0f;
      for (int i = 0; i < pcnt; i++) {
        float v = z2[cl*200 + pix0 + i];
        s += wh ? v*v : v;
      }
      s += __shfl_xor(s, 1, 64);
      s += __shfl_xor(s, 2, 64);
      s += __shfl_xor(s, 4, 64);
      if (seg == 0)
        part[(size_t)blk*72 + wh*36 + g*12 + cl] = s;
    }
  }
}

// ---- pass B: z from cached y2 (blk<NCACHE) or full recompute (batch 31); z stats ----
// z for b<31 written over attn planes (zatt); batch-31 z -> z31 aux.
__global__ __launch_bounds__(256) void k_dlaB(const float* __restrict__ attn,
                                              const ushort* __restrict__ rA,
                                              const ushort* __restrict__ rB,
                                              const ushort* __restrict__ rC,
                                              const float* __restrict__ w_exp,
                                              const float* __restrict__ w_dw,
                                              const float* __restrict__ w_pro,
                                              const float* __restrict__ stats,
                                              float* __restrict__ zatt,
                                              float* __restrict__ z31,
                                              float* __restrict__ part) {
  __shared__ float y_s[12*256];
  __shared__ float z2[12*200];
  const int t = threadIdx.x;
  const int blk = blockIdx.x;
  const int b = blk / 196, tile = blk - b*196;
  const int tyq = tile / 14;
  const int ty0 = tyq * 14, tx0 = (tile - tyq*14) * 14;
  const bool act = (t < 196);
  const int py = t / 14, px = t - py*14;
  const int oy = ty0 + py, ox = tx0 + px;
  float z[12] = {};

  if (blk < NCACHE) {
    // light path: read cached y2 fp16, bn2 affine + clip, project
    if (act) {
      const ushort* src = y2chunk_r(blk, rA, rB, rC);
#pragma unroll
      for (int c = 0; c < 36; c++) {
        float y2 = h2f_(src[c*196 + t]);
        float y2c = y2*stats[72+c] + stats[108+c];
        y2c = fminf(fmaxf(y2c, 0.0f), 6.0f);
#pragma unroll
        for (int cc = 0; cc < 12; cc++) z[cc] = fmaf(w_pro[cc*36+c], y2c, z[cc]);
      }
#pragma unroll
      for (int cc = 0; cc < 12; cc++)
        zatt[((size_t)(b*12+cc))*NN2 + (size_t)oy*196 + ox] = z[cc];
    }
  } else {
    // heavy path: batch 31 full recompute (attn[31] still intact)
    const int hy = ty0 + (t >> 4) - 1, hx = tx0 + (t & 15) - 1;
    const bool inb = (hy >= 0) && (hy < 196) && (hx >= 0) && (hx < 196);
    float a[12];
#pragma unroll
    for (int ch = 0; ch < 12; ch++)
      a[ch] = inb ? attn[((size_t)(b*12+ch))*NN2 + (size_t)hy*196 + hx] : 0.0f;
    const int base = (py+1)*16 + (px+1);
    for (int g = 0; g < 3; g++) {
      __syncthreads();
#pragma unroll
      for (int cl = 0; cl < 12; cl++) {
        const int c = g*12 + cl;
        float y = 0.0f;
#pragma unroll
        for (int h = 0; h < 12; h++) y = fmaf(w_exp[c*12+h], a[h], y);
        y = y*stats[c] + stats[36+c];
        y = fminf(fmaxf(y, 0.0f), 6.0f);
        y_s[cl*256 + t] = inb ? y : 0.0f;
      }
      __syncthreads();
      if (act) {
#pragma unroll
        for (int cl = 0; cl < 12; cl++) {
          const int c = g*12 + cl;
          const float* ys = &y_s[cl*256];
          float y2 = 0.0f;
#pragma unroll
          for (int di = 0; di < 3; di++)
#pragma unroll
            for (int dj = 0; dj < 3; dj++)
              y2 = fmaf(w_dw[c*9 + di*3 + dj], ys[base + (di-1)*16 + (dj-1)], y2);
          float y2c = y2*stats[72+c] + stats[108+c];
          y2c = fminf(fmaxf(y2c, 0.0f), 6.0f);
#pragma unroll
          for (int cc = 0; cc < 12; cc++) z[cc] = fmaf(w_pro[cc*36+c], y2c, z[cc]);
        }
      }
    }
    if (act) {
#pragma unroll
      for (int cc = 0; cc < 12; cc++)
        z31[(size_t)cc*NN2 + (size_t)oy*196 + ox] = z[cc];
    }
  }
  // z stats (both paths)
  __syncthreads();
  if (act) {
#pragma unroll
    for (int cc = 0; cc < 12; cc++) z2[cc*200 + t] = z[cc];
  }
  __syncthreads();
  const int rs = t >> 3, seg = t & 7;
  const int pix0 = seg*25;
  const int pcnt = (seg == 7) ? 21 : 25;
  if (rs < 24) {
    const int cl = rs % 12, wh = rs / 12;
    float s = 0.0f;
    for (int i = 0; i < pcnt; i++) {
      float v = z2[cl*200 + pix0 + i];
      s += wh ? v*v : v;
    }
    s += __shfl_xor(s, 1, 64);
    s += __shfl_xor(s, 2, 64);
    s += __shfl_xor(s, 4, 64);
    if (seg == 0)
      part[(size_t)blk*24 + wh*12 + cl] = s;
  }
}

// ---------------- dsum -> BN affine (36 ch, bn2) ----------------
__global__ void k_bnaffine36(const double* __restrict__ dsum,
                             const float* __restrict__ g, const float* __restrict__ beta,
                             float* __restrict__ stats, int off) {
  int c = threadIdx.x;
  if (c >= 36) return;
  double m = dsum[c] / (double)SAMP;
  double v = dsum[36 + c] / (double)SAMP - m*m;
  float a = g[c] * rsqrtf((float)v + 1e-5f);
  stats[off + c] = a;
  stats[off + 36 + c] = beta[c] - (float)m * a;
}

// ---------------- combined bn3 + adapt_bn affine (from dsum[24]) ----------------
__global__ void k_bnfinal(const double* __restrict__ dsum,
                          const float* __restrict__ g3, const float* __restrict__ b3,
                          const float* __restrict__ ag, const float* __restrict__ ab,
                          float* __restrict__ stats) {
  int c = threadIdx.x;
  if (c >= 12) return;
  (void)b3;
  double m = dsum[c] / (double)SAMP;
  double v = dsum[12 + c] / (double)SAMP - m*m;
  float r1 = rsqrtf((float)v + 1e-5f);
  float vt = g3[c]*g3[c]*(float)v*r1*r1;
  float r2 = rsqrtf(vt + 1e-5f);
  float A = g3[c]*ag[c]*r1*r2;
  stats[144 + c] = A;
  stats[156 + c] = ab[c] - (float)m*A;
}

// ---------------- MFMA PV: attn_r = z*Af+Bf (f32, in-place for b<31), O = P@V -> out_pre bf16 ----------------
__global__ __launch_bounds__(256) void k_pvm(const float* __restrict__ z31,
                                             const ushort* __restrict__ v16,
                                             const float* __restrict__ stats,
                                             float* __restrict__ attn_r,
                                             ushort* __restrict__ out_pre) {
  constexpr int STR = 232;
  __shared__ ushort Vt[64*STR];
  __shared__ ushort U[32*STR];
  const int t = threadIdx.x;
  const int bh = blockIdx.x;
  const int r0 = blockIdx.y * 32;
  const int b = bh / 12, h = bh - b*12;
  const float Af = stats[144 + h], Bf = stats[156 + h];
  const ushort* vp = v16 + (size_t)bh * Nn * Dd;

#pragma unroll
  for (int half = 0; half < 2; half++) {
    const int mbase = half * 104;
    const int nm = half ? 92 : 104;
    for (int i = t; i < nm*8; i += 256) {
      int lm = i >> 3, d0 = (i & 7)*8;
      *(uint4*)&U[lm*64 + d0] = *(const uint4*)(vp + (size_t)(mbase+lm)*64 + d0);
    }
    __syncthreads();
    const int ngrp = (nm + 7) >> 3;
    for (int i = t; i < 64*ngrp; i += 256) {
      int d = i & 63, mg = i >> 6;
      int lm0 = mg*8;
      ushort tmp[8];
      int cnt = nm - lm0; if (cnt > 8) cnt = 8;
      for (int j = 0; j < cnt; j++) tmp[j] = U[(lm0+j)*64 + d];
      for (int j = cnt; j < 8; j++) tmp[j] = 0;
      *(uint4*)&Vt[d*STR + mbase + lm0] = *(uint4*)tmp;
    }
    __syncthreads();
  }
  for (int i = t; i < 64*36; i += 256) {
    int d = i / 36, m = 196 + i % 36;
    Vt[d*STR + m] = 0;
  }
  for (int i = t; i < 32*STR/8; i += 256)
    ((uint4*)U)[i] = make_uint4(0,0,0,0);
  __syncthreads();
  const int nvalid = (r0 + 32 <= 196) ? 32 : (196 - r0);
  float* arp = attn_r + (size_t)bh*NN2 + (size_t)r0*196;
  const float* zp = (b < 31) ? arp : (z31 + (size_t)h*NN2 + (size_t)r0*196);
  for (int idx = t; idx < nvalid*196; idx += 256) {
    int rr = idx / 196, m = idx - rr*196;
    float val = fmaf(zp[(size_t)rr*196 + m], Af, Bf);
    arp[(size_t)rr*196 + m] = val;
    U[rr*STR + m] = f2b(val);
  }
  __syncthreads();
  const int w = t >> 6, lane = t & 63;
  const int mt = w >> 1, ct = w & 1;
  const int lr = lane & 15, lk = lane >> 4;
#pragma unroll
  for (int cn = 0; cn < 2; cn++) {
    const int n0 = ct*32 + cn*16;
    f32x4 acc = {};
#pragma unroll
    for (int ks = 0; ks < 7; ks++) {
      bf16x8 af = *(const bf16x8*)&U[(mt*16 + lr)*STR + ks*32 + lk*8];
      bf16x8 bf = *(const bf16x8*)&Vt[(n0 + lr)*STR + ks*32 + lk*8];
      acc = __builtin_amdgcn_mfma_f32_16x16x32_bf16(af, bf, acc, 0, 0, 0);
    }
#pragma unroll
    for (int r = 0; r < 4; r++) {
      int row = mt*16 + lk*4 + r;
      if (row < nvalid)
        out_pre[((size_t)(b*196 + r0 + row))*Cc + h*64 + n0 + lr] = f2b(acc[r]);
    }
  }
}

// ---------------- launch ----------------
extern "C" void kernel_launch(void* const* d_in, const int* in_sizes, int n_in,
                              void* d_out, int out_size, void* d_ws, size_t ws_size,
                              hipStream_t stream) {
  (void)in_sizes; (void)n_in; (void)out_size; (void)ws_size;
  const float* x      = (const float*)d_in[0];
  const float* w_qkv  = (const float*)d_in[1];
  const float* w_exp  = (const float*)d_in[2];
  const float* bn1_g  = (const float*)d_in[3];
  const float* bn1_b  = (const float*)d_in[4];
  const float* w_dw   = (const float*)d_in[5];
  const float* bn2_g  = (const float*)d_in[6];
  const float* bn2_b  = (const float*)d_in[7];
  const float* w_pro  = (const float*)d_in[8];
  const float* bn3_g  = (const float*)d_in[9];
  const float* bn3_b  = (const float*)d_in[10];
  const float* abn_g  = (const float*)d_in[11];
  const float* abn_b  = (const float*)d_in[12];
  const float* w_proj = (const float*)d_in[13];
  const float* b_proj = (const float*)d_in[14];

  float* out      = (float*)d_out;
  float* attn_out = out + (size_t)QSZ;      // d_out attn region: attn -> z(b<31) -> attn_r
  float* ws    = (float*)d_ws;
  ushort* vb16 = (ushort*)ws;               // [QSZ ushorts]
  ushort* opb  = (ushort*)ws + (size_t)QSZ; // [QSZ ushorts]: y2 cache rC -> out_pre
  float*  big  = ws + (size_t)QSZ;          // [ATT]: {q,k bf16} -> y2 cache rA
  ushort* qb16 = (ushort*)big;
  ushort* kb16 = qb16 + (size_t)QSZ;
  float* stats = ws + (size_t)QSZ + ATT;    // [256]
  float* part  = stats + 256;               // [6272*72]
  double* dsum = (double*)(part + (size_t)6272*72); // [96]
  float* z31   = (float*)(dsum + 96);       // [12*NN2] batch-31 z aux

  // staging in dead d_out region:
  ushort* xb   = (ushort*)out;              // x bf16
  ushort* wqb  = xb + (size_t)QSZ;          // w_qkv bf16
  ushort* rB   = (ushort*)out;              // y2 cache region B (after gemm<0> consumed xb/wqb)
  ushort* wpb  = (ushort*)part;             // w_proj bf16 (part dead after last reduce)

  k_cast <<<QSZ/2048, 256, 0, stream>>>(x, xb);
  k_cast <<<(2304*768)/2048, 256, 0, stream>>>(w_qkv, wqb);
  k_mfma_gemm<0><<<dim3(18, 49), 256, 0, stream>>>(xb, wqb, nullptr, qb16, kb16, vb16);
  k_qks      <<<dim3(384, 4), 256, 0, stream>>>(qb16, kb16, attn_out);
  k_gram     <<<2048, 256, 0, stream>>>(attn_out, part);
  k_reduce   <<<78, 256, 0, stream>>>(part, 2048, 78, dsum);
  k_bn1gram  <<<1, 64, 0, stream>>>(dsum, w_exp, bn1_g, bn1_b, stats);
  k_dlaA     <<<6272, 256, 0, stream>>>(attn_out, w_exp, w_dw, stats,
                                        (ushort*)big, rB, opb, part);
  k_reduce   <<<72, 256, 0, stream>>>(part, 6272, 72, dsum);
  k_bnaffine36<<<1, 64, 0, stream>>>(dsum, bn2_g, bn2_b, stats, 72);
  k_dlaB     <<<6272, 256, 0, stream>>>(attn_out, (const ushort*)big, rB, opb,
                                        w_exp, w_dw, w_pro, stats, attn_out, z31, part);
  k_reduce   <<<24, 256, 0, stream>>>(part, 6272, 24, dsum);
  k_bnfinal  <<<1, 64, 0, stream>>>(dsum, bn3_g, bn3_b, abn_g, abn_b, stats);
  k_cast     <<<(768*768)/2048, 256, 0, stream>>>(w_proj, wpb);
  k_pvm      <<<dim3(384, 7), 256, 0, stream>>>(z31, vb16, stats, attn_out, opb);
  k_mfma_gemm<1><<<dim3(6, 49), 256, 0, stream>>>(opb, wpb, b_proj, out, nullptr, nullptr);
}

// Round 12
// 366.909 us; speedup vs baseline: 10.2364x; 1.0676x over previous
//
#include <hip/hip_runtime.h>
#include <hip/hip_bf16.h>
#include <hip/hip_fp16.h>
#include <math.h>

// ---------------- problem constants ----------------
constexpr int Bz  = 32;
constexpr int Nn  = 196;
constexpr int Cc  = 768;
constexpr int Hh  = 12;
constexpr int Dd  = 64;
constexpr int NN2 = Nn * Nn;      // 38416
constexpr int QSZ = Bz * Nn * Cc;          // 4,816,896
constexpr int ATT = Bz * Hh * NN2;         // 14,751,744
constexpr int SAMP = Bz * NN2;    // 1,229,312 samples per BN channel
constexpr float RS = 0.35355339059327373f; // 64^-0.25
// y2 cache geometry: 36*196 = 7056 fp16 per block; blocks 0..6075 cached (batches 0..30)
constexpr int CHUNK = 7056;
constexpr int NCACHE = 6076;      // 31 batches * 196 tiles
constexpr int RA_CAP = 4181;      // blocks in big region
constexpr int RB_CAP = 1365;      // blocks in d_out[0..QSZ) region

typedef short bf16x8 __attribute__((ext_vector_type(8)));
typedef float f32x4  __attribute__((ext_vector_type(4)));

__device__ inline ushort f2b(float f) {
  __hip_bfloat16 h = __float2bfloat16(f);
  return *reinterpret_cast<ushort*>(&h);
}
__device__ inline float b2f(ushort u) {
  union { float f; unsigned i; } x; x.i = ((unsigned)u) << 16; return x.f;
}
__device__ inline ushort f2h_(float f) {
  __half h = __float2half(f);
  return *reinterpret_cast<ushort*>(&h);
}
__device__ inline float h2f_(ushort u) {
  __half h = *reinterpret_cast<__half*>(&u);
  return __half2float(h);
}
__device__ inline const ushort* y2chunk_r(int blk, const ushort* rA, const ushort* rB,
                                          const ushort* rC) {
  if (blk < RA_CAP) return rA + (size_t)blk*CHUNK;
  if (blk < RA_CAP + RB_CAP) return rB + (size_t)(blk - RA_CAP)*CHUNK;
  return rC + (size_t)(blk - RA_CAP - RB_CAP)*CHUNK;
}
__device__ inline ushort* y2chunk_w(int blk, ushort* rA, ushort* rB, ushort* rC) {
  if (blk < RA_CAP) return rA + (size_t)blk*CHUNK;
  if (blk < RA_CAP + RB_CAP) return rB + (size_t)(blk - RA_CAP)*CHUNK;
  return rC + (size_t)(blk - RA_CAP - RB_CAP)*CHUNK;
}

// ---------------- f32 -> bf16 cast (8 elems/thread) ----------------
__global__ __launch_bounds__(256) void k_cast(const float* __restrict__ in,
                                              ushort* __restrict__ outp) {
  const int j = blockIdx.x*256 + threadIdx.x;       // 8-elem group
  float4 a = ((const float4*)in)[2*j];
  float4 b = ((const float4*)in)[2*j+1];
  ushort o[8] = { f2b(a.x), f2b(a.y), f2b(a.z), f2b(a.w),
                  f2b(b.x), f2b(b.y), f2b(b.z), f2b(b.w) };
  ((uint4*)outp)[j] = *(const uint4*)o;
}

// ---------------- bf16 MFMA GEMM: C = A[M,768] x B[N,768]^T ----------------
// EPI 0: qkv epilogue (RS scale q,k; bf16 scatter to [B,H,N,D]); EPI 1: +bias, f32 row-major
template<int EPI>
__global__ __launch_bounds__(256) void k_mfma_gemm(const ushort* __restrict__ A,
                                                   const ushort* __restrict__ B,
                                                   const float* __restrict__ bias,
                                                   void* __restrict__ o0,
                                                   void* __restrict__ o1,
                                                   void* __restrict__ o2) {
  __shared__ ushort As[128*72];
  __shared__ ushort Bs[128*72];
  const int t = threadIdx.x;
  const int m0 = blockIdx.y*128, n0 = blockIdx.x*128;
  const int w = t>>6, lane = t&63;
  const int wr = w>>1, wc = w&1;
  const int lrow = lane&15, lkb = lane>>4;
  f32x4 acc[4][4] = {};
  const int srow = t>>1, skoff = (t&1)*32;
  const ushort* aP = A + (size_t)(m0+srow)*768 + skoff;
  const ushort* bP = B + (size_t)(n0+srow)*768 + skoff;
  ushort* aw = &As[srow*72 + skoff];
  ushort* bw = &Bs[srow*72 + skoff];
  for (int k0 = 0; k0 < 768; k0 += 64) {
    uint4 a0 = *(const uint4*)(aP+k0),    a1 = *(const uint4*)(aP+k0+8);
    uint4 a2 = *(const uint4*)(aP+k0+16), a3 = *(const uint4*)(aP+k0+24);
    uint4 b0 = *(const uint4*)(bP+k0),    b1 = *(const uint4*)(bP+k0+8);
    uint4 b2 = *(const uint4*)(bP+k0+16), b3 = *(const uint4*)(bP+k0+24);
    __syncthreads();
    *(uint4*)(aw)    = a0; *(uint4*)(aw+8)  = a1;
    *(uint4*)(aw+16) = a2; *(uint4*)(aw+24) = a3;
    *(uint4*)(bw)    = b0; *(uint4*)(bw+8)  = b1;
    *(uint4*)(bw+16) = b2; *(uint4*)(bw+24) = b3;
    __syncthreads();
#pragma unroll
    for (int kk = 0; kk < 2; kk++) {
      bf16x8 af[4], bfr[4];
#pragma unroll
      for (int m = 0; m < 4; m++)
        af[m] = *(const bf16x8*)&As[(wr*64+m*16+lrow)*72 + kk*32 + lkb*8];
#pragma unroll
      for (int n = 0; n < 4; n++)
        bfr[n] = *(const bf16x8*)&Bs[(wc*64+n*16+lrow)*72 + kk*32 + lkb*8];
#pragma unroll
      for (int m = 0; m < 4; m++)
#pragma unroll
        for (int n = 0; n < 4; n++)
          acc[m][n] = __builtin_amdgcn_mfma_f32_16x16x32_bf16(af[m], bfr[n], acc[m][n], 0, 0, 0);
    }
  }
  const int r4 = lane>>4;
#pragma unroll
  for (int m = 0; m < 4; m++) {
#pragma unroll
    for (int r = 0; r < 4; r++) {
      const int grow = m0 + wr*64 + m*16 + r4*4 + r;
      if (EPI == 0) {
        ushort* q = (ushort*)o0; ushort* k = (ushort*)o1; ushort* v = (ushort*)o2;
        const int b = grow/196, nn = grow - b*196;
#pragma unroll
        for (int n = 0; n < 4; n++) {
          const int gcol = n0 + wc*64 + n*16 + lrow;
          const int three = gcol/768, rem = gcol - three*768;
          const int h = rem>>6, dd = rem&63;
          float val = acc[m][n][r] * (three < 2 ? RS : 1.0f);
          ushort* base = (three == 0) ? q : (three == 1) ? k : v;
          base[((size_t)(b*12+h)*196 + nn)*64 + dd] = f2b(val);
        }
      } else {
        float* outp = (float*)o0;
#pragma unroll
        for (int n = 0; n < 4; n++) {
          const int gcol = n0 + wc*64 + n*16 + lrow;
          outp[(size_t)grow*768 + gcol] = acc[m][n][r] + bias[gcol];
        }
      }
    }
  }
}

// ---------------- fused QK^T (MFMA) + register softmax -> attn f32 ----------------
__global__ __launch_bounds__(256) void k_qks(const ushort* __restrict__ qb,
                                             const ushort* __restrict__ kb,
                                             float* __restrict__ attn) {
  __shared__ ushort K_lds[208*68];   // 28288 B
  const int t = threadIdx.x;
  const int bh = blockIdx.x;
  const ushort* kp = kb + (size_t)bh*Nn*Dd;
  const ushort* qp = qb + (size_t)bh*Nn*Dd;
  for (int i = t; i < 1568; i += 256) {
    int row = i >> 3, ko = (i & 7)*8;
    *(uint4*)&K_lds[row*68 + ko] = *(const uint4*)(kp + (size_t)row*64 + ko);
  }
  for (int i = t; i < 408; i += 256)
    ((unsigned*)&K_lds[196*68])[i] = 0u;
  __syncthreads();
  const int w = t >> 6, lane = t & 63;
  const int slot = blockIdx.y*4 + w;       // m-tile 0..15 (13..15 idle)
  if (slot >= 13) return;
  const int lrow = lane & 15, lk = lane >> 4;
  int qrow = slot*16 + lrow; if (qrow > 195) qrow = 195;
  bf16x8 aq0 = *(const bf16x8*)(qp + (size_t)qrow*64 + lk*8);
  bf16x8 aq1 = *(const bf16x8*)(qp + (size_t)qrow*64 + 32 + lk*8);
  f32x4 acc[13];
#pragma unroll
  for (int nt = 0; nt < 13; nt++) {
    f32x4 a = {};
    bf16x8 b0 = *(const bf16x8*)&K_lds[(nt*16 + lrow)*68 + lk*8];
    a = __builtin_amdgcn_mfma_f32_16x16x32_bf16(aq0, b0, a, 0, 0, 0);
    bf16x8 b1 = *(const bf16x8*)&K_lds[(nt*16 + lrow)*68 + 32 + lk*8];
    acc[nt] = __builtin_amdgcn_mfma_f32_16x16x32_bf16(aq1, b1, a, 0, 0, 0);
  }
  const bool tailok = (lrow < 4);          // nt==12 valid cols: 192..195
  float inv[4];
#pragma unroll
  for (int r = 0; r < 4; r++) {
    float mx = -1e30f;
#pragma unroll
    for (int nt = 0; nt < 12; nt++) mx = fmaxf(mx, acc[nt][r]);
    if (tailok) mx = fmaxf(mx, acc[12][r]);
    mx = fmaxf(mx, __shfl_xor(mx, 1, 64));
    mx = fmaxf(mx, __shfl_xor(mx, 2, 64));
    mx = fmaxf(mx, __shfl_xor(mx, 4, 64));
    mx = fmaxf(mx, __shfl_xor(mx, 8, 64));
    float s = 0.0f;
#pragma unroll
    for (int nt = 0; nt < 13; nt++) {
      bool valid = (nt < 12) || tailok;
      float e = valid ? __expf(acc[nt][r] - mx) : 0.0f;
      acc[nt][r] = e;
      s += e;
    }
    s += __shfl_xor(s, 1, 64);
    s += __shfl_xor(s, 2, 64);
    s += __shfl_xor(s, 4, 64);
    s += __shfl_xor(s, 8, 64);
    inv[r] = 1.0f / s;
  }
  const int rowb = slot*16 + lk*4;
#pragma unroll
  for (int r = 0; r < 4; r++) {
    const int row = rowb + r;
    if (row < 196) {
      float* op = attn + ((size_t)bh*196 + row)*196;
#pragma unroll
      for (int nt = 0; nt < 13; nt++) {
        int col = nt*16 + lrow;
        if (col < 196) op[col] = acc[nt][r]*inv[r];
      }
    }
  }
}

// ---------------- Gram matrix M[h,h'] = sum attn_h * attn_h' (78 upper-tri) ----------------
__global__ __launch_bounds__(256) void k_gram(const float* __restrict__ attn,
                                              float* __restrict__ part) {
  __shared__ float red2[4*78];
  const int t = threadIdx.x;
  float m[78] = {};
  const int stride = gridDim.x * 256;
  for (int s = blockIdx.x*256 + t; s < SAMP; s += stride) {
    int b = s / NN2, p = s - b*NN2;
    float a[12];
#pragma unroll
    for (int h = 0; h < 12; h++) a[h] = attn[((size_t)(b*12+h))*NN2 + p];
    int idx = 0;
#pragma unroll
    for (int h = 0; h < 12; h++)
#pragma unroll
      for (int h2 = h; h2 < 12; h2++, idx++) m[idx] = fmaf(a[h], a[h2], m[idx]);
  }
#pragma unroll
  for (int i = 0; i < 78; i++) {
#pragma unroll
    for (int off = 32; off; off >>= 1) m[i] += __shfl_xor(m[i], off, 64);
  }
  const int w = t >> 6;
  if ((t & 63) == 0) {
#pragma unroll
    for (int i = 0; i < 78; i++) red2[w*78 + i] = m[i];
  }
  __syncthreads();
  if (t < 78)
    part[(size_t)blockIdx.x*78 + t] = red2[t] + red2[78+t] + red2[156+t] + red2[234+t];
}

// ---------------- hierarchical deterministic reduce ----------------
__global__ __launch_bounds__(256) void k_reduce(const float* __restrict__ part, int nb,
                                               int stride, double* __restrict__ dsum) {
  __shared__ double sh[256];
  const int c = blockIdx.x;
  const int t = threadIdx.x;
  double s = 0.0;
  for (int i = t; i < nb; i += 256) s += (double)part[(size_t)i*stride + c];
  sh[t] = s;
  __syncthreads();
  for (int o = 128; o; o >>= 1) {
    if (t < o) sh[t] += sh[t + o];
    __syncthreads();
  }
  if (t == 0) dsum[c] = sh[0];
}

// ---------------- bn1 affine from Gram (dsum[78]) ----------------
__global__ void k_bn1gram(const double* __restrict__ dsum,
                          const float* __restrict__ w_exp,
                          const float* __restrict__ g, const float* __restrict__ beta,
                          float* __restrict__ stats) {
  int c = threadIdx.x;
  if (c >= 36) return;
  float wv[12];
  float mean = 0.0f;
#pragma unroll
  for (int h = 0; h < 12; h++) { wv[h] = w_exp[c*12+h]; mean += wv[h]; }
  mean *= (1.0f/196.0f);
  double e2 = 0.0;
  int idx = 0;
#pragma unroll
  for (int h = 0; h < 12; h++)
#pragma unroll
    for (int h2 = h; h2 < 12; h2++, idx++) {
      double coef = (double)wv[h] * (double)wv[h2] * (h == h2 ? 1.0 : 2.0);
      e2 += coef * dsum[idx];
    }
  double var = e2 / (double)SAMP - (double)mean*mean;
  float a = g[c] * rsqrtf((float)var + 1e-5f);
  stats[c] = a;
  stats[36 + c] = beta[c] - mean * a;
}

// ---- pass A: expand (halo, 256 thr) + column-sweep dw (168 thr: ch x col,
//      register row rotation -> 48 LDS reads/thread/group vs 108) ----
// y2 stats -> part[blk][72]; y2 fp16 cached (coalesced via LDS transpose) for blk < NCACHE
__global__ __launch_bounds__(256) void k_dlaA(const float* __restrict__ attn,
                                              const float* __restrict__ w_exp,
                                              const float* __restrict__ w_dw,
                                              const float* __restrict__ stats,
                                              ushort* __restrict__ rA,
                                              ushort* __restrict__ rB,
                                              ushort* __restrict__ rC,
                                              float* __restrict__ part) {
  __shared__ float  y_s[12*263];    // stride 263 (mod32=7): (cl,col) lane pattern ~2-way
  __shared__ ushort y2l[12*200];    // y2 fp16 transpose-staging
  __shared__ float  sbuf[2*168];    // per-(cl,col) s1/s2 partials
  const int t = threadIdx.x;
  const int blk = blockIdx.x;
  const int b = blk / 196, tile = blk - b*196;
  const int tyq = tile / 14;
  const int ty0 = tyq * 14, tx0 = (tile - tyq*14) * 14;
  const int hy = ty0 + (t >> 4) - 1, hx = tx0 + (t & 15) - 1;
  const bool inb = (hy >= 0) && (hy < 196) && (hx >= 0) && (hx < 196);
  float a[12];
#pragma unroll
  for (int ch = 0; ch < 12; ch++)
    a[ch] = inb ? attn[((size_t)(b*12+ch))*NN2 + (size_t)hy*196 + hx] : 0.0f;

  const bool dwact = (t < 168);
  const int cl = t % 12, col = t / 12;       // dw role: channel-in-group, output column
  ushort* ydst = (blk < NCACHE) ? y2chunk_w(blk, rA, rB, rC) : nullptr;

  for (int g = 0; g < 3; g++) {
    __syncthreads();   // y_s / y2l / sbuf free (prev group consumers done)
    // expand: y1c = clip(bn1(conv_exp)) for this group's 12 channels; 0 outside image
#pragma unroll
    for (int c2 = 0; c2 < 12; c2++) {
      const int c = g*12 + c2;
      float y = 0.0f;
#pragma unroll
      for (int h = 0; h < 12; h++) y = fmaf(w_exp[c*12+h], a[h], y);
      y = y*stats[c] + stats[36+c];
      y = fminf(fmaxf(y, 0.0f), 6.0f);
      y_s[c2*263 + t] = inb ? y : 0.0f;
    }
    __syncthreads();
    if (dwact) {
      const int c = g*12 + cl;
      const float* ys = &y_s[cl*263 + col];
      const float* wd = &w_dw[c*9];
      float s1 = 0.0f, s2 = 0.0f;
      ushort y2h[14];
      float r0c0 = ys[0],  r0c1 = ys[1],  r0c2 = ys[2];
      float r1c0 = ys[16], r1c1 = ys[17], r1c2 = ys[18];
#pragma unroll
      for (int r = 0; r < 14; r++) {
        float r2c0 = ys[(r+2)*16], r2c1 = ys[(r+2)*16+1], r2c2 = ys[(r+2)*16+2];
        float y2 = wd[0]*r0c0;
        y2 = fmaf(wd[1], r0c1, y2); y2 = fmaf(wd[2], r0c2, y2);
        y2 = fmaf(wd[3], r1c0, y2); y2 = fmaf(wd[4], r1c1, y2);
        y2 = fmaf(wd[5], r1c2, y2); y2 = fmaf(wd[6], r2c0, y2);
        y2 = fmaf(wd[7], r2c1, y2); y2 = fmaf(wd[8], r2c2, y2);
        s1 += y2; s2 = fmaf(y2, y2, s2);
        y2h[r] = f2h_(y2);
        r0c0 = r1c0; r0c1 = r1c1; r0c2 = r1c2;
        r1c0 = r2c0; r1c1 = r2c1; r1c2 = r2c2;
      }
      sbuf[cl*14 + col] = s1;
      sbuf[168 + cl*14 + col] = s2;
#pragma unroll
      for (int r = 0; r < 14; r++) y2l[cl*200 + r*14 + col] = y2h[r];
    }
    __syncthreads();
    if (ydst) {
      for (int i = t; i < 2352; i += 256) {
        int c2 = i / 196, px = i - c2*196;
        ydst[g*2352 + i] = y2l[c2*200 + px];
      }
    }
    if (t < 24) {
      const int cc = t % 12, wh = t / 12;
      float s = 0.0f;
#pragma unroll
      for (int j = 0; j < 14; j++) s += sbuf[wh*168 + cc*14 + j];
      part[(size_t)blk*72 + wh*36 + g*12 + cc] = s;
    }
  }
}

// ---- pass B: z from cached y2 (blk<NCACHE) or full recompute (batch 31); z stats ----
__global__ __launch_bounds__(256) void k_dlaB(const float* __restrict__ attn,
                                              const ushort* __restrict__ rA,
                                              const ushort* __restrict__ rB,
                                              const ushort* __restrict__ rC,
                                              const float* __restrict__ w_exp,
                                              const float* __restrict__ w_dw,
                                              const float* __restrict__ w_pro,
                                              const float* __restrict__ stats,
                                              float* __restrict__ zatt,
                                              float* __restrict__ z31,
                                              float* __restrict__ part) {
  __shared__ float y_s[12*256];
  __shared__ float z2[12*200];
  const int t = threadIdx.x;
  const int blk = blockIdx.x;
  const int b = blk / 196, tile = blk - b*196;
  const int tyq = tile / 14;
  const int ty0 = tyq * 14, tx0 = (tile - tyq*14) * 14;
  const bool act = (t < 196);
  const int py = t / 14, px = t - py*14;
  const int oy = ty0 + py, ox = tx0 + px;
  float z[12] = {};

  if (blk < NCACHE) {
    if (act) {
      const ushort* src = y2chunk_r(blk, rA, rB, rC);
#pragma unroll
      for (int c = 0; c < 36; c++) {
        float y2 = h2f_(src[c*196 + t]);
        float y2c = y2*stats[72+c] + stats[108+c];
        y2c = fminf(fmaxf(y2c, 0.0f), 6.0f);
#pragma unroll
        for (int cc = 0; cc < 12; cc++) z[cc] = fmaf(w_pro[cc*36+c], y2c, z[cc]);
      }
#pragma unroll
      for (int cc = 0; cc < 12; cc++)
        zatt[((size_t)(b*12+cc))*NN2 + (size_t)oy*196 + ox] = z[cc];
    }
  } else {
    const int hy = ty0 + (t >> 4) - 1, hx = tx0 + (t & 15) - 1;
    const bool inb = (hy >= 0) && (hy < 196) && (hx >= 0) && (hx < 196);
    float a[12];
#pragma unroll
    for (int ch = 0; ch < 12; ch++)
      a[ch] = inb ? attn[((size_t)(b*12+ch))*NN2 + (size_t)hy*196 + hx] : 0.0f;
    const int base = (py+1)*16 + (px+1);
    for (int g = 0; g < 3; g++) {
      __syncthreads();
#pragma unroll
      for (int cl = 0; cl < 12; cl++) {
        const int c = g*12 + cl;
        float y = 0.0f;
#pragma unroll
        for (int h = 0; h < 12; h++) y = fmaf(w_exp[c*12+h], a[h], y);
        y = y*stats[c] + stats[36+c];
        y = fminf(fmaxf(y, 0.0f), 6.0f);
        y_s[cl*256 + t] = inb ? y : 0.0f;
      }
      __syncthreads();
      if (act) {
#pragma unroll
        for (int cl = 0; cl < 12; cl++) {
          const int c = g*12 + cl;
          const float* ys = &y_s[cl*256];
          float y2 = 0.0f;
#pragma unroll
          for (int di = 0; di < 3; di++)
#pragma unroll
            for (int dj = 0; dj < 3; dj++)
              y2 = fmaf(w_dw[c*9 + di*3 + dj], ys[base + (di-1)*16 + (dj-1)], y2);
          float y2c = y2*stats[72+c] + stats[108+c];
          y2c = fminf(fmaxf(y2c, 0.0f), 6.0f);
#pragma unroll
          for (int cc = 0; cc < 12; cc++) z[cc] = fmaf(w_pro[cc*36+c], y2c, z[cc]);
        }
      }
    }
    if (act) {
#pragma unroll
      for (int cc = 0; cc < 12; cc++)
        z31[(size_t)cc*NN2 + (size_t)oy*196 + ox] = z[cc];
    }
  }
  // z stats (both paths)
  __syncthreads();
  if (act) {
#pragma unroll
    for (int cc = 0; cc < 12; cc++) z2[cc*200 + t] = z[cc];
  }
  __syncthreads();
  const int rs = t >> 3, seg = t & 7;
  const int pix0 = seg*25;
  const int pcnt = (seg == 7) ? 21 : 25;
  if (rs < 24) {
    const int cl = rs % 12, wh = rs / 12;
    float s = 0.0f;
    for (int i = 0; i < pcnt; i++) {
      float v = z2[cl*200 + pix0 + i];
      s += wh ? v*v : v;
    }
    s += __shfl_xor(s, 1, 64);
    s += __shfl_xor(s, 2, 64);
    s += __shfl_xor(s, 4, 64);
    if (seg == 0)
      part[(size_t)blk*24 + wh*12 + cl] = s;
  }
}

// ---------------- dsum -> BN affine (36 ch, bn2) ----------------
__global__ void k_bnaffine36(const double* __restrict__ dsum,
                             const float* __restrict__ g, const float* __restrict__ beta,
                             float* __restrict__ stats, int off) {
  int c = threadIdx.x;
  if (c >= 36) return;
  double m = dsum[c] / (double)SAMP;
  double v = dsum[36 + c] / (double)SAMP - m*m;
  float a = g[c] * rsqrtf((float)v + 1e-5f);
  stats[off + c] = a;
  stats[off + 36 + c] = beta[c] - (float)m * a;
}

// ---------------- combined bn3 + adapt_bn affine (from dsum[24]) ----------------
__global__ void k_bnfinal(const double* __restrict__ dsum,
                          const float* __restrict__ g3, const float* __restrict__ b3,
                          const float* __restrict__ ag, const float* __restrict__ ab,
                          float* __restrict__ stats) {
  int c = threadIdx.x;
  if (c >= 12) return;
  (void)b3;
  double m = dsum[c] / (double)SAMP;
  double v = dsum[12 + c] / (double)SAMP - m*m;
  float r1 = rsqrtf((float)v + 1e-5f);
  float vt = g3[c]*g3[c]*(float)v*r1*r1;
  float r2 = rsqrtf(vt + 1e-5f);
  float A = g3[c]*ag[c]*r1*r2;
  stats[144 + c] = A;
  stats[156 + c] = ab[c] - (float)m*A;
}

// ---------------- MFMA PV: attn_r = z*Af+Bf (f32, in-place for b<31), O = P@V -> out_pre bf16 ----------------
__global__ __launch_bounds__(256) void k_pvm(const float* __restrict__ z31,
                                             const ushort* __restrict__ v16,
                                             const float* __restrict__ stats,
                                             float* __restrict__ attn_r,
                                             ushort* __restrict__ out_pre) {
  constexpr int STR = 232;
  __shared__ ushort Vt[64*STR];
  __shared__ ushort U[32*STR];
  const int t = threadIdx.x;
  const int bh = blockIdx.x;
  const int r0 = blockIdx.y * 32;
  const int b = bh / 12, h = bh - b*12;
  const float Af = stats[144 + h], Bf = stats[156 + h];
  const ushort* vp = v16 + (size_t)bh * Nn * Dd;

#pragma unroll
  for (int half = 0; half < 2; half++) {
    const int mbase = half * 104;
    const int nm = half ? 92 : 104;
    for (int i = t; i < nm*8; i += 256) {
      int lm = i >> 3, d0 = (i & 7)*8;
      *(uint4*)&U[lm*64 + d0] = *(const uint4*)(vp + (size_t)(mbase+lm)*64 + d0);
    }
    __syncthreads();
    const int ngrp = (nm + 7) >> 3;
    for (int i = t; i < 64*ngrp; i += 256) {
      int d = i & 63, mg = i >> 6;
      int lm0 = mg*8;
      ushort tmp[8];
      int cnt = nm - lm0; if (cnt > 8) cnt = 8;
      for (int j = 0; j < cnt; j++) tmp[j] = U[(lm0+j)*64 + d];
      for (int j = cnt; j < 8; j++) tmp[j] = 0;
      *(uint4*)&Vt[d*STR + mbase + lm0] = *(uint4*)tmp;
    }
    __syncthreads();
  }
  for (int i = t; i < 64*36; i += 256) {
    int d = i / 36, m = 196 + i % 36;
    Vt[d*STR + m] = 0;
  }
  for (int i = t; i < 32*STR/8; i += 256)
    ((uint4*)U)[i] = make_uint4(0,0,0,0);
  __syncthreads();
  const int nvalid = (r0 + 32 <= 196) ? 32 : (196 - r0);
  float* arp = attn_r + (size_t)bh*NN2 + (size_t)r0*196;
  const float* zp = (b < 31) ? arp : (z31 + (size_t)h*NN2 + (size_t)r0*196);
  for (int idx = t; idx < nvalid*196; idx += 256) {
    int rr = idx / 196, m = idx - rr*196;
    float val = fmaf(zp[(size_t)rr*196 + m], Af, Bf);
    arp[(size_t)rr*196 + m] = val;
    U[rr*STR + m] = f2b(val);
  }
  __syncthreads();
  const int w = t >> 6, lane = t & 63;
  const int mt = w >> 1, ct = w & 1;
  const int lr = lane & 15, lk = lane >> 4;
#pragma unroll
  for (int cn = 0; cn < 2; cn++) {
    const int n0 = ct*32 + cn*16;
    f32x4 acc = {};
#pragma unroll
    for (int ks = 0; ks < 7; ks++) {
      bf16x8 af = *(const bf16x8*)&U[(mt*16 + lr)*STR + ks*32 + lk*8];
      bf16x8 bf = *(const bf16x8*)&Vt[(n0 + lr)*STR + ks*32 + lk*8];
      acc = __builtin_amdgcn_mfma_f32_16x16x32_bf16(af, bf, acc, 0, 0, 0);
    }
#pragma unroll
    for (int r = 0; r < 4; r++) {
      int row = mt*16 + lk*4 + r;
      if (row < nvalid)
        out_pre[((size_t)(b*196 + r0 + row))*Cc + h*64 + n0 + lr] = f2b(acc[r]);
    }
  }
}

// ---------------- launch ----------------
extern "C" void kernel_launch(void* const* d_in, const int* in_sizes, int n_in,
                              void* d_out, int out_size, void* d_ws, size_t ws_size,
                              hipStream_t stream) {
  (void)in_sizes; (void)n_in; (void)out_size; (void)ws_size;
  const float* x      = (const float*)d_in[0];
  const float* w_qkv  = (const float*)d_in[1];
  const float* w_exp  = (const float*)d_in[2];
  const float* bn1_g  = (const float*)d_in[3];
  const float* bn1_b  = (const float*)d_in[4];
  const float* w_dw   = (const float*)d_in[5];
  const float* bn2_g  = (const float*)d_in[6];
  const float* bn2_b  = (const float*)d_in[7];
  const float* w_pro  = (const float*)d_in[8];
  const float* bn3_g  = (const float*)d_in[9];
  const float* bn3_b  = (const float*)d_in[10];
  const float* abn_g  = (const float*)d_in[11];
  const float* abn_b  = (const float*)d_in[12];
  const float* w_proj = (const float*)d_in[13];
  const float* b_proj = (const float*)d_in[14];

  float* out      = (float*)d_out;
  float* attn_out = out + (size_t)QSZ;      // d_out attn region: attn -> z(b<31) -> attn_r
  float* ws    = (float*)d_ws;
  ushort* vb16 = (ushort*)ws;               // [QSZ ushorts]
  ushort* opb  = (ushort*)ws + (size_t)QSZ; // [QSZ ushorts]: y2 cache rC -> out_pre
  float*  big  = ws + (size_t)QSZ;          // [ATT]: {q,k bf16} -> y2 cache rA
  ushort* qb16 = (ushort*)big;
  ushort* kb16 = qb16 + (size_t)QSZ;
  float* stats = ws + (size_t)QSZ + ATT;    // [256]
  float* part  = stats + 256;               // [6272*72]
  double* dsum = (double*)(part + (size_t)6272*72); // [96]
  float* z31   = (float*)(dsum + 96);       // [12*NN2] batch-31 z aux

  // staging in dead d_out region:
  ushort* xb   = (ushort*)out;              // x bf16
  ushort* wqb  = xb + (size_t)QSZ;          // w_qkv bf16
  ushort* rB   = (ushort*)out;              // y2 cache region B (after gemm<0> consumed xb/wqb)
  ushort* wpb  = (ushort*)part;             // w_proj bf16 (part dead after last reduce)

  k_cast <<<QSZ/2048, 256, 0, stream>>>(x, xb);
  k_cast <<<(2304*768)/2048, 256, 0, stream>>>(w_qkv, wqb);
  k_mfma_gemm<0><<<dim3(18, 49), 256, 0, stream>>>(xb, wqb, nullptr, qb16, kb16, vb16);
  k_qks      <<<dim3(384, 4), 256, 0, stream>>>(qb16, kb16, attn_out);
  k_gram     <<<2048, 256, 0, stream>>>(attn_out, part);
  k_reduce   <<<78, 256, 0, stream>>>(part, 2048, 78, dsum);
  k_bn1gram  <<<1, 64, 0, stream>>>(dsum, w_exp, bn1_g, bn1_b, stats);
  k_dlaA     <<<6272, 256, 0, stream>>>(attn_out, w_exp, w_dw, stats,
                                        (ushort*)big, rB, opb, part);
  k_reduce   <<<72, 256, 0, stream>>>(part, 6272, 72, dsum);
  k_bnaffine36<<<1, 64, 0, stream>>>(dsum, bn2_g, bn2_b, stats, 72);
  k_dlaB     <<<6272, 256, 0, stream>>>(attn_out, (const ushort*)big, rB, opb,
                                        w_exp, w_dw, w_pro, stats, attn_out, z31, part);
  k_reduce   <<<24, 256, 0, stream>>>(part, 6272, 24, dsum);
  k_bnfinal  <<<1, 64, 0, stream>>>(dsum, bn3_g, bn3_b, abn_g, abn_b, stats);
  k_cast     <<<(768*768)/2048, 256, 0, stream>>>(w_proj, wpb);
  k_pvm      <<<dim3(384, 7), 256, 0, stream>>>(z31, vb16, stats, attn_out, opb);
  k_mfma_gemm<1><<<dim3(6, 49), 256, 0, stream>>>(opb, wpb, b_proj, out, nullptr, nullptr);
}